// Round 3
// baseline (7372.725 us; speedup 1.0000x reference)
//
#include <hip/hip_runtime.h>
#include <hip/hip_bf16.h>

#define T_TOK 3600
#define D_    512
#define H_    8
#define HD    64
#define FF_   2048
#define NKT   57   // ceil(3600/64)

// timestep of token index: players [0,3000) step i/10, ball [3000,3300), cls [3300,3600)
__device__ __forceinline__ int step_of(int i) {
    return (i < 3000) ? (i / 10) : ((i < 3300) ? (i - 3000) : (i - 3300));
}

// ---------------- token embedding MLPs -------------------------------------
__global__ __launch_bounds__(256) void token_kernel(
    const float* __restrict__ pxs, const float* __restrict__ pys, const float* __restrict__ phs,
    const float* __restrict__ bxs, const float* __restrict__ bys, const float* __restrict__ bzs,
    const float* __restrict__ emb_table, const float* __restrict__ ball_emb,
    const float* __restrict__ cls_emb,
    const float* __restrict__ pW0, const float* __restrict__ pb0,
    const float* __restrict__ pW1, const float* __restrict__ pb1,
    const float* __restrict__ pW2, const float* __restrict__ pb2,
    const float* __restrict__ bW0, const float* __restrict__ bb0,
    const float* __restrict__ bW1, const float* __restrict__ bb1,
    const float* __restrict__ bW2, const float* __restrict__ bb2,
    const int* __restrict__ pidx, float* __restrict__ x)
{
    int tok = blockIdx.x;
    int t = threadIdx.x;
    if (tok >= 3300) { // cls rows: broadcast, NOT scaled
        x[(size_t)tok * D_ + t]       = cls_emb[t];
        x[(size_t)tok * D_ + t + 256] = cls_emb[t + 256];
        return;
    }
    __shared__ float in[24];
    __shared__ float h0[128];
    __shared__ float h1[256];
    bool isP = tok < 3000;
    const float *W0 = isP ? pW0 : bW0, *b0 = isP ? pb0 : bb0;
    const float *W1 = isP ? pW1 : bW1, *b1 = isP ? pb1 : bb1;
    const float *W2 = isP ? pW2 : bW2, *b2 = isP ? pb2 : bb2;
    if (t < 20) {
        if (isP) { int id = pidx[tok]; in[t] = emb_table[id * 20 + t]; }
        else     { in[t] = ball_emb[t]; }
    } else if (t < 23) {
        if (isP) in[t] = (t == 20) ? pxs[tok] : (t == 21) ? pys[tok] : phs[tok];
        else { int b = tok - 3000;
               in[t] = (t == 20) ? bxs[b] : (t == 21) ? bys[b] : bzs[b]; }
    }
    __syncthreads();
    if (t < 128) {
        float s = b0[t];
        const float* wr = W0 + t * 23;
        #pragma unroll
        for (int k = 0; k < 23; k++) s += wr[k] * in[k];
        h0[t] = fmaxf(s, 0.f);
    }
    __syncthreads();
    {
        float s = b1[t];
        const float4* wr4 = reinterpret_cast<const float4*>(W1 + t * 128);
        #pragma unroll 8
        for (int k4 = 0; k4 < 32; k4++) {
            float4 u = wr4[k4];
            s += u.x * h0[k4*4+0] + u.y * h0[k4*4+1]
               + u.z * h0[k4*4+2] + u.w * h0[k4*4+3];
        }
        h1[t] = fmaxf(s, 0.f);
    }
    __syncthreads();
    const float scale = 22.627416997969522f; // sqrt(512)
    for (int j = t; j < D_; j += 256) {
        float s = b2[j];
        const float4* wr4 = reinterpret_cast<const float4*>(W2 + j * 256);
        #pragma unroll 8
        for (int k4 = 0; k4 < 64; k4++) {
            float4 u = wr4[k4];
            s += u.x * h1[k4*4+0] + u.y * h1[k4*4+1]
               + u.z * h1[k4*4+2] + u.w * h1[k4*4+3];
        }
        x[(size_t)tok * D_ + j] = s * scale;
    }
}

// ---------------- fp32 tiled GEMM: C[M,N] = act(A[M,K] * W[N,K]^T + bias) ---
template<int RELU>
__global__ __launch_bounds__(256) void gemm_nt(
    const float* __restrict__ A, const float* __restrict__ W,
    const float* __restrict__ bias,
    float* __restrict__ C,
    int M, int N, int K)
{
    __shared__ float As[16][68]; // [k][m], pad->2-way max conflict on float4 reads
    __shared__ float Ws[16][68]; // [k][n]
    int t = threadIdx.x;
    int tx = t & 15, ty = t >> 4;
    int m0 = blockIdx.x * 64, n0 = blockIdx.y * 64;
    int lm = t >> 2;        // 0..63  (row within tile to load)
    int lk = (t & 3) * 4;   // 0,4,8,12 (k offset, float4)
    float acc[4][4] = {};
    for (int kk = 0; kk < K; kk += 16) {
        {
            int m = m0 + lm;
            float4 v = make_float4(0.f, 0.f, 0.f, 0.f);
            if (m < M) v = *reinterpret_cast<const float4*>(A + (size_t)m * K + kk + lk);
            As[lk + 0][lm] = v.x; As[lk + 1][lm] = v.y;
            As[lk + 2][lm] = v.z; As[lk + 3][lm] = v.w;
        }
        {
            int n = n0 + lm;
            float4 v = make_float4(0.f, 0.f, 0.f, 0.f);
            if (n < N) v = *reinterpret_cast<const float4*>(W + (size_t)n * K + kk + lk);
            Ws[lk + 0][lm] = v.x; Ws[lk + 1][lm] = v.y;
            Ws[lk + 2][lm] = v.z; Ws[lk + 3][lm] = v.w;
        }
        __syncthreads();
        #pragma unroll
        for (int k = 0; k < 16; k++) {
            float4 a = *reinterpret_cast<const float4*>(&As[k][ty * 4]);
            float4 b = *reinterpret_cast<const float4*>(&Ws[k][tx * 4]);
            float av[4] = {a.x, a.y, a.z, a.w};
            float bv[4] = {b.x, b.y, b.z, b.w};
            #pragma unroll
            for (int i = 0; i < 4; i++)
                #pragma unroll
                for (int j = 0; j < 4; j++)
                    acc[i][j] += av[i] * bv[j];
        }
        __syncthreads();
    }
    #pragma unroll
    for (int i = 0; i < 4; i++) {
        int m = m0 + ty * 4 + i;
        if (m >= M) continue;
        #pragma unroll
        for (int j = 0; j < 4; j++) {
            int n = n0 + tx * 4 + j;
            if (n >= N) continue;
            float v = acc[i][j] + bias[n];
            if (RELU) v = fmaxf(v, 0.f);
            C[(size_t)m * N + n] = v;
        }
    }
}

// ---------------- flash attention (fp32), block-causal by timestep ----------
// grid: (57 q-tiles, 8 heads), block: 256 = 4 waves splitting key tiles.
// No K/V LDS staging (K/V rows are lane-uniform reads, L1/L2/L3-cached).
// LDS only for the 4-way partial merge (padded to kill bank conflicts).
__global__ __launch_bounds__(256) void attn_kernel(
    const float* __restrict__ qkv, float* __restrict__ ob)
{
    __shared__ float P[4][64][65];   // per-wave partial O, padded
    __shared__ float ML[4][2][64];   // per-wave running max / sum
    int t = threadIdx.x;
    int w = t >> 6;   // wave 0..3
    int l = t & 63;   // lane = query within tile

    int q0 = blockIdx.x * 64;
    int h = blockIdx.y;
    int q = q0 + l;
    bool valid = q < T_TOK;
    int sq = valid ? step_of(q) : -1;

    int smax = sq;
    #pragma unroll
    for (int off = 32; off > 0; off >>= 1) smax = max(smax, __shfl_xor(smax, off));

    float qreg[64];
    if (valid) {
        const float* qp = qkv + (size_t)q * (3 * D_) + h * HD;
        #pragma unroll
        for (int k4 = 0; k4 < 16; k4++) {
            float4 v = *reinterpret_cast<const float4*>(qp + k4 * 4);
            qreg[k4*4+0] = v.x; qreg[k4*4+1] = v.y; qreg[k4*4+2] = v.z; qreg[k4*4+3] = v.w;
        }
    } else {
        #pragma unroll
        for (int k = 0; k < 64; k++) qreg[k] = 0.f;
    }
    const float sc = 0.125f; // 1/sqrt(64)
    #pragma unroll
    for (int k = 0; k < 64; k++) qreg[k] *= sc;

    float oacc[64];
    #pragma unroll
    for (int k = 0; k < 64; k++) oacc[k] = 0.f;
    float m = -INFINITY, lsum = 0.f;

    const float* kp0 = qkv + D_ + h * HD;       // K base
    const float* vp0 = qkv + 2 * D_ + h * HD;   // V base

    #pragma unroll 1
    for (int kt = w; kt < NKT; kt += 4) {
        int kbase = kt * 64;
        // skip tiles whose minimum step exceeds this block's max query step
        int a = kbase, b = min(kbase + 63, T_TOK - 1);
        int mn = 0x7fffffff;
        if (a < 3000) mn = min(mn, a / 10);
        if (b >= 3000 && a < 3300) mn = min(mn, max(a, 3000) - 3000);
        if (b >= 3300) mn = min(mn, max(a, 3300) - 3300);
        if (mn > smax) continue;

        #pragma unroll 1
        for (int c = 0; c < 4; c++) {
            float s[16];
            #pragma unroll
            for (int j = 0; j < 16; j++) {
                int key = kbase + c * 16 + j;
                float sj = -INFINITY;
                if (key < T_TOK) { // uniform branch
                    const float4* kr = reinterpret_cast<const float4*>(kp0 + (size_t)key * (3 * D_));
                    float a0 = 0.f, a1 = 0.f, a2 = 0.f, a3 = 0.f;
                    #pragma unroll
                    for (int k4 = 0; k4 < 16; k4 += 4) {
                        float4 v0 = kr[k4+0], v1 = kr[k4+1], v2 = kr[k4+2], v3 = kr[k4+3];
                        a0 += qreg[(k4+0)*4+0]*v0.x + qreg[(k4+0)*4+1]*v0.y
                            + qreg[(k4+0)*4+2]*v0.z + qreg[(k4+0)*4+3]*v0.w;
                        a1 += qreg[(k4+1)*4+0]*v1.x + qreg[(k4+1)*4+1]*v1.y
                            + qreg[(k4+1)*4+2]*v1.z + qreg[(k4+1)*4+3]*v1.w;
                        a2 += qreg[(k4+2)*4+0]*v2.x + qreg[(k4+2)*4+1]*v2.y
                            + qreg[(k4+2)*4+2]*v2.z + qreg[(k4+2)*4+3]*v2.w;
                        a3 += qreg[(k4+3)*4+0]*v3.x + qreg[(k4+3)*4+1]*v3.y
                            + qreg[(k4+3)*4+2]*v3.z + qreg[(k4+3)*4+3]*v3.w;
                    }
                    float acc = (a0 + a1) + (a2 + a3);
                    bool vis = step_of(key) <= sq;
                    sj = vis ? acc : -INFINITY;
                }
                s[j] = sj;
            }
            float mt = s[0];
            #pragma unroll
            for (int j = 1; j < 16; j++) mt = fmaxf(mt, s[j]);
            if (mt == -INFINITY) continue; // fully masked chunk (per-lane)
            if (mt > m) {
                float cc = __expf(m - mt); // m=-inf -> 0
                lsum *= cc;
                #pragma unroll
                for (int k = 0; k < 64; k++) oacc[k] *= cc;
                m = mt;
            }
            #pragma unroll
            for (int j = 0; j < 16; j++) {
                int key = kbase + c * 16 + j;
                if (key >= T_TOK) continue; // uniform
                float p = __expf(s[j] - m);
                lsum += p;
                const float4* vr = reinterpret_cast<const float4*>(vp0 + (size_t)key * (3 * D_));
                #pragma unroll
                for (int k4 = 0; k4 < 16; k4++) {
                    float4 vv = vr[k4];
                    oacc[k4*4+0] += p * vv.x; oacc[k4*4+1] += p * vv.y;
                    oacc[k4*4+2] += p * vv.z; oacc[k4*4+3] += p * vv.w;
                }
            }
        }
    }
    // publish per-wave partials
    #pragma unroll
    for (int k = 0; k < 64; k++) P[w][l][k] = oacc[k];
    ML[w][0][l] = m;
    ML[w][1][l] = lsum;
    __syncthreads();
    // merge: each wave handles a 16-wide d-slice of all 64 queries (lane = query)
    if (valid) {
        float mc[4], lc[4];
        #pragma unroll
        for (int c = 0; c < 4; c++) { mc[c] = ML[c][0][l]; lc[c] = ML[c][1][l]; }
        float M = -INFINITY;
        #pragma unroll
        for (int c = 0; c < 4; c++) if (lc[c] > 0.f) M = fmaxf(M, mc[c]);
        float wts[4]; float den = 0.f;
        #pragma unroll
        for (int c = 0; c < 4; c++) {
            wts[c] = (lc[c] > 0.f) ? __expf(mc[c] - M) : 0.f;
            den += wts[c] * lc[c];
        }
        float inv = (den > 0.f) ? 1.f / den : 0.f;
        float* op = ob + (size_t)q * D_ + h * HD + w * 16;
        #pragma unroll
        for (int d = 0; d < 16; d++) {
            int dd = w * 16 + d;
            float o = P[0][l][dd] * wts[0] + P[1][l][dd] * wts[1]
                    + P[2][l][dd] * wts[2] + P[3][l][dd] * wts[3];
            op[d] = o * inv;
        }
    }
}

// ---------------- fused residual add + LayerNorm ---------------------------
__global__ __launch_bounds__(256) void add_ln_kernel(
    float* __restrict__ x, const float* __restrict__ r,
    const float* __restrict__ g, const float* __restrict__ b)
{
    int row = blockIdx.x, t = threadIdx.x;
    size_t base = (size_t)row * D_;
    float v0 = x[base + t] + r[base + t];
    float v1 = x[base + t + 256] + r[base + t + 256];
    float s = v0 + v1, ss = v0 * v0 + v1 * v1;
    #pragma unroll
    for (int off = 32; off > 0; off >>= 1) {
        s  += __shfl_xor(s, off);
        ss += __shfl_xor(ss, off);
    }
    __shared__ float rs[4], rss[4];
    int w = t >> 6;
    if ((t & 63) == 0) { rs[w] = s; rss[w] = ss; }
    __syncthreads();
    s  = rs[0] + rs[1] + rs[2] + rs[3];
    ss = rss[0] + rss[1] + rss[2] + rss[3];
    float mean = s * (1.f / 512.f);
    float var = ss * (1.f / 512.f) - mean * mean;
    float rstd = rsqrtf(var + 1e-5f);
    x[base + t]       = (v0 - mean) * rstd * g[t]       + b[t];
    x[base + t + 256] = (v1 - mean) * rstd * g[t + 256] + b[t + 256];
}

// ---------------------------------------------------------------------------
extern "C" void kernel_launch(void* const* d_in, const int* in_sizes, int n_in,
                              void* d_out, int out_size, void* d_ws, size_t ws_size,
                              hipStream_t stream)
{
    const float* player_xs = (const float*)d_in[0];
    const float* player_ys = (const float*)d_in[1];
    const float* player_hs = (const float*)d_in[2];
    const float* ball_xs   = (const float*)d_in[3];
    const float* ball_ys   = (const float*)d_in[4];
    const float* ball_zs   = (const float*)d_in[5];
    const float* emb_table = (const float*)d_in[6];
    const float* ball_emb  = (const float*)d_in[7];
    const float* cls_emb   = (const float*)d_in[8];
    const float* pW0 = (const float*)d_in[9];   const float* pb0 = (const float*)d_in[10];
    const float* pW1 = (const float*)d_in[11];  const float* pb1 = (const float*)d_in[12];
    const float* pW2 = (const float*)d_in[13];  const float* pb2 = (const float*)d_in[14];
    const float* bW0 = (const float*)d_in[15];  const float* bb0 = (const float*)d_in[16];
    const float* bW1 = (const float*)d_in[17];  const float* bb1 = (const float*)d_in[18];
    const float* bW2 = (const float*)d_in[19];  const float* bb2 = (const float*)d_in[20];
    const float* Wqkv = (const float*)d_in[21]; const float* bqkv = (const float*)d_in[22];
    const float* Wo  = (const float*)d_in[23];  const float* bo  = (const float*)d_in[24];
    const float* W1f = (const float*)d_in[25];  const float* b1f = (const float*)d_in[26];
    const float* W2f = (const float*)d_in[27];  const float* b2f = (const float*)d_in[28];
    const float* g1  = (const float*)d_in[29];  const float* be1 = (const float*)d_in[30];
    const float* g2  = (const float*)d_in[31];  const float* be2 = (const float*)d_in[32];
    const float* cpW = (const float*)d_in[33];  const float* cpb = (const float*)d_in[34];
    const float* cbW = (const float*)d_in[35];  const float* cbb = (const float*)d_in[36];
    const float* csW = (const float*)d_in[37];  const float* csb = (const float*)d_in[38];
    const int* pidx = (const int*)d_in[39];

    // workspace (fp32): x | big(qkv/ff1) | o | tmp  = 51.7 MB
    float* x   = (float*)d_ws;            // 3600*512   = 1,843,200
    float* big = x + 1843200;             // 3600*2048  = 7,372,800 (holds qkv 3600*1536 too)
    float* ob  = big + 7372800;           // 3600*512
    float* tmp = ob + 1843200;            // 3600*512
    float* out = (float*)d_out;

    token_kernel<<<3600, 256, 0, stream>>>(
        player_xs, player_ys, player_hs, ball_xs, ball_ys, ball_zs,
        emb_table, ball_emb, cls_emb,
        pW0, pb0, pW1, pb1, pW2, pb2,
        bW0, bb0, bW1, bb1, bW2, bb2, pidx, x);

    for (int l = 0; l < 4; l++) {
        const float* Wqkv_l = Wqkv + (size_t)l * 1536 * 512;
        const float* bqkv_l = bqkv + (size_t)l * 1536;
        const float* Wo_l   = Wo   + (size_t)l * 512 * 512;
        const float* bo_l   = bo   + (size_t)l * 512;
        const float* W1f_l  = W1f  + (size_t)l * 2048 * 512;
        const float* b1f_l  = b1f  + (size_t)l * 2048;
        const float* W2f_l  = W2f  + (size_t)l * 512 * 2048;
        const float* b2f_l  = b2f  + (size_t)l * 512;

        gemm_nt<0><<<dim3(57, 24), 256, 0, stream>>>(x,   Wqkv_l, bqkv_l, big, 3600, 1536, 512);
        attn_kernel<<<dim3(57, 8), 256, 0, stream>>>(big, ob);
        gemm_nt<0><<<dim3(57, 8),  256, 0, stream>>>(ob,  Wo_l,   bo_l,   tmp, 3600, 512,  512);
        add_ln_kernel<<<3600, 256, 0, stream>>>(x, tmp, g1 + (size_t)l * 512, be1 + (size_t)l * 512);
        gemm_nt<1><<<dim3(57, 32), 256, 0, stream>>>(x,   W1f_l,  b1f_l,  big, 3600, 2048, 512);
        gemm_nt<0><<<dim3(57, 8),  256, 0, stream>>>(big, W2f_l,  b2f_l,  tmp, 3600, 512,  2048);
        add_ln_kernel<<<3600, 256, 0, stream>>>(x, tmp, g2 + (size_t)l * 512, be2 + (size_t)l * 512);
    }

    gemm_nt<0><<<dim3(57, 2),  256, 0, stream>>>(x, cpW, cpb, out + 0,       3600, 121,  512);
    gemm_nt<0><<<dim3(57, 21), 256, 0, stream>>>(x, cbW, cbb, out + 435600,  3600, 1331, 512);
    gemm_nt<0><<<dim3(57, 1),  256, 0, stream>>>(x, csW, csb, out + 5227200, 3600, 10,   512);
}

// Round 4
// 2907.510 us; speedup vs baseline: 2.5358x; 2.5358x over previous
//
#include <hip/hip_runtime.h>
#include <hip/hip_bf16.h>

typedef unsigned short u16;
typedef __attribute__((ext_vector_type(8))) short bf16x8;
typedef __attribute__((ext_vector_type(4))) float f32x4;

#define T_TOK 3600
#define D_    512
#define H_    8
#define HD    64
#define FF_   2048
#define NKT   57    // ceil(3600/64)
#define VT_S  3648  // padded token stride for Vt (57*64)

__device__ __forceinline__ u16 f2bf(float f) {
    unsigned int x = __float_as_uint(f);
    unsigned int lsb = (x >> 16) & 1;
    return (u16)((x + 0x7fffu + lsb) >> 16);
}
// timestep of token index: players [0,3000) step i/10, ball [3000,3300), cls [3300,3600)
__device__ __forceinline__ int step_of(int i) {
    return (i < 3000) ? (i / 10) : ((i < 3300) ? (i - 3000) : (i - 3300));
}

// ---------------- token embedding MLPs -------------------------------------
__global__ __launch_bounds__(256) void token_kernel(
    const float* __restrict__ pxs, const float* __restrict__ pys, const float* __restrict__ phs,
    const float* __restrict__ bxs, const float* __restrict__ bys, const float* __restrict__ bzs,
    const float* __restrict__ emb_table, const float* __restrict__ ball_emb,
    const float* __restrict__ cls_emb,
    const float* __restrict__ pW0, const float* __restrict__ pb0,
    const float* __restrict__ pW1, const float* __restrict__ pb1,
    const float* __restrict__ pW2, const float* __restrict__ pb2,
    const float* __restrict__ bW0, const float* __restrict__ bb0,
    const float* __restrict__ bW1, const float* __restrict__ bb1,
    const float* __restrict__ bW2, const float* __restrict__ bb2,
    const int* __restrict__ pidx, float* __restrict__ x)
{
    int tok = blockIdx.x;
    int t = threadIdx.x;
    if (tok >= 3300) { // cls rows: broadcast, NOT scaled
        x[(size_t)tok * D_ + t]       = cls_emb[t];
        x[(size_t)tok * D_ + t + 256] = cls_emb[t + 256];
        return;
    }
    __shared__ float in[24];
    __shared__ float h0[128];
    __shared__ float h1[256];
    bool isP = tok < 3000;
    const float *W0 = isP ? pW0 : bW0, *b0 = isP ? pb0 : bb0;
    const float *W1 = isP ? pW1 : bW1, *b1 = isP ? pb1 : bb1;
    const float *W2 = isP ? pW2 : bW2, *b2 = isP ? pb2 : bb2;
    if (t < 20) {
        if (isP) { int id = pidx[tok]; in[t] = emb_table[id * 20 + t]; }
        else     { in[t] = ball_emb[t]; }
    } else if (t < 23) {
        if (isP) in[t] = (t == 20) ? pxs[tok] : (t == 21) ? pys[tok] : phs[tok];
        else { int b = tok - 3000;
               in[t] = (t == 20) ? bxs[b] : (t == 21) ? bys[b] : bzs[b]; }
    }
    __syncthreads();
    if (t < 128) {
        float s = b0[t];
        const float* wr = W0 + t * 23;
        #pragma unroll
        for (int k = 0; k < 23; k++) s += wr[k] * in[k];
        h0[t] = fmaxf(s, 0.f);
    }
    __syncthreads();
    {
        float s = b1[t];
        const float4* wr4 = reinterpret_cast<const float4*>(W1 + t * 128);
        #pragma unroll 8
        for (int k4 = 0; k4 < 32; k4++) {
            float4 u = wr4[k4];
            s += u.x * h0[k4*4+0] + u.y * h0[k4*4+1]
               + u.z * h0[k4*4+2] + u.w * h0[k4*4+3];
        }
        h1[t] = fmaxf(s, 0.f);
    }
    __syncthreads();
    const float scale = 22.627416997969522f; // sqrt(512)
    for (int j = t; j < D_; j += 256) {
        float s = b2[j];
        const float4* wr4 = reinterpret_cast<const float4*>(W2 + j * 256);
        #pragma unroll 8
        for (int k4 = 0; k4 < 64; k4++) {
            float4 u = wr4[k4];
            s += u.x * h1[k4*4+0] + u.y * h1[k4*4+1]
               + u.z * h1[k4*4+2] + u.w * h1[k4*4+3];
        }
        x[(size_t)tok * D_ + j] = s * scale;
    }
}

// ---------------- fp32 tiled GEMM: C[M,N] = act(A[M,K] * W[N,K]^T + bias) ---
template<int RELU>
__global__ __launch_bounds__(256) void gemm_nt(
    const float* __restrict__ A, const float* __restrict__ W,
    const float* __restrict__ bias,
    float* __restrict__ C,
    int M, int N, int K)
{
    __shared__ float As[16][68];
    __shared__ float Ws[16][68];
    int t = threadIdx.x;
    int tx = t & 15, ty = t >> 4;
    int m0 = blockIdx.x * 64, n0 = blockIdx.y * 64;
    int lm = t >> 2;
    int lk = (t & 3) * 4;
    float acc[4][4] = {};
    for (int kk = 0; kk < K; kk += 16) {
        {
            int m = m0 + lm;
            float4 v = make_float4(0.f, 0.f, 0.f, 0.f);
            if (m < M) v = *reinterpret_cast<const float4*>(A + (size_t)m * K + kk + lk);
            As[lk + 0][lm] = v.x; As[lk + 1][lm] = v.y;
            As[lk + 2][lm] = v.z; As[lk + 3][lm] = v.w;
        }
        {
            int n = n0 + lm;
            float4 v = make_float4(0.f, 0.f, 0.f, 0.f);
            if (n < N) v = *reinterpret_cast<const float4*>(W + (size_t)n * K + kk + lk);
            Ws[lk + 0][lm] = v.x; Ws[lk + 1][lm] = v.y;
            Ws[lk + 2][lm] = v.z; Ws[lk + 3][lm] = v.w;
        }
        __syncthreads();
        #pragma unroll
        for (int k = 0; k < 16; k++) {
            float4 a = *reinterpret_cast<const float4*>(&As[k][ty * 4]);
            float4 b = *reinterpret_cast<const float4*>(&Ws[k][tx * 4]);
            float av[4] = {a.x, a.y, a.z, a.w};
            float bv[4] = {b.x, b.y, b.z, b.w};
            #pragma unroll
            for (int i = 0; i < 4; i++)
                #pragma unroll
                for (int j = 0; j < 4; j++)
                    acc[i][j] += av[i] * bv[j];
        }
        __syncthreads();
    }
    #pragma unroll
    for (int i = 0; i < 4; i++) {
        int m = m0 + ty * 4 + i;
        if (m >= M) continue;
        #pragma unroll
        for (int j = 0; j < 4; j++) {
            int n = n0 + tx * 4 + j;
            if (n >= N) continue;
            float v = acc[i][j] + bias[n];
            if (RELU) v = fmaxf(v, 0.f);
            C[(size_t)m * N + n] = v;
        }
    }
}

// ---------------- convert qkv fp32 -> bf16 Q|K and transposed V -------------
// qkb[tok][0..1023] = bf16(qkv[tok][0..1023]); vt[h*64+d][tok] = bf16(V[tok][h*64+d])
// vt token-padded to 3648, pad zero-filled (so masked-key frag reads are finite).
__global__ __launch_bounds__(256) void convert_kernel(
    const float* __restrict__ qkv, u16* __restrict__ qkb, u16* __restrict__ vt)
{
    __shared__ u16 tile[64][66];
    int t = threadIdx.x;
    int tok0 = blockIdx.x * 64;
    for (int j = 0; j < 64; j++) {
        int row = j;
        int tok = tok0 + row;
        if (tok < T_TOK) {
            float4 v = *reinterpret_cast<const float4*>(qkv + (size_t)tok * 1536 + t * 4);
            ushort4 o;
            o.x = f2bf(v.x); o.y = f2bf(v.y); o.z = f2bf(v.z); o.w = f2bf(v.w);
            *reinterpret_cast<ushort4*>(qkb + (size_t)tok * 1024 + t * 4) = o;
        }
    }
    for (int h = 0; h < H_; h++) {
        __syncthreads();
        #pragma unroll
        for (int j = 0; j < 4; j++) {
            int idx4 = t + j * 256;      // 1024 float4, 16 per row
            int i = idx4 >> 4;
            int c4 = idx4 & 15;
            int tok = tok0 + i;
            float4 v = make_float4(0.f, 0.f, 0.f, 0.f);
            if (tok < T_TOK)
                v = *reinterpret_cast<const float4*>(qkv + (size_t)tok * 1536 + 1024 + h * HD + c4 * 4);
            tile[i][c4*4+0] = f2bf(v.x); tile[i][c4*4+1] = f2bf(v.y);
            tile[i][c4*4+2] = f2bf(v.z); tile[i][c4*4+3] = f2bf(v.w);
        }
        __syncthreads();
        int d = t >> 2;
        int i0 = (t & 3) * 16;
        u16 tt[16];
        #pragma unroll
        for (int i = 0; i < 16; i++) tt[i] = tile[i0 + i][d];
        ushort4* dst = reinterpret_cast<ushort4*>(vt + (size_t)(h * HD + d) * VT_S + tok0 + i0);
        dst[0] = make_ushort4(tt[0],  tt[1],  tt[2],  tt[3]);
        dst[1] = make_ushort4(tt[4],  tt[5],  tt[6],  tt[7]);
        dst[2] = make_ushort4(tt[8],  tt[9],  tt[10], tt[11]);
        dst[3] = make_ushort4(tt[12], tt[13], tt[14], tt[15]);
    }
}

// ---------------- MFMA flash attention (bf16 in, fp32 out) -----------------
// grid (57, 8), block 256 = 4 waves; wave w owns queries q0+16w..+15.
// Layouts (gfx950 16x16x32 bf16, m89-verified C/D):
//   A/B frag: row|col = lane&15, k = (lane>>4)*8 + j (8 contiguous bf16)
//   C/D:      col = lane&15, row = (lane>>4)*4 + reg
__global__ __launch_bounds__(256) void attn_mfma_kernel(
    const u16* __restrict__ qkb, const u16* __restrict__ vt, float* __restrict__ ob)
{
    __shared__ u16 plds_all[4][16][80];  // per-wave P buffer (pad 80 vs bank stride)
    int t = threadIdx.x;
    int w = t >> 6, l = t & 63;
    int lg = l >> 4, ll = l & 15;
    u16 (*plds)[80] = plds_all[w];
    int h = blockIdx.y;
    int q0 = blockIdx.x * 64 + w * 16;

    // Q A-frags (2 d-chunks); clamp token to stay in-bounds (masked rows unused)
    int qa = q0 + ll;
    int qac = min(qa, T_TOK - 1);
    const u16* qrow = qkb + (size_t)qac * 1024 + h * HD + lg * 8;
    bf16x8 qf0 = *reinterpret_cast<const bf16x8*>(qrow);
    bf16x8 qf1 = *reinterpret_cast<const bf16x8*>(qrow + 32);

    // softmax-row steps: rows q0+lg*4+r
    int sq[4];
    #pragma unroll
    for (int r = 0; r < 4; r++) {
        int qq = q0 + lg * 4 + r;
        sq[r] = (qq < T_TOK) ? step_of(qq) : -1;
    }
    // wave-wide max step (16-lane pattern repeats across wave -> reduce 1..8)
    int sqa = (qa < T_TOK) ? step_of(qa) : -1;
    int smax = sqa;
    #pragma unroll
    for (int off = 1; off < 16; off <<= 1) smax = max(smax, __shfl_xor(smax, off));

    f32x4 oacc[4];
    #pragma unroll
    for (int i = 0; i < 4; i++) oacc[i] = (f32x4){0.f, 0.f, 0.f, 0.f};
    float m[4], lsum[4];
    #pragma unroll
    for (int r = 0; r < 4; r++) { m[r] = -INFINITY; lsum[r] = 0.f; }

    #pragma unroll 1
    for (int kt = 0; kt < NKT; kt++) {
        int kbase = kt * 64;
        // tile min-step vs smax skip
        int a = kbase, b = min(kbase + 63, T_TOK - 1);
        int mn = 0x7fffffff;
        if (a < 3000) mn = min(mn, a / 10);
        if (b >= 3000 && a < 3300) mn = min(mn, max(a, 3000) - 3000);
        if (b >= 3300) mn = min(mn, max(a, 3300) - 3300);
        if (mn > smax) continue;

        // ---- QK^T: S[16q][64k] as 4 C-frags ----
        f32x4 sfr[4];
        #pragma unroll
        for (int f = 0; f < 4; f++) {
            int key = kbase + f * 16 + ll;
            int keyc = min(key, T_TOK - 1);
            const u16* krow = qkb + (size_t)keyc * 1024 + 512 + h * HD + lg * 8;
            bf16x8 kf0 = *reinterpret_cast<const bf16x8*>(krow);
            bf16x8 kf1 = *reinterpret_cast<const bf16x8*>(krow + 32);
            f32x4 acc = (f32x4){0.f, 0.f, 0.f, 0.f};
            acc = __builtin_amdgcn_mfma_f32_16x16x32_bf16(qf0, kf0, acc, 0, 0, 0);
            acc = __builtin_amdgcn_mfma_f32_16x16x32_bf16(qf1, kf1, acc, 0, 0, 0);
            sfr[f] = acc;
        }
        // ---- mask + scale + row max ----
        float rmax[4];
        #pragma unroll
        for (int r = 0; r < 4; r++) rmax[r] = -INFINITY;
        #pragma unroll
        for (int f = 0; f < 4; f++) {
            int key = kbase + f * 16 + ll;
            int sk = (key < T_TOK) ? step_of(key) : 0x7fffffff;
            #pragma unroll
            for (int r = 0; r < 4; r++) {
                float v = sfr[f][r] * 0.125f;
                v = (sk <= sq[r]) ? v : -INFINITY;   // select kills any OOB NaN
                sfr[f][r] = v;
                rmax[r] = fmaxf(rmax[r], v);
            }
        }
        #pragma unroll
        for (int r = 0; r < 4; r++) {
            float v = rmax[r];
            v = fmaxf(v, __shfl_xor(v, 1));
            v = fmaxf(v, __shfl_xor(v, 2));
            v = fmaxf(v, __shfl_xor(v, 4));
            v = fmaxf(v, __shfl_xor(v, 8));
            rmax[r] = v;
        }
        // ---- online softmax update ----
        float csc[4];
        #pragma unroll
        for (int r = 0; r < 4; r++) {
            float mn2 = fmaxf(m[r], rmax[r]);
            float c = (m[r] == -INFINITY) ? 0.f : __expf(m[r] - mn2);
            csc[r] = c;
            m[r] = mn2;
            lsum[r] *= c;
        }
        #pragma unroll
        for (int i = 0; i < 4; i++)
            #pragma unroll
            for (int r = 0; r < 4; r++) oacc[i][r] *= csc[r];
        // ---- P = exp(S - m) -> bf16 -> LDS (transpose to A-frag layout) ----
        #pragma unroll
        for (int f = 0; f < 4; f++) {
            #pragma unroll
            for (int r = 0; r < 4; r++) {
                float sv = sfr[f][r];
                float p = (sv == -INFINITY) ? 0.f : __expf(sv - m[r]);
                lsum[r] += p;
                plds[lg * 4 + r][f * 16 + ll] = f2bf(p);
            }
        }
        // same-wave LDS RAW: compiler inserts lgkmcnt wait
        // ---- PV: O += P * V ----
        #pragma unroll
        for (int kc = 0; kc < 2; kc++) {
            bf16x8 pf = *reinterpret_cast<const bf16x8*>(&plds[ll][kc * 32 + lg * 8]);
            #pragma unroll
            for (int i = 0; i < 4; i++) {
                const u16* vrow = vt + (size_t)(h * HD + i * 16 + ll) * VT_S + kbase + kc * 32 + lg * 8;
                bf16x8 vf = *reinterpret_cast<const bf16x8*>(vrow);
                oacc[i] = __builtin_amdgcn_mfma_f32_16x16x32_bf16(pf, vf, oacc[i], 0, 0, 0);
            }
        }
    }
    // final row-sum of lsum across the 16 col-lanes
    #pragma unroll
    for (int r = 0; r < 4; r++) {
        float v = lsum[r];
        v += __shfl_xor(v, 1);
        v += __shfl_xor(v, 2);
        v += __shfl_xor(v, 4);
        v += __shfl_xor(v, 8);
        lsum[r] = v;
    }
    #pragma unroll
    for (int r = 0; r < 4; r++) {
        int q = q0 + lg * 4 + r;
        if (q >= T_TOK) continue;
        float inv = (lsum[r] > 0.f) ? 1.f / lsum[r] : 0.f;
        float* op = ob + (size_t)q * D_ + h * HD;
        #pragma unroll
        for (int i = 0; i < 4; i++)
            op[i * 16 + ll] = oacc[i][r] * inv;
    }
}

// ---------------- fused residual add + LayerNorm ---------------------------
__global__ __launch_bounds__(256) void add_ln_kernel(
    float* __restrict__ x, const float* __restrict__ r,
    const float* __restrict__ g, const float* __restrict__ b)
{
    int row = blockIdx.x, t = threadIdx.x;
    size_t base = (size_t)row * D_;
    float v0 = x[base + t] + r[base + t];
    float v1 = x[base + t + 256] + r[base + t + 256];
    float s = v0 + v1, ss = v0 * v0 + v1 * v1;
    #pragma unroll
    for (int off = 32; off > 0; off >>= 1) {
        s  += __shfl_xor(s, off);
        ss += __shfl_xor(ss, off);
    }
    __shared__ float rs[4], rss[4];
    int w = t >> 6;
    if ((t & 63) == 0) { rs[w] = s; rss[w] = ss; }
    __syncthreads();
    s  = rs[0] + rs[1] + rs[2] + rs[3];
    ss = rss[0] + rss[1] + rss[2] + rss[3];
    float mean = s * (1.f / 512.f);
    float var = ss * (1.f / 512.f) - mean * mean;
    float rstd = rsqrtf(var + 1e-5f);
    x[base + t]       = (v0 - mean) * rstd * g[t]       + b[t];
    x[base + t + 256] = (v1 - mean) * rstd * g[t + 256] + b[t + 256];
}

// ---------------------------------------------------------------------------
extern "C" void kernel_launch(void* const* d_in, const int* in_sizes, int n_in,
                              void* d_out, int out_size, void* d_ws, size_t ws_size,
                              hipStream_t stream)
{
    const float* player_xs = (const float*)d_in[0];
    const float* player_ys = (const float*)d_in[1];
    const float* player_hs = (const float*)d_in[2];
    const float* ball_xs   = (const float*)d_in[3];
    const float* ball_ys   = (const float*)d_in[4];
    const float* ball_zs   = (const float*)d_in[5];
    const float* emb_table = (const float*)d_in[6];
    const float* ball_emb  = (const float*)d_in[7];
    const float* cls_emb   = (const float*)d_in[8];
    const float* pW0 = (const float*)d_in[9];   const float* pb0 = (const float*)d_in[10];
    const float* pW1 = (const float*)d_in[11];  const float* pb1 = (const float*)d_in[12];
    const float* pW2 = (const float*)d_in[13];  const float* pb2 = (const float*)d_in[14];
    const float* bW0 = (const float*)d_in[15];  const float* bb0 = (const float*)d_in[16];
    const float* bW1 = (const float*)d_in[17];  const float* bb1 = (const float*)d_in[18];
    const float* bW2 = (const float*)d_in[19];  const float* bb2 = (const float*)d_in[20];
    const float* Wqkv = (const float*)d_in[21]; const float* bqkv = (const float*)d_in[22];
    const float* Wo  = (const float*)d_in[23];  const float* bo  = (const float*)d_in[24];
    const float* W1f = (const float*)d_in[25];  const float* b1f = (const float*)d_in[26];
    const float* W2f = (const float*)d_in[27];  const float* b2f = (const float*)d_in[28];
    const float* g1  = (const float*)d_in[29];  const float* be1 = (const float*)d_in[30];
    const float* g2  = (const float*)d_in[31];  const float* be2 = (const float*)d_in[32];
    const float* cpW = (const float*)d_in[33];  const float* cpb = (const float*)d_in[34];
    const float* cbW = (const float*)d_in[35];  const float* cbb = (const float*)d_in[36];
    const float* csW = (const float*)d_in[37];  const float* csb = (const float*)d_in[38];
    const int* pidx = (const int*)d_in[39];

    // workspace (51.7 MB):
    //   x   : 3600*512 f32
    //   big : 3600*2048 f32 (qkv uses first 1536 cols; bf16 Q|K copy in the tail)
    //   ob  : 3600*512 f32
    //   tmp : 3600*512 f32 (Vt bf16 lives here during attention)
    float* x   = (float*)d_ws;
    float* big = x + 1843200;
    float* ob  = big + 7372800;
    float* tmp = ob + 1843200;
    u16* qkb = (u16*)(big + 3600 * 1536);  // 3600*1024 bf16 = 7.37MB (exact tail fit)
    u16* vt  = (u16*)tmp;                  // 512*3648 bf16 = 3.74MB
    float* out = (float*)d_out;

    token_kernel<<<3600, 256, 0, stream>>>(
        player_xs, player_ys, player_hs, ball_xs, ball_ys, ball_zs,
        emb_table, ball_emb, cls_emb,
        pW0, pb0, pW1, pb1, pW2, pb2,
        bW0, bb0, bW1, bb1, bW2, bb2, pidx, x);

    for (int l = 0; l < 4; l++) {
        const float* Wqkv_l = Wqkv + (size_t)l * 1536 * 512;
        const float* bqkv_l = bqkv + (size_t)l * 1536;
        const float* Wo_l   = Wo   + (size_t)l * 512 * 512;
        const float* bo_l   = bo   + (size_t)l * 512;
        const float* W1f_l  = W1f  + (size_t)l * 2048 * 512;
        const float* b1f_l  = b1f  + (size_t)l * 2048;
        const float* W2f_l  = W2f  + (size_t)l * 512 * 2048;
        const float* b2f_l  = b2f  + (size_t)l * 512;

        gemm_nt<0><<<dim3(57, 24), 256, 0, stream>>>(x, Wqkv_l, bqkv_l, big, 3600, 1536, 512);
        convert_kernel<<<57, 256, 0, stream>>>(big, qkb, vt);
        attn_mfma_kernel<<<dim3(57, 8), 256, 0, stream>>>(qkb, vt, ob);
        gemm_nt<0><<<dim3(57, 8),  256, 0, stream>>>(ob,  Wo_l,  bo_l,  tmp, 3600, 512,  512);
        add_ln_kernel<<<3600, 256, 0, stream>>>(x, tmp, g1 + (size_t)l * 512, be1 + (size_t)l * 512);
        gemm_nt<1><<<dim3(57, 32), 256, 0, stream>>>(x,   W1f_l, b1f_l, big, 3600, 2048, 512);
        gemm_nt<0><<<dim3(57, 8),  256, 0, stream>>>(big, W2f_l, b2f_l, tmp, 3600, 512,  2048);
        add_ln_kernel<<<3600, 256, 0, stream>>>(x, tmp, g2 + (size_t)l * 512, be2 + (size_t)l * 512);
    }

    gemm_nt<0><<<dim3(57, 2),  256, 0, stream>>>(x, cpW, cpb, out + 0,       3600, 121,  512);
    gemm_nt<0><<<dim3(57, 21), 256, 0, stream>>>(x, cbW, cbb, out + 435600,  3600, 1331, 512);
    gemm_nt<0><<<dim3(57, 1),  256, 0, stream>>>(x, csW, csb, out + 5227200, 3600, 10,   512);
}

// Round 5
// 1966.401 us; speedup vs baseline: 3.7494x; 1.4786x over previous
//
#include <hip/hip_runtime.h>
#include <hip/hip_bf16.h>

typedef unsigned short u16;
typedef __attribute__((ext_vector_type(8))) short bf16x8;
typedef __attribute__((ext_vector_type(4))) float f32x4;

#define T_TOK 3600
#define D_    512
#define H_    8
#define HD    64
#define FF_   2048
#define NKT   57    // ceil(3600/64)
#define VT_S  3648  // padded token stride for Vt (57*64)
#define SQRT512 22.627416997969522f

__device__ __forceinline__ u16 f2bf(float f) {
    unsigned int x = __float_as_uint(f);
    unsigned int lsb = (x >> 16) & 1;
    return (u16)((x + 0x7fffu + lsb) >> 16);
}
// timestep of token index: players [0,3000) step i/10, ball [3000,3300), cls [3300,3600)
__device__ __forceinline__ int step_of(int i) {
    return (i < 3000) ? (i / 10) : ((i < 3300) ? (i - 3000) : (i - 3300));
}

// ---------------- gather: build IN[3600][24] + fill cls rows of x ----------
__global__ __launch_bounds__(256) void gather_kernel(
    const float* __restrict__ pxs, const float* __restrict__ pys, const float* __restrict__ phs,
    const float* __restrict__ bxs, const float* __restrict__ bys, const float* __restrict__ bzs,
    const float* __restrict__ emb_table, const float* __restrict__ ball_emb,
    const float* __restrict__ cls_emb, const int* __restrict__ pidx,
    float* __restrict__ IN, float* __restrict__ x)
{
    int g = blockIdx.x * 256 + threadIdx.x;   // 15 blocks * 256 = 3840
    if (g < 3300) {
        float* row = IN + g * 24;
        if (g < 3000) {
            int id = pidx[g];
            #pragma unroll
            for (int e = 0; e < 20; e++) row[e] = emb_table[id * 20 + e];
            row[20] = pxs[g]; row[21] = pys[g]; row[22] = phs[g];
        } else {
            int b = g - 3000;
            #pragma unroll
            for (int e = 0; e < 20; e++) row[e] = ball_emb[e];
            row[20] = bxs[b]; row[21] = bys[b]; row[22] = bzs[b];
        }
        row[23] = 0.f;
    }
    // cls rows: x[3300..3600) = cls_emb (broadcast, not scaled)
    for (int i = g; i < 300 * 512; i += 3840) {
        x[3300 * 512 + i] = cls_emb[i & 511];
    }
}

// ---------------- MFMA GEMM: C[M,N] = (A[M,K(lda)] * W[N,K]^T + bias)*scale -
// fp32 inputs converted to bf16 during LDS staging.
// 128x128 tile, 4 waves (2x2), wave = 64x64 = 4x4 frags of 16x16x32.
__device__ __forceinline__ void stage_tile(
    const float* __restrict__ src, int nrows, int K, int lda,
    int r0, int kk, int srow, int scg, u16* dst)
{
    u16 tmp[16];
    int rr = r0 + srow;
    if (rr < nrows) {
        if (((lda & 3) == 0) && (kk + scg + 16 <= K)) {
            const float4* p = reinterpret_cast<const float4*>(src + (size_t)rr * lda + kk + scg);
            #pragma unroll
            for (int q = 0; q < 4; q++) {
                float4 v = p[q];
                tmp[q*4+0] = f2bf(v.x); tmp[q*4+1] = f2bf(v.y);
                tmp[q*4+2] = f2bf(v.z); tmp[q*4+3] = f2bf(v.w);
            }
        } else {
            #pragma unroll
            for (int e = 0; e < 16; e++) {
                int kc = kk + scg + e;
                tmp[e] = (kc < K) ? f2bf(src[(size_t)rr * lda + kc]) : (u16)0;
            }
        }
    } else {
        #pragma unroll
        for (int e = 0; e < 16; e++) tmp[e] = 0;
    }
    *reinterpret_cast<bf16x8*>(dst)     = *reinterpret_cast<const bf16x8*>(&tmp[0]);
    *reinterpret_cast<bf16x8*>(dst + 8) = *reinterpret_cast<const bf16x8*>(&tmp[8]);
}

template<int RELU>
__global__ __launch_bounds__(256) void gemm_mfma(
    const float* __restrict__ A, const float* __restrict__ W,
    const float* __restrict__ bias, float* __restrict__ C,
    int M, int N, int K, int lda, float scale)
{
    __shared__ u16 As[128][40];   // [m][k] pad->2-way max (free) on b128 reads
    __shared__ u16 Bs[128][40];   // [n][k]
    int t = threadIdx.x;
    int w = t >> 6, l = t & 63;
    int ll = l & 15, lg = l >> 4;
    int wr = w >> 1, wc = w & 1;
    int m0 = blockIdx.x * 128, n0 = blockIdx.y * 128;
    int srow = t >> 1;            // 0..127
    int scg  = (t & 1) * 16;      // 0 or 16

    f32x4 acc[4][4];
    #pragma unroll
    for (int i = 0; i < 4; i++)
        #pragma unroll
        for (int j = 0; j < 4; j++) acc[i][j] = (f32x4){0.f, 0.f, 0.f, 0.f};

    for (int kk = 0; kk < K; kk += 32) {
        stage_tile(A, M, K, lda, m0, kk, srow, scg, &As[srow][scg]);
        stage_tile(W, N, K, K,   n0, kk, srow, scg, &Bs[srow][scg]);
        __syncthreads();
        bf16x8 af[4], bf[4];
        #pragma unroll
        for (int i = 0; i < 4; i++)
            af[i] = *reinterpret_cast<const bf16x8*>(&As[wr*64 + i*16 + ll][lg*8]);
        #pragma unroll
        for (int j = 0; j < 4; j++)
            bf[j] = *reinterpret_cast<const bf16x8*>(&Bs[wc*64 + j*16 + ll][lg*8]);
        #pragma unroll
        for (int i = 0; i < 4; i++)
            #pragma unroll
            for (int j = 0; j < 4; j++)
                acc[i][j] = __builtin_amdgcn_mfma_f32_16x16x32_bf16(af[i], bf[j], acc[i][j], 0, 0, 0);
        __syncthreads();
    }

    float bv[4];
    #pragma unroll
    for (int j = 0; j < 4; j++) {
        int n = n0 + wc*64 + j*16 + ll;
        bv[j] = (n < N) ? bias[n] : 0.f;
    }
    #pragma unroll
    for (int i = 0; i < 4; i++) {
        #pragma unroll
        for (int r = 0; r < 4; r++) {
            int m = m0 + wr*64 + i*16 + lg*4 + r;
            if (m >= M) continue;
            #pragma unroll
            for (int j = 0; j < 4; j++) {
                int n = n0 + wc*64 + j*16 + ll;
                if (n >= N) continue;
                float v = acc[i][j][r] + bv[j];
                if (RELU) v = fmaxf(v, 0.f);
                C[(size_t)m * N + n] = v * scale;
            }
        }
    }
}

// ---------------- convert qkv fp32 -> bf16 Q|K and transposed V -------------
__global__ __launch_bounds__(256) void convert_kernel(
    const float* __restrict__ qkv, u16* __restrict__ qkb, u16* __restrict__ vt)
{
    __shared__ u16 tile[64][66];
    int t = threadIdx.x;
    int tok0 = blockIdx.x * 64;
    for (int j = 0; j < 64; j++) {
        int tok = tok0 + j;
        if (tok < T_TOK) {
            float4 v = *reinterpret_cast<const float4*>(qkv + (size_t)tok * 1536 + t * 4);
            ushort4 o;
            o.x = f2bf(v.x); o.y = f2bf(v.y); o.z = f2bf(v.z); o.w = f2bf(v.w);
            *reinterpret_cast<ushort4*>(qkb + (size_t)tok * 1024 + t * 4) = o;
        }
    }
    for (int h = 0; h < H_; h++) {
        __syncthreads();
        #pragma unroll
        for (int j = 0; j < 4; j++) {
            int idx4 = t + j * 256;
            int i = idx4 >> 4;
            int c4 = idx4 & 15;
            int tok = tok0 + i;
            float4 v = make_float4(0.f, 0.f, 0.f, 0.f);
            if (tok < T_TOK)
                v = *reinterpret_cast<const float4*>(qkv + (size_t)tok * 1536 + 1024 + h * HD + c4 * 4);
            tile[i][c4*4+0] = f2bf(v.x); tile[i][c4*4+1] = f2bf(v.y);
            tile[i][c4*4+2] = f2bf(v.z); tile[i][c4*4+3] = f2bf(v.w);
        }
        __syncthreads();
        int d = t >> 2;
        int i0 = (t & 3) * 16;
        u16 tt[16];
        #pragma unroll
        for (int i = 0; i < 16; i++) tt[i] = tile[i0 + i][d];
        ushort4* dst = reinterpret_cast<ushort4*>(vt + (size_t)(h * HD + d) * VT_S + tok0 + i0);
        dst[0] = make_ushort4(tt[0],  tt[1],  tt[2],  tt[3]);
        dst[1] = make_ushort4(tt[4],  tt[5],  tt[6],  tt[7]);
        dst[2] = make_ushort4(tt[8],  tt[9],  tt[10], tt[11]);
        dst[3] = make_ushort4(tt[12], tt[13], tt[14], tt[15]);
    }
}

// ---------------- MFMA flash attention (bf16 in, fp32 out) -----------------
__global__ __launch_bounds__(256) void attn_mfma_kernel(
    const u16* __restrict__ qkb, const u16* __restrict__ vt, float* __restrict__ ob)
{
    __shared__ u16 plds_all[4][16][80];
    int t = threadIdx.x;
    int w = t >> 6, l = t & 63;
    int lg = l >> 4, ll = l & 15;
    u16 (*plds)[80] = plds_all[w];
    int h = blockIdx.y;
    int q0 = blockIdx.x * 64 + w * 16;

    int qa = q0 + ll;
    int qac = min(qa, T_TOK - 1);
    const u16* qrow = qkb + (size_t)qac * 1024 + h * HD + lg * 8;
    bf16x8 qf0 = *reinterpret_cast<const bf16x8*>(qrow);
    bf16x8 qf1 = *reinterpret_cast<const bf16x8*>(qrow + 32);

    int sq[4];
    #pragma unroll
    for (int r = 0; r < 4; r++) {
        int qq = q0 + lg * 4 + r;
        sq[r] = (qq < T_TOK) ? step_of(qq) : -1;
    }
    int sqa = (qa < T_TOK) ? step_of(qa) : -1;
    int smax = sqa;
    #pragma unroll
    for (int off = 1; off < 16; off <<= 1) smax = max(smax, __shfl_xor(smax, off));

    f32x4 oacc[4];
    #pragma unroll
    for (int i = 0; i < 4; i++) oacc[i] = (f32x4){0.f, 0.f, 0.f, 0.f};
    float m[4], lsum[4];
    #pragma unroll
    for (int r = 0; r < 4; r++) { m[r] = -INFINITY; lsum[r] = 0.f; }

    #pragma unroll 1
    for (int kt = 0; kt < NKT; kt++) {
        int kbase = kt * 64;
        int a = kbase, b = min(kbase + 63, T_TOK - 1);
        int mn = 0x7fffffff;
        if (a < 3000) mn = min(mn, a / 10);
        if (b >= 3000 && a < 3300) mn = min(mn, max(a, 3000) - 3000);
        if (b >= 3300) mn = min(mn, max(a, 3300) - 3300);
        if (mn > smax) continue;

        f32x4 sfr[4];
        #pragma unroll
        for (int f = 0; f < 4; f++) {
            int key = kbase + f * 16 + ll;
            int keyc = min(key, T_TOK - 1);
            const u16* krow = qkb + (size_t)keyc * 1024 + 512 + h * HD + lg * 8;
            bf16x8 kf0 = *reinterpret_cast<const bf16x8*>(krow);
            bf16x8 kf1 = *reinterpret_cast<const bf16x8*>(krow + 32);
            f32x4 acc = (f32x4){0.f, 0.f, 0.f, 0.f};
            acc = __builtin_amdgcn_mfma_f32_16x16x32_bf16(qf0, kf0, acc, 0, 0, 0);
            acc = __builtin_amdgcn_mfma_f32_16x16x32_bf16(qf1, kf1, acc, 0, 0, 0);
            sfr[f] = acc;
        }
        float rmax[4];
        #pragma unroll
        for (int r = 0; r < 4; r++) rmax[r] = -INFINITY;
        #pragma unroll
        for (int f = 0; f < 4; f++) {
            int key = kbase + f * 16 + ll;
            int sk = (key < T_TOK) ? step_of(key) : 0x7fffffff;
            #pragma unroll
            for (int r = 0; r < 4; r++) {
                float v = sfr[f][r] * 0.125f;
                v = (sk <= sq[r]) ? v : -INFINITY;
                sfr[f][r] = v;
                rmax[r] = fmaxf(rmax[r], v);
            }
        }
        #pragma unroll
        for (int r = 0; r < 4; r++) {
            float v = rmax[r];
            v = fmaxf(v, __shfl_xor(v, 1));
            v = fmaxf(v, __shfl_xor(v, 2));
            v = fmaxf(v, __shfl_xor(v, 4));
            v = fmaxf(v, __shfl_xor(v, 8));
            rmax[r] = v;
        }
        float csc[4];
        #pragma unroll
        for (int r = 0; r < 4; r++) {
            float mn2 = fmaxf(m[r], rmax[r]);
            float c = (m[r] == -INFINITY) ? 0.f : __expf(m[r] - mn2);
            csc[r] = c;
            m[r] = mn2;
            lsum[r] *= c;
        }
        #pragma unroll
        for (int i = 0; i < 4; i++)
            #pragma unroll
            for (int r = 0; r < 4; r++) oacc[i][r] *= csc[r];
        #pragma unroll
        for (int f = 0; f < 4; f++) {
            #pragma unroll
            for (int r = 0; r < 4; r++) {
                float sv = sfr[f][r];
                float p = (sv == -INFINITY) ? 0.f : __expf(sv - m[r]);
                lsum[r] += p;
                plds[lg * 4 + r][f * 16 + ll] = f2bf(p);
            }
        }
        #pragma unroll
        for (int kc = 0; kc < 2; kc++) {
            bf16x8 pf = *reinterpret_cast<const bf16x8*>(&plds[ll][kc * 32 + lg * 8]);
            #pragma unroll
            for (int i = 0; i < 4; i++) {
                const u16* vrow = vt + (size_t)(h * HD + i * 16 + ll) * VT_S + kbase + kc * 32 + lg * 8;
                bf16x8 vf = *reinterpret_cast<const bf16x8*>(vrow);
                oacc[i] = __builtin_amdgcn_mfma_f32_16x16x32_bf16(pf, vf, oacc[i], 0, 0, 0);
            }
        }
    }
    #pragma unroll
    for (int r = 0; r < 4; r++) {
        float v = lsum[r];
        v += __shfl_xor(v, 1);
        v += __shfl_xor(v, 2);
        v += __shfl_xor(v, 4);
        v += __shfl_xor(v, 8);
        lsum[r] = v;
    }
    #pragma unroll
    for (int r = 0; r < 4; r++) {
        int q = q0 + lg * 4 + r;
        if (q >= T_TOK) continue;
        float inv = (lsum[r] > 0.f) ? 1.f / lsum[r] : 0.f;
        float* op = ob + (size_t)q * D_ + h * HD;
        #pragma unroll
        for (int i = 0; i < 4; i++)
            op[i * 16 + ll] = oacc[i][r] * inv;
    }
}

// ---------------- fused residual add + LayerNorm ---------------------------
__global__ __launch_bounds__(256) void add_ln_kernel(
    float* __restrict__ x, const float* __restrict__ r,
    const float* __restrict__ g, const float* __restrict__ b)
{
    int row = blockIdx.x, t = threadIdx.x;
    size_t base = (size_t)row * D_;
    float v0 = x[base + t] + r[base + t];
    float v1 = x[base + t + 256] + r[base + t + 256];
    float s = v0 + v1, ss = v0 * v0 + v1 * v1;
    #pragma unroll
    for (int off = 32; off > 0; off >>= 1) {
        s  += __shfl_xor(s, off);
        ss += __shfl_xor(ss, off);
    }
    __shared__ float rs[4], rss[4];
    int w = t >> 6;
    if ((t & 63) == 0) { rs[w] = s; rss[w] = ss; }
    __syncthreads();
    s  = rs[0] + rs[1] + rs[2] + rs[3];
    ss = rss[0] + rss[1] + rss[2] + rss[3];
    float mean = s * (1.f / 512.f);
    float var = ss * (1.f / 512.f) - mean * mean;
    float rstd = rsqrtf(var + 1e-5f);
    x[base + t]       = (v0 - mean) * rstd * g[t]       + b[t];
    x[base + t + 256] = (v1 - mean) * rstd * g[t + 256] + b[t + 256];
}

// ---------------------------------------------------------------------------
extern "C" void kernel_launch(void* const* d_in, const int* in_sizes, int n_in,
                              void* d_out, int out_size, void* d_ws, size_t ws_size,
                              hipStream_t stream)
{
    const float* player_xs = (const float*)d_in[0];
    const float* player_ys = (const float*)d_in[1];
    const float* player_hs = (const float*)d_in[2];
    const float* ball_xs   = (const float*)d_in[3];
    const float* ball_ys   = (const float*)d_in[4];
    const float* ball_zs   = (const float*)d_in[5];
    const float* emb_table = (const float*)d_in[6];
    const float* ball_emb  = (const float*)d_in[7];
    const float* cls_emb   = (const float*)d_in[8];
    const float* pW0 = (const float*)d_in[9];   const float* pb0 = (const float*)d_in[10];
    const float* pW1 = (const float*)d_in[11];  const float* pb1 = (const float*)d_in[12];
    const float* pW2 = (const float*)d_in[13];  const float* pb2 = (const float*)d_in[14];
    const float* bW0 = (const float*)d_in[15];  const float* bb0 = (const float*)d_in[16];
    const float* bW1 = (const float*)d_in[17];  const float* bb1 = (const float*)d_in[18];
    const float* bW2 = (const float*)d_in[19];  const float* bb2 = (const float*)d_in[20];
    const float* Wqkv = (const float*)d_in[21]; const float* bqkv = (const float*)d_in[22];
    const float* Wo  = (const float*)d_in[23];  const float* bo  = (const float*)d_in[24];
    const float* W1f = (const float*)d_in[25];  const float* b1f = (const float*)d_in[26];
    const float* W2f = (const float*)d_in[27];  const float* b2f = (const float*)d_in[28];
    const float* g1  = (const float*)d_in[29];  const float* be1 = (const float*)d_in[30];
    const float* g2  = (const float*)d_in[31];  const float* be2 = (const float*)d_in[32];
    const float* cpW = (const float*)d_in[33];  const float* cpb = (const float*)d_in[34];
    const float* cbW = (const float*)d_in[35];  const float* cbb = (const float*)d_in[36];
    const float* csW = (const float*)d_in[37];  const float* csb = (const float*)d_in[38];
    const int* pidx = (const int*)d_in[39];

    float* x    = (float*)d_ws;            // 3600*512
    float* big  = x + 1843200;             // 3600*2048
    float* ob   = big + 7372800;           // 3600*512
    float* tmp2 = ob + 1843200;            // 3600*512
    u16* qkb = (u16*)(big + 3600 * 1536);  // bf16 Q|K (tail of big; dead when FF1 writes)
    u16* vt  = (u16*)tmp2;                 // bf16 Vt (dead when Wo writes tmp2)
    // token-MLP temporaries live in big (free until qkv GEMM)
    float* IN = big;                       // 3600*24
    float* h0 = big + 131072;              // 3600*128
    float* h1 = big + 131072 + 460800;     // 3600*256
    float* out = (float*)d_out;

    gather_kernel<<<15, 256, 0, stream>>>(
        player_xs, player_ys, player_hs, ball_xs, ball_ys, ball_zs,
        emb_table, ball_emb, cls_emb, pidx, IN, x);

    // token MLPs as MFMA GEMMs (players rows 0..2999, balls 3000..3299)
    gemm_mfma<1><<<dim3(24, 1), 256, 0, stream>>>(IN,            pW0, pb0, h0,            3000, 128, 23, 24, 1.f);
    gemm_mfma<1><<<dim3(3,  1), 256, 0, stream>>>(IN + 3000*24,  bW0, bb0, h0 + 3000*128,  300, 128, 23, 24, 1.f);
    gemm_mfma<1><<<dim3(24, 2), 256, 0, stream>>>(h0,            pW1, pb1, h1,            3000, 256, 128, 128, 1.f);
    gemm_mfma<1><<<dim3(3,  2), 256, 0, stream>>>(h0 + 3000*128, bW1, bb1, h1 + 3000*256,  300, 256, 128, 128, 1.f);
    gemm_mfma<0><<<dim3(24, 4), 256, 0, stream>>>(h1,            pW2, pb2, x,             3000, 512, 256, 256, SQRT512);
    gemm_mfma<0><<<dim3(3,  4), 256, 0, stream>>>(h1 + 3000*256, bW2, bb2, x + 3000*512,   300, 512, 256, 256, SQRT512);

    for (int l = 0; l < 4; l++) {
        const float* Wqkv_l = Wqkv + (size_t)l * 1536 * 512;
        const float* bqkv_l = bqkv + (size_t)l * 1536;
        const float* Wo_l   = Wo   + (size_t)l * 512 * 512;
        const float* bo_l   = bo   + (size_t)l * 512;
        const float* W1f_l  = W1f  + (size_t)l * 2048 * 512;
        const float* b1f_l  = b1f  + (size_t)l * 2048;
        const float* W2f_l  = W2f  + (size_t)l * 512 * 2048;
        const float* b2f_l  = b2f  + (size_t)l * 512;

        gemm_mfma<0><<<dim3(29, 12), 256, 0, stream>>>(x, Wqkv_l, bqkv_l, big, 3600, 1536, 512, 512, 1.f);
        convert_kernel<<<57, 256, 0, stream>>>(big, qkb, vt);
        attn_mfma_kernel<<<dim3(57, 8), 256, 0, stream>>>(qkb, vt, ob);
        gemm_mfma<0><<<dim3(29, 4), 256, 0, stream>>>(ob, Wo_l, bo_l, tmp2, 3600, 512, 512, 512, 1.f);
        add_ln_kernel<<<3600, 256, 0, stream>>>(x, tmp2, g1 + (size_t)l * 512, be1 + (size_t)l * 512);
        gemm_mfma<1><<<dim3(29, 16), 256, 0, stream>>>(x, W1f_l, b1f_l, big, 3600, 2048, 512, 512, 1.f);
        gemm_mfma<0><<<dim3(29, 4), 256, 0, stream>>>(big, W2f_l, b2f_l, tmp2, 3600, 512, 2048, 2048, 1.f);
        add_ln_kernel<<<3600, 256, 0, stream>>>(x, tmp2, g2 + (size_t)l * 512, be2 + (size_t)l * 512);
    }

    gemm_mfma<0><<<dim3(29, 1),  256, 0, stream>>>(x, cpW, cpb, out + 0,       3600, 121,  512, 512, 1.f);
    gemm_mfma<0><<<dim3(29, 11), 256, 0, stream>>>(x, cbW, cbb, out + 435600,  3600, 1331, 512, 512, 1.f);
    gemm_mfma<0><<<dim3(29, 1),  256, 0, stream>>>(x, csW, csb, out + 5227200, 3600, 10,   512, 512, 1.f);
}

// Round 6
// 1593.683 us; speedup vs baseline: 4.6262x; 1.2339x over previous
//
#include <hip/hip_runtime.h>
#include <hip/hip_bf16.h>

typedef unsigned short u16;
typedef __attribute__((ext_vector_type(8))) short bf16x8;
typedef __attribute__((ext_vector_type(4))) float f32x4;

#define T_TOK 3600
#define D_    512
#define H_    8
#define HD    64
#define NKT   57    // ceil(3600/64)
#define VT_S  3648  // padded token stride for Vt
#define KSPLIT 3
#define SQRT512 22.627416997969522f

__device__ __forceinline__ u16 f2bf(float f) {
    unsigned int x = __float_as_uint(f);
    unsigned int lsb = (x >> 16) & 1;
    return (u16)((x + 0x7fffu + lsb) >> 16);
}
__device__ __forceinline__ float bf2f(u16 u) {
    return __uint_as_float(((unsigned int)u) << 16);
}
// timestep of token: players [0,3000) -> i/10, ball [3000,3300), cls [3300,3600)
__device__ __forceinline__ int step_of(int i) {
    return (i < 3000) ? (i / 10) : ((i < 3300) ? (i - 3000) : (i - 3300));
}

// ---------------- gather: build IN[3600][24] + fill cls rows of x ----------
__global__ __launch_bounds__(256) void gather_kernel(
    const float* __restrict__ pxs, const float* __restrict__ pys, const float* __restrict__ phs,
    const float* __restrict__ bxs, const float* __restrict__ bys, const float* __restrict__ bzs,
    const float* __restrict__ emb_table, const float* __restrict__ ball_emb,
    const float* __restrict__ cls_emb, const int* __restrict__ pidx,
    float* __restrict__ IN, float* __restrict__ x)
{
    int g = blockIdx.x * 256 + threadIdx.x;   // 15*256 = 3840
    if (g < 3300) {
        float* row = IN + g * 24;
        if (g < 3000) {
            int id = pidx[g];
            #pragma unroll
            for (int e = 0; e < 20; e++) row[e] = emb_table[id * 20 + e];
            row[20] = pxs[g]; row[21] = pys[g]; row[22] = phs[g];
        } else {
            int b = g - 3000;
            #pragma unroll
            for (int e = 0; e < 20; e++) row[e] = ball_emb[e];
            row[20] = bxs[b]; row[21] = bys[b]; row[22] = bzs[b];
        }
        row[23] = 0.f;
    }
    for (int i = g; i < 300 * 512; i += 3840) {
        x[3300 * 512 + i] = cls_emb[i & 511];
    }
}

// ---------------- MFMA GEMM ------------------------------------------------
// C[M,N] = act(A[M,K] * W[N,K]^T + bias) * scale.  A fp32 or bf16; C fp32 or bf16.
__device__ __forceinline__ void stage_f32(
    const float* __restrict__ src, int nrows, int K, int lda,
    int r0, int kk, int srow, int scg, u16* dst)
{
    u16 tmp[16];
    int rr = r0 + srow;
    if (rr < nrows) {
        if (((lda & 3) == 0) && (kk + scg + 16 <= K)) {
            const float4* p = reinterpret_cast<const float4*>(src + (size_t)rr * lda + kk + scg);
            #pragma unroll
            for (int q = 0; q < 4; q++) {
                float4 v = p[q];
                tmp[q*4+0] = f2bf(v.x); tmp[q*4+1] = f2bf(v.y);
                tmp[q*4+2] = f2bf(v.z); tmp[q*4+3] = f2bf(v.w);
            }
        } else {
            #pragma unroll
            for (int e = 0; e < 16; e++) {
                int kc = kk + scg + e;
                tmp[e] = (kc < K) ? f2bf(src[(size_t)rr * lda + kc]) : (u16)0;
            }
        }
    } else {
        #pragma unroll
        for (int e = 0; e < 16; e++) tmp[e] = 0;
    }
    *reinterpret_cast<bf16x8*>(dst)     = *reinterpret_cast<const bf16x8*>(&tmp[0]);
    *reinterpret_cast<bf16x8*>(dst + 8) = *reinterpret_cast<const bf16x8*>(&tmp[8]);
}

__device__ __forceinline__ void stage_b16(
    const u16* __restrict__ src, int nrows, int lda,
    int r0, int kk, int srow, int scg, u16* dst)
{
    int rr = r0 + srow;
    bf16x8 a = {}, b = {};
    if (rr < nrows) {
        const bf16x8* p = reinterpret_cast<const bf16x8*>(src + (size_t)rr * lda + kk + scg);
        a = p[0]; b = p[1];
    }
    *reinterpret_cast<bf16x8*>(dst)     = a;
    *reinterpret_cast<bf16x8*>(dst + 8) = b;
}

template<int RELU, int BF16OUT, int ABF16>
__global__ __launch_bounds__(256) void gemm_mfma(
    const void* __restrict__ Av, const float* __restrict__ W,
    const float* __restrict__ bias, void* __restrict__ Cv,
    int M, int N, int K, int lda, float scale)
{
    __shared__ u16 As[128][40];
    __shared__ u16 Bs[128][40];
    int t = threadIdx.x;
    int w = t >> 6, l = t & 63;
    int ll = l & 15, lg = l >> 4;
    int wr = w >> 1, wc = w & 1;
    int m0 = blockIdx.x * 128, n0 = blockIdx.y * 128;
    int srow = t >> 1;
    int scg  = (t & 1) * 16;

    f32x4 acc[4][4];
    #pragma unroll
    for (int i = 0; i < 4; i++)
        #pragma unroll
        for (int j = 0; j < 4; j++) acc[i][j] = (f32x4){0.f, 0.f, 0.f, 0.f};

    for (int kk = 0; kk < K; kk += 32) {
        if (ABF16) stage_b16((const u16*)Av, M, lda, m0, kk, srow, scg, &As[srow][scg]);
        else       stage_f32((const float*)Av, M, K, lda, m0, kk, srow, scg, &As[srow][scg]);
        stage_f32(W, N, K, K, n0, kk, srow, scg, &Bs[srow][scg]);
        __syncthreads();
        bf16x8 af[4], bf[4];
        #pragma unroll
        for (int i = 0; i < 4; i++)
            af[i] = *reinterpret_cast<const bf16x8*>(&As[wr*64 + i*16 + ll][lg*8]);
        #pragma unroll
        for (int j = 0; j < 4; j++)
            bf[j] = *reinterpret_cast<const bf16x8*>(&Bs[wc*64 + j*16 + ll][lg*8]);
        #pragma unroll
        for (int i = 0; i < 4; i++)
            #pragma unroll
            for (int j = 0; j < 4; j++)
                acc[i][j] = __builtin_amdgcn_mfma_f32_16x16x32_bf16(af[i], bf[j], acc[i][j], 0, 0, 0);
        __syncthreads();
    }

    float bv[4];
    #pragma unroll
    for (int j = 0; j < 4; j++) {
        int n = n0 + wc*64 + j*16 + ll;
        bv[j] = (n < N) ? bias[n] : 0.f;
    }
    #pragma unroll
    for (int i = 0; i < 4; i++) {
        #pragma unroll
        for (int r = 0; r < 4; r++) {
            int m = m0 + wr*64 + i*16 + lg*4 + r;
            if (m >= M) continue;
            #pragma unroll
            for (int j = 0; j < 4; j++) {
                int n = n0 + wc*64 + j*16 + ll;
                if (n >= N) continue;
                float v = acc[i][j][r] + bv[j];
                if (RELU) v = fmaxf(v, 0.f);
                v *= scale;
                if (BF16OUT) ((u16*)Cv)[(size_t)m * N + n] = f2bf(v);
                else         ((float*)Cv)[(size_t)m * N + n] = v;
            }
        }
    }
}

// ---------------- V transpose: vt[h*64+d][tok] = qkvb[tok][1024+h*64+d] ----
__global__ __launch_bounds__(256) void vtrans_kernel(
    const u16* __restrict__ qkvb, u16* __restrict__ vt)
{
    __shared__ u16 tile[64][72];
    int t = threadIdx.x;
    int tok0 = blockIdx.x * 64;
    int h = blockIdx.y;
    {
        int i = t >> 2, c16 = (t & 3) * 16;
        int tok = tok0 + i;
        bf16x8 a = {}, b = {};
        if (tok < T_TOK) {
            const bf16x8* p = reinterpret_cast<const bf16x8*>(qkvb + (size_t)tok * 1536 + 1024 + h * HD + c16);
            a = p[0]; b = p[1];
        }
        *reinterpret_cast<bf16x8*>(&tile[i][c16])     = a;
        *reinterpret_cast<bf16x8*>(&tile[i][c16 + 8]) = b;
    }
    __syncthreads();
    {
        int d = t >> 2, i0 = (t & 3) * 16;
        u16 tt[16];
        #pragma unroll
        for (int e = 0; e < 16; e++) tt[e] = tile[i0 + e][d];
        u16* dst = vt + (size_t)(h * HD + d) * VT_S + tok0 + i0;
        *reinterpret_cast<bf16x8*>(dst)     = *reinterpret_cast<const bf16x8*>(&tt[0]);
        *reinterpret_cast<bf16x8*>(dst + 8) = *reinterpret_cast<const bf16x8*>(&tt[8]);
    }
}

// ---------------- MFMA flash attention, key-split over blockIdx.z ----------
// grid (57, 8, 3); block 256 = 4 waves; wave owns 16 queries.
// Writes UNNORMALIZED partials: Opart bf16 [z][h][3600][64], mlpart f32 [z][h][3600][2].
__global__ __launch_bounds__(256) void attn_mfma_kernel(
    const u16* __restrict__ qkvb, const u16* __restrict__ vt,
    u16* __restrict__ Opart, float* __restrict__ mlpart)
{
    __shared__ u16 plds_all[4][16][80];
    int t = threadIdx.x;
    int w = t >> 6, l = t & 63;
    int lg = l >> 4, ll = l & 15;
    u16 (*plds)[80] = plds_all[w];
    int h = blockIdx.y;
    int z = blockIdx.z;
    int q0 = blockIdx.x * 64 + w * 16;

    int qa = q0 + ll;
    int qac = min(qa, T_TOK - 1);
    const u16* qrow = qkvb + (size_t)qac * 1536 + h * HD + lg * 8;
    bf16x8 qf0 = *reinterpret_cast<const bf16x8*>(qrow);
    bf16x8 qf1 = *reinterpret_cast<const bf16x8*>(qrow + 32);

    int sq[4];
    #pragma unroll
    for (int r = 0; r < 4; r++) {
        int qq = q0 + lg * 4 + r;
        sq[r] = (qq < T_TOK) ? step_of(qq) : -1;
    }
    int sqa = (qa < T_TOK) ? step_of(qa) : -1;
    int smax = sqa;
    #pragma unroll
    for (int off = 1; off < 16; off <<= 1) smax = max(smax, __shfl_xor(smax, off));

    f32x4 oacc[4];
    #pragma unroll
    for (int i = 0; i < 4; i++) oacc[i] = (f32x4){0.f, 0.f, 0.f, 0.f};
    float m[4], lsum[4];
    #pragma unroll
    for (int r = 0; r < 4; r++) { m[r] = -INFINITY; lsum[r] = 0.f; }

    #pragma unroll 1
    for (int kt = z; kt < NKT; kt += KSPLIT) {
        int kbase = kt * 64;
        int a = kbase, b = min(kbase + 63, T_TOK - 1);
        int mn = 0x7fffffff;
        if (a < 3000) mn = min(mn, a / 10);
        if (b >= 3000 && a < 3300) mn = min(mn, max(a, 3000) - 3000);
        if (b >= 3300) mn = min(mn, max(a, 3300) - 3300);
        if (mn > smax) continue;

        // ---- V preload (independent of QK; latency hides under softmax) ----
        bf16x8 vf0[4], vf1[4];
        #pragma unroll
        for (int i = 0; i < 4; i++) {
            const u16* vr = vt + (size_t)(h * HD + i * 16 + ll) * VT_S + kbase + lg * 8;
            vf0[i] = *reinterpret_cast<const bf16x8*>(vr);
            vf1[i] = *reinterpret_cast<const bf16x8*>(vr + 32);
        }

        // ---- QK^T ----
        f32x4 sfr[4];
        __builtin_amdgcn_s_setprio(1);
        #pragma unroll
        for (int f = 0; f < 4; f++) {
            int key = kbase + f * 16 + ll;
            int keyc = min(key, T_TOK - 1);
            const u16* krow = qkvb + (size_t)keyc * 1536 + 512 + h * HD + lg * 8;
            bf16x8 kf0 = *reinterpret_cast<const bf16x8*>(krow);
            bf16x8 kf1 = *reinterpret_cast<const bf16x8*>(krow + 32);
            f32x4 acc = (f32x4){0.f, 0.f, 0.f, 0.f};
            acc = __builtin_amdgcn_mfma_f32_16x16x32_bf16(qf0, kf0, acc, 0, 0, 0);
            acc = __builtin_amdgcn_mfma_f32_16x16x32_bf16(qf1, kf1, acc, 0, 0, 0);
            sfr[f] = acc;
        }
        __builtin_amdgcn_s_setprio(0);

        // ---- mask + scale + row max ----
        float rmax[4];
        #pragma unroll
        for (int r = 0; r < 4; r++) rmax[r] = -INFINITY;
        #pragma unroll
        for (int f = 0; f < 4; f++) {
            int key = kbase + f * 16 + ll;
            int sk = (key < T_TOK) ? step_of(key) : 0x7fffffff;
            #pragma unroll
            for (int r = 0; r < 4; r++) {
                float v = sfr[f][r] * 0.125f;
                v = (sk <= sq[r]) ? v : -INFINITY;
                sfr[f][r] = v;
                rmax[r] = fmaxf(rmax[r], v);
            }
        }
        #pragma unroll
        for (int r = 0; r < 4; r++) {
            float v = rmax[r];
            v = fmaxf(v, __shfl_xor(v, 1));
            v = fmaxf(v, __shfl_xor(v, 2));
            v = fmaxf(v, __shfl_xor(v, 4));
            v = fmaxf(v, __shfl_xor(v, 8));
            rmax[r] = v;
        }
        // ---- defer-max: rescale only when some row grew past THR=8 ----
        bool upd = false;
        #pragma unroll
        for (int r = 0; r < 4; r++) upd = upd || (rmax[r] > m[r] + 8.f);
        if (__any(upd)) {
            float csc[4];
            #pragma unroll
            for (int r = 0; r < 4; r++) {
                float mn2 = fmaxf(m[r], rmax[r]);
                float c = (m[r] == -INFINITY) ? 0.f : __expf(m[r] - mn2);
                csc[r] = c;
                m[r] = mn2;
                lsum[r] *= c;
            }
            #pragma unroll
            for (int i = 0; i < 4; i++)
                #pragma unroll
                for (int r = 0; r < 4; r++) oacc[i][r] *= csc[r];
        }
        // ---- P = exp(S - m) -> bf16 -> LDS (A-frag layout) ----
        #pragma unroll
        for (int f = 0; f < 4; f++) {
            #pragma unroll
            for (int r = 0; r < 4; r++) {
                float sv = sfr[f][r];
                float p = (sv == -INFINITY) ? 0.f : __expf(sv - m[r]);
                lsum[r] += p;
                plds[lg * 4 + r][f * 16 + ll] = f2bf(p);
            }
        }
        // ---- PV ----
        __builtin_amdgcn_s_setprio(1);
        {
            bf16x8 pf0 = *reinterpret_cast<const bf16x8*>(&plds[ll][lg * 8]);
            #pragma unroll
            for (int i = 0; i < 4; i++)
                oacc[i] = __builtin_amdgcn_mfma_f32_16x16x32_bf16(pf0, vf0[i], oacc[i], 0, 0, 0);
            bf16x8 pf1 = *reinterpret_cast<const bf16x8*>(&plds[ll][32 + lg * 8]);
            #pragma unroll
            for (int i = 0; i < 4; i++)
                oacc[i] = __builtin_amdgcn_mfma_f32_16x16x32_bf16(pf1, vf1[i], oacc[i], 0, 0, 0);
        }
        __builtin_amdgcn_s_setprio(0);
    }

    // row-sum lsum across 16 col-lanes
    #pragma unroll
    for (int r = 0; r < 4; r++) {
        float v = lsum[r];
        v += __shfl_xor(v, 1);
        v += __shfl_xor(v, 2);
        v += __shfl_xor(v, 4);
        v += __shfl_xor(v, 8);
        lsum[r] = v;
    }
    // write partials (unnormalized)
    #pragma unroll
    for (int r = 0; r < 4; r++) {
        int q = q0 + lg * 4 + r;
        if (q >= T_TOK) continue;
        size_t ob = ((size_t)(z * 8 + h) * 3600 + q) * 64;
        #pragma unroll
        for (int i = 0; i < 4; i++)
            Opart[ob + i * 16 + ll] = f2bf(oacc[i][r]);
        if (ll == 0) {
            size_t mi = ((size_t)(z * 8 + h) * 3600 + q) * 2;
            mlpart[mi]     = m[r];
            mlpart[mi + 1] = lsum[r];
        }
    }
}

// ---------------- merge KSPLIT partials -> ob ------------------------------
__global__ __launch_bounds__(256) void attn_merge_kernel(
    const u16* __restrict__ Opart, const float* __restrict__ mlpart,
    float* __restrict__ ob)
{
    int t = threadIdx.x;
    int h = blockIdx.y;
    int q = blockIdx.x * 64 + (t >> 2);
    if (q >= T_TOK) return;
    int dg = (t & 3) * 16;
    float mz[KSPLIT], lz[KSPLIT];
    #pragma unroll
    for (int zz = 0; zz < KSPLIT; zz++) {
        size_t mi = ((size_t)(zz * 8 + h) * 3600 + q) * 2;
        mz[zz] = mlpart[mi];
        lz[zz] = mlpart[mi + 1];
    }
    float M = -INFINITY;
    #pragma unroll
    for (int zz = 0; zz < KSPLIT; zz++) if (lz[zz] > 0.f) M = fmaxf(M, mz[zz]);
    float wz[KSPLIT], den = 0.f;
    #pragma unroll
    for (int zz = 0; zz < KSPLIT; zz++) {
        wz[zz] = (lz[zz] > 0.f) ? __expf(mz[zz] - M) : 0.f;
        den += wz[zz] * lz[zz];
    }
    float inv = (den > 0.f) ? 1.f / den : 0.f;
    float* op = ob + (size_t)q * D_ + h * HD + dg;
    #pragma unroll
    for (int e = 0; e < 16; e++) {
        float o = 0.f;
        #pragma unroll
        for (int zz = 0; zz < KSPLIT; zz++)
            o += bf2f(Opart[((size_t)(zz * 8 + h) * 3600 + q) * 64 + dg + e]) * wz[zz];
        op[e] = o * inv;
    }
}

// ---------------- fused residual add + LayerNorm ---------------------------
__global__ __launch_bounds__(256) void add_ln_kernel(
    float* __restrict__ x, const float* __restrict__ r,
    const float* __restrict__ g, const float* __restrict__ b)
{
    int row = blockIdx.x, t = threadIdx.x;
    size_t base = (size_t)row * D_;
    float v0 = x[base + t] + r[base + t];
    float v1 = x[base + t + 256] + r[base + t + 256];
    float s = v0 + v1, ss = v0 * v0 + v1 * v1;
    #pragma unroll
    for (int off = 32; off > 0; off >>= 1) {
        s  += __shfl_xor(s, off);
        ss += __shfl_xor(ss, off);
    }
    __shared__ float rs[4], rss[4];
    int w = t >> 6;
    if ((t & 63) == 0) { rs[w] = s; rss[w] = ss; }
    __syncthreads();
    s  = rs[0] + rs[1] + rs[2] + rs[3];
    ss = rss[0] + rss[1] + rss[2] + rss[3];
    float mean = s * (1.f / 512.f);
    float var = ss * (1.f / 512.f) - mean * mean;
    float rstd = rsqrtf(var + 1e-5f);
    x[base + t]       = (v0 - mean) * rstd * g[t]       + b[t];
    x[base + t + 256] = (v1 - mean) * rstd * g[t + 256] + b[t + 256];
}

// ---------------------------------------------------------------------------
extern "C" void kernel_launch(void* const* d_in, const int* in_sizes, int n_in,
                              void* d_out, int out_size, void* d_ws, size_t ws_size,
                              hipStream_t stream)
{
    const float* player_xs = (const float*)d_in[0];
    const float* player_ys = (const float*)d_in[1];
    const float* player_hs = (const float*)d_in[2];
    const float* ball_xs   = (const float*)d_in[3];
    const float* ball_ys   = (const float*)d_in[4];
    const float* ball_zs   = (const float*)d_in[5];
    const float* emb_table = (const float*)d_in[6];
    const float* ball_emb  = (const float*)d_in[7];
    const float* cls_emb   = (const float*)d_in[8];
    const float* pW0 = (const float*)d_in[9];   const float* pb0 = (const float*)d_in[10];
    const float* pW1 = (const float*)d_in[11];  const float* pb1 = (const float*)d_in[12];
    const float* pW2 = (const float*)d_in[13];  const float* pb2 = (const float*)d_in[14];
    const float* bW0 = (const float*)d_in[15];  const float* bb0 = (const float*)d_in[16];
    const float* bW1 = (const float*)d_in[17];  const float* bb1 = (const float*)d_in[18];
    const float* bW2 = (const float*)d_in[19];  const float* bb2 = (const float*)d_in[20];
    const float* Wqkv = (const float*)d_in[21]; const float* bqkv = (const float*)d_in[22];
    const float* Wo  = (const float*)d_in[23];  const float* bo  = (const float*)d_in[24];
    const float* W1f = (const float*)d_in[25];  const float* b1f = (const float*)d_in[26];
    const float* W2f = (const float*)d_in[27];  const float* b2f = (const float*)d_in[28];
    const float* g1  = (const float*)d_in[29];  const float* be1 = (const float*)d_in[30];
    const float* g2  = (const float*)d_in[31];  const float* be2 = (const float*)d_in[32];
    const float* cpW = (const float*)d_in[33];  const float* cpb = (const float*)d_in[34];
    const float* cbW = (const float*)d_in[35];  const float* cbb = (const float*)d_in[36];
    const float* csW = (const float*)d_in[37];  const float* csb = (const float*)d_in[38];
    const int* pidx = (const int*)d_in[39];

    // workspace (51.7 MB): x | big | ob | tmp2
    float* x    = (float*)d_ws;            // 1,843,200 f32
    float* big  = x + 1843200;             // 7,372,800 f32
    float* ob   = big + 7372800;           // 1,843,200 f32
    float* tmp2 = ob + 1843200;            // 1,843,200 f32
    // attention-phase aliases inside big:
    u16*   qkvb   = (u16*)big;             // [3600][1536] bf16 = 2,764,800 f32-slots
    u16*   Opart  = (u16*)(big + 2764800); // [3][8][3600][64] bf16 = 2,764,800 f32-slots
    float* mlpart = big + 5529600;         // [3][8][3600][2] f32 = 172,800
    u16*   ff1b   = (u16*)big;             // [3600][2048] bf16 (FF phase)
    u16*   vt     = (u16*)tmp2;            // [512][3648] bf16
    // token-MLP temporaries (big is free before qkv GEMM)
    float* IN = big;                       // 3600*24
    float* h0 = big + 131072;              // 3600*128
    float* h1 = big + 131072 + 460800;     // 3600*256
    float* out = (float*)d_out;

    gather_kernel<<<15, 256, 0, stream>>>(
        player_xs, player_ys, player_hs, ball_xs, ball_ys, ball_zs,
        emb_table, ball_emb, cls_emb, pidx, IN, x);

    gemm_mfma<1,0,0><<<dim3(24, 1), 256, 0, stream>>>(IN,            pW0, pb0, h0,            3000, 128, 23, 24, 1.f);
    gemm_mfma<1,0,0><<<dim3(3,  1), 256, 0, stream>>>(IN + 3000*24,  bW0, bb0, h0 + 3000*128,  300, 128, 23, 24, 1.f);
    gemm_mfma<1,0,0><<<dim3(24, 2), 256, 0, stream>>>(h0,            pW1, pb1, h1,            3000, 256, 128, 128, 1.f);
    gemm_mfma<1,0,0><<<dim3(3,  2), 256, 0, stream>>>(h0 + 3000*128, bW1, bb1, h1 + 3000*256,  300, 256, 128, 128, 1.f);
    gemm_mfma<0,0,0><<<dim3(24, 4), 256, 0, stream>>>(h1,            pW2, pb2, x,             3000, 512, 256, 256, SQRT512);
    gemm_mfma<0,0,0><<<dim3(3,  4), 256, 0, stream>>>(h1 + 3000*256, bW2, bb2, x + 3000*512,   300, 512, 256, 256, SQRT512);

    for (int l = 0; l < 4; l++) {
        const float* Wqkv_l = Wqkv + (size_t)l * 1536 * 512;
        const float* bqkv_l = bqkv + (size_t)l * 1536;
        const float* Wo_l   = Wo   + (size_t)l * 512 * 512;
        const float* bo_l   = bo   + (size_t)l * 512;
        const float* W1f_l  = W1f  + (size_t)l * 2048 * 512;
        const float* b1f_l  = b1f  + (size_t)l * 2048;
        const float* W2f_l  = W2f  + (size_t)l * 512 * 2048;
        const float* b2f_l  = b2f  + (size_t)l * 512;

        gemm_mfma<0,1,0><<<dim3(29, 12), 256, 0, stream>>>(x, Wqkv_l, bqkv_l, qkvb, 3600, 1536, 512, 512, 1.f);
        vtrans_kernel<<<dim3(57, 8), 256, 0, stream>>>(qkvb, vt);
        attn_mfma_kernel<<<dim3(57, 8, KSPLIT), 256, 0, stream>>>(qkvb, vt, Opart, mlpart);
        attn_merge_kernel<<<dim3(57, 8), 256, 0, stream>>>(Opart, mlpart, ob);
        gemm_mfma<0,0,0><<<dim3(29, 4), 256, 0, stream>>>(ob, Wo_l, bo_l, tmp2, 3600, 512, 512, 512, 1.f);
        add_ln_kernel<<<3600, 256, 0, stream>>>(x, tmp2, g1 + (size_t)l * 512, be1 + (size_t)l * 512);
        gemm_mfma<1,1,0><<<dim3(29, 16), 256, 0, stream>>>(x, W1f_l, b1f_l, ff1b, 3600, 2048, 512, 512, 1.f);
        gemm_mfma<0,0,1><<<dim3(29, 4), 256, 0, stream>>>(ff1b, W2f_l, b2f_l, tmp2, 3600, 512, 2048, 2048, 1.f);
        add_ln_kernel<<<3600, 256, 0, stream>>>(x, tmp2, g2 + (size_t)l * 512, be2 + (size_t)l * 512);
    }

    gemm_mfma<0,0,0><<<dim3(29, 1),  256, 0, stream>>>(x, cpW, cpb, out + 0,       3600, 121,  512, 512, 1.f);
    gemm_mfma<0,0,0><<<dim3(29, 11), 256, 0, stream>>>(x, cbW, cbb, out + 435600,  3600, 1331, 512, 512, 1.f);
    gemm_mfma<0,0,0><<<dim3(29, 1),  256, 0, stream>>>(x, csW, csb, out + 5227200, 3600, 10,   512, 512, 1.f);
}

// Round 7
// 1508.042 us; speedup vs baseline: 4.8889x; 1.0568x over previous
//
#include <hip/hip_runtime.h>
#include <hip/hip_bf16.h>

typedef unsigned short u16;
typedef __attribute__((ext_vector_type(8))) short bf16x8;
typedef __attribute__((ext_vector_type(4))) float f32x4;

#define T_TOK 3600
#define D_    512
#define H_    8
#define HD    64
#define NKT   57    // ceil(3600/64)
#define VT_S  3648  // padded token stride for Vt
#define KSPLIT 4
#define SQRT512 22.627416997969522f

__device__ __forceinline__ u16 f2bf(float f) {
    unsigned int x = __float_as_uint(f);
    unsigned int lsb = (x >> 16) & 1;
    return (u16)((x + 0x7fffu + lsb) >> 16);
}
__device__ __forceinline__ float bf2f(u16 u) {
    return __uint_as_float(((unsigned int)u) << 16);
}
// timestep of token: players [0,3000) -> i/10, ball [3000,3300), cls [3300,3600)
__device__ __forceinline__ int step_of(int i) {
    return (i < 3000) ? (i / 10) : ((i < 3300) ? (i - 3000) : (i - 3300));
}

// ---------------- gather: build IN[3600][24] + fill cls rows of x ----------
__global__ __launch_bounds__(256) void gather_kernel(
    const float* __restrict__ pxs, const float* __restrict__ pys, const float* __restrict__ phs,
    const float* __restrict__ bxs, const float* __restrict__ bys, const float* __restrict__ bzs,
    const float* __restrict__ emb_table, const float* __restrict__ ball_emb,
    const float* __restrict__ cls_emb, const int* __restrict__ pidx,
    float* __restrict__ IN, float* __restrict__ x)
{
    int g = blockIdx.x * 256 + threadIdx.x;   // 15*256 = 3840
    if (g < 3300) {
        float* row = IN + g * 24;
        if (g < 3000) {
            int id = pidx[g];
            #pragma unroll
            for (int e = 0; e < 20; e++) row[e] = emb_table[id * 20 + e];
            row[20] = pxs[g]; row[21] = pys[g]; row[22] = phs[g];
        } else {
            int b = g - 3000;
            #pragma unroll
            for (int e = 0; e < 20; e++) row[e] = ball_emb[e];
            row[20] = bxs[b]; row[21] = bys[b]; row[22] = bzs[b];
        }
        row[23] = 0.f;
    }
    for (int i = g; i < 300 * 512; i += 3840) {
        x[3300 * 512 + i] = cls_emb[i & 511];
    }
}

// ---------------- MFMA GEMM ------------------------------------------------
// C[M,N] = act(A[M,K] * W[N,K]^T + bias) * scale.  A fp32 or bf16; C fp32 or bf16.
__device__ __forceinline__ void stage_f32(
    const float* __restrict__ src, int nrows, int K, int lda,
    int r0, int kk, int srow, int scg, u16* dst)
{
    u16 tmp[16];
    int rr = r0 + srow;
    if (rr < nrows) {
        if (((lda & 3) == 0) && (kk + scg + 16 <= K)) {
            const float4* p = reinterpret_cast<const float4*>(src + (size_t)rr * lda + kk + scg);
            #pragma unroll
            for (int q = 0; q < 4; q++) {
                float4 v = p[q];
                tmp[q*4+0] = f2bf(v.x); tmp[q*4+1] = f2bf(v.y);
                tmp[q*4+2] = f2bf(v.z); tmp[q*4+3] = f2bf(v.w);
            }
        } else {
            #pragma unroll
            for (int e = 0; e < 16; e++) {
                int kc = kk + scg + e;
                tmp[e] = (kc < K) ? f2bf(src[(size_t)rr * lda + kc]) : (u16)0;
            }
        }
    } else {
        #pragma unroll
        for (int e = 0; e < 16; e++) tmp[e] = 0;
    }
    *reinterpret_cast<bf16x8*>(dst)     = *reinterpret_cast<const bf16x8*>(&tmp[0]);
    *reinterpret_cast<bf16x8*>(dst + 8) = *reinterpret_cast<const bf16x8*>(&tmp[8]);
}

__device__ __forceinline__ void stage_b16(
    const u16* __restrict__ src, int nrows, int lda,
    int r0, int kk, int srow, int scg, u16* dst)
{
    int rr = r0 + srow;
    bf16x8 a = {}, b = {};
    if (rr < nrows) {
        const bf16x8* p = reinterpret_cast<const bf16x8*>(src + (size_t)rr * lda + kk + scg);
        a = p[0]; b = p[1];
    }
    *reinterpret_cast<bf16x8*>(dst)     = a;
    *reinterpret_cast<bf16x8*>(dst + 8) = b;
}

template<int RELU, int BF16OUT, int ABF16>
__global__ __launch_bounds__(256) void gemm_mfma(
    const void* __restrict__ Av, const float* __restrict__ W,
    const float* __restrict__ bias, void* __restrict__ Cv,
    int M, int N, int K, int lda, float scale)
{
    __shared__ u16 As[128][40];
    __shared__ u16 Bs[128][40];
    int t = threadIdx.x;
    int w = t >> 6, l = t & 63;
    int ll = l & 15, lg = l >> 4;
    int wr = w >> 1, wc = w & 1;
    int m0 = blockIdx.x * 128, n0 = blockIdx.y * 128;
    int srow = t >> 1;
    int scg  = (t & 1) * 16;

    f32x4 acc[4][4];
    #pragma unroll
    for (int i = 0; i < 4; i++)
        #pragma unroll
        for (int j = 0; j < 4; j++) acc[i][j] = (f32x4){0.f, 0.f, 0.f, 0.f};

    for (int kk = 0; kk < K; kk += 32) {
        if (ABF16) stage_b16((const u16*)Av, M, lda, m0, kk, srow, scg, &As[srow][scg]);
        else       stage_f32((const float*)Av, M, K, lda, m0, kk, srow, scg, &As[srow][scg]);
        stage_f32(W, N, K, K, n0, kk, srow, scg, &Bs[srow][scg]);
        __syncthreads();
        bf16x8 af[4], bf[4];
        #pragma unroll
        for (int i = 0; i < 4; i++)
            af[i] = *reinterpret_cast<const bf16x8*>(&As[wr*64 + i*16 + ll][lg*8]);
        #pragma unroll
        for (int j = 0; j < 4; j++)
            bf[j] = *reinterpret_cast<const bf16x8*>(&Bs[wc*64 + j*16 + ll][lg*8]);
        #pragma unroll
        for (int i = 0; i < 4; i++)
            #pragma unroll
            for (int j = 0; j < 4; j++)
                acc[i][j] = __builtin_amdgcn_mfma_f32_16x16x32_bf16(af[i], bf[j], acc[i][j], 0, 0, 0);
        __syncthreads();
    }

    float bv[4];
    #pragma unroll
    for (int j = 0; j < 4; j++) {
        int n = n0 + wc*64 + j*16 + ll;
        bv[j] = (n < N) ? bias[n] : 0.f;
    }
    #pragma unroll
    for (int i = 0; i < 4; i++) {
        #pragma unroll
        for (int r = 0; r < 4; r++) {
            int m = m0 + wr*64 + i*16 + lg*4 + r;
            if (m >= M) continue;
            #pragma unroll
            for (int j = 0; j < 4; j++) {
                int n = n0 + wc*64 + j*16 + ll;
                if (n >= N) continue;
                float v = acc[i][j][r] + bv[j];
                if (RELU) v = fmaxf(v, 0.f);
                v *= scale;
                if (BF16OUT) ((u16*)Cv)[(size_t)m * N + n] = f2bf(v);
                else         ((float*)Cv)[(size_t)m * N + n] = v;
            }
        }
    }
}

// ---------------- V transpose: vt[h*64+d][tok] = qkvb[tok][1024+h*64+d] ----
__global__ __launch_bounds__(256) void vtrans_kernel(
    const u16* __restrict__ qkvb, u16* __restrict__ vt)
{
    __shared__ u16 tile[64][72];
    int t = threadIdx.x;
    int tok0 = blockIdx.x * 64;
    int h = blockIdx.y;
    {
        int i = t >> 2, c16 = (t & 3) * 16;
        int tok = tok0 + i;
        bf16x8 a = {}, b = {};
        if (tok < T_TOK) {
            const bf16x8* p = reinterpret_cast<const bf16x8*>(qkvb + (size_t)tok * 1536 + 1024 + h * HD + c16);
            a = p[0]; b = p[1];
        }
        *reinterpret_cast<bf16x8*>(&tile[i][c16])     = a;
        *reinterpret_cast<bf16x8*>(&tile[i][c16 + 8]) = b;
    }
    __syncthreads();
    {
        int d = t >> 2, i0 = (t & 3) * 16;
        u16 tt[16];
        #pragma unroll
        for (int e = 0; e < 16; e++) tt[e] = tile[i0 + e][d];
        u16* dst = vt + (size_t)(h * HD + d) * VT_S + tok0 + i0;
        *reinterpret_cast<bf16x8*>(dst)     = *reinterpret_cast<const bf16x8*>(&tt[0]);
        *reinterpret_cast<bf16x8*>(dst + 8) = *reinterpret_cast<const bf16x8*>(&tt[8]);
    }
}

// ---------------- MFMA flash attention, 1 wave per 16 queries --------------
// grid (225, 8, KSPLIT); block 64 = 1 wave owning queries [bx*16, bx*16+16).
// Writes UNNORMALIZED partials: Opart bf16 [z][h][3600][64], mlpart f32 [z][h][3600][2].
__global__ __launch_bounds__(64) void attn_mfma_kernel(
    const u16* __restrict__ qkvb, const u16* __restrict__ vt,
    u16* __restrict__ Opart, float* __restrict__ mlpart)
{
    __shared__ u16 plds[16][80];
    int l = threadIdx.x;
    int lg = l >> 4, ll = l & 15;
    int h = blockIdx.y;
    int z = blockIdx.z;
    int q0 = blockIdx.x * 16;

    int qa = q0 + ll;
    const u16* qrow = qkvb + (size_t)qa * 1536 + h * HD + lg * 8;
    bf16x8 qf0 = *reinterpret_cast<const bf16x8*>(qrow);
    bf16x8 qf1 = *reinterpret_cast<const bf16x8*>(qrow + 32);

    int sq[4];
    #pragma unroll
    for (int r = 0; r < 4; r++) sq[r] = step_of(q0 + lg * 4 + r);
    int smax = step_of(qa);
    #pragma unroll
    for (int off = 1; off < 16; off <<= 1) smax = max(smax, __shfl_xor(smax, off));

    f32x4 oacc[4];
    #pragma unroll
    for (int i = 0; i < 4; i++) oacc[i] = (f32x4){0.f, 0.f, 0.f, 0.f};
    float m[4], lsum[4];
    #pragma unroll
    for (int r = 0; r < 4; r++) { m[r] = -INFINITY; lsum[r] = 0.f; }

    #pragma unroll 1
    for (int kt = z; kt < NKT; kt += KSPLIT) {
        int kbase = kt * 64;
        int a = kbase, b = min(kbase + 63, T_TOK - 1);
        int mn = 0x7fffffff;
        if (a < 3000) mn = min(mn, a / 10);
        if (b >= 3000 && a < 3300) mn = min(mn, max(a, 3000) - 3000);
        if (b >= 3300) mn = min(mn, max(a, 3300) - 3300);
        if (mn > smax) continue;

        // ---- V preload (independent of QK; latency hides under QK+softmax) -
        bf16x8 vf0[4], vf1[4];
        #pragma unroll
        for (int i = 0; i < 4; i++) {
            const u16* vr = vt + (size_t)(h * HD + i * 16 + ll) * VT_S + kbase + lg * 8;
            vf0[i] = *reinterpret_cast<const bf16x8*>(vr);
            vf1[i] = *reinterpret_cast<const bf16x8*>(vr + 32);
        }

        // ---- QK^T ----
        f32x4 sfr[4];
        __builtin_amdgcn_s_setprio(1);
        #pragma unroll
        for (int f = 0; f < 4; f++) {
            int key = kbase + f * 16 + ll;
            int keyc = min(key, T_TOK - 1);
            const u16* krow = qkvb + (size_t)keyc * 1536 + 512 + h * HD + lg * 8;
            bf16x8 kf0 = *reinterpret_cast<const bf16x8*>(krow);
            bf16x8 kf1 = *reinterpret_cast<const bf16x8*>(krow + 32);
            f32x4 acc = (f32x4){0.f, 0.f, 0.f, 0.f};
            acc = __builtin_amdgcn_mfma_f32_16x16x32_bf16(qf0, kf0, acc, 0, 0, 0);
            acc = __builtin_amdgcn_mfma_f32_16x16x32_bf16(qf1, kf1, acc, 0, 0, 0);
            sfr[f] = acc;
        }
        __builtin_amdgcn_s_setprio(0);

        // ---- mask + scale + row max ----
        float rmax[4];
        #pragma unroll
        for (int r = 0; r < 4; r++) rmax[r] = -INFINITY;
        #pragma unroll
        for (int f = 0; f < 4; f++) {
            int key = kbase + f * 16 + ll;
            int sk = (key < T_TOK) ? step_of(key) : 0x7fffffff;
            #pragma unroll
            for (int r = 0; r < 4; r++) {
                float v = sfr[f][r] * 0.125f;
                v = (sk <= sq[r]) ? v : -INFINITY;
                sfr[f][r] = v;
                rmax[r] = fmaxf(rmax[r], v);
            }
        }
        #pragma unroll
        for (int r = 0; r < 4; r++) {
            float v = rmax[r];
            v = fmaxf(v, __shfl_xor(v, 1));
            v = fmaxf(v, __shfl_xor(v, 2));
            v = fmaxf(v, __shfl_xor(v, 4));
            v = fmaxf(v, __shfl_xor(v, 8));
            rmax[r] = v;
        }
        // ---- defer-max: rescale only when some row grew past THR=8 ----
        bool upd = false;
        #pragma unroll
        for (int r = 0; r < 4; r++) upd = upd || (rmax[r] > m[r] + 8.f);
        if (__any(upd)) {
            float csc[4];
            #pragma unroll
            for (int r = 0; r < 4; r++) {
                float mn2 = fmaxf(m[r], rmax[r]);
                float c = (m[r] == -INFINITY) ? 0.f : __expf(m[r] - mn2);
                csc[r] = c;
                m[r] = mn2;
                lsum[r] *= c;
            }
            #pragma unroll
            for (int i = 0; i < 4; i++)
                #pragma unroll
                for (int r = 0; r < 4; r++) oacc[i][r] *= csc[r];
        }
        // ---- P = exp(S - m) -> bf16 -> LDS (A-frag layout) ----
        #pragma unroll
        for (int f = 0; f < 4; f++) {
            #pragma unroll
            for (int r = 0; r < 4; r++) {
                float sv = sfr[f][r];
                float p = (sv == -INFINITY) ? 0.f : __expf(sv - m[r]);
                lsum[r] += p;
                plds[lg * 4 + r][f * 16 + ll] = f2bf(p);
            }
        }
        // ---- PV (same-wave LDS RAW: compiler inserts lgkmcnt wait) ----
        __builtin_amdgcn_s_setprio(1);
        {
            bf16x8 pf0 = *reinterpret_cast<const bf16x8*>(&plds[ll][lg * 8]);
            #pragma unroll
            for (int i = 0; i < 4; i++)
                oacc[i] = __builtin_amdgcn_mfma_f32_16x16x32_bf16(pf0, vf0[i], oacc[i], 0, 0, 0);
            bf16x8 pf1 = *reinterpret_cast<const bf16x8*>(&plds[ll][32 + lg * 8]);
            #pragma unroll
            for (int i = 0; i < 4; i++)
                oacc[i] = __builtin_amdgcn_mfma_f32_16x16x32_bf16(pf1, vf1[i], oacc[i], 0, 0, 0);
        }
        __builtin_amdgcn_s_setprio(0);
    }

    // row-sum lsum across 16 col-lanes
    #pragma unroll
    for (int r = 0; r < 4; r++) {
        float v = lsum[r];
        v += __shfl_xor(v, 1);
        v += __shfl_xor(v, 2);
        v += __shfl_xor(v, 4);
        v += __shfl_xor(v, 8);
        lsum[r] = v;
    }
    // write partials (unnormalized)
    #pragma unroll
    for (int r = 0; r < 4; r++) {
        int q = q0 + lg * 4 + r;
        size_t ob = ((size_t)(z * 8 + h) * 3600 + q) * 64;
        #pragma unroll
        for (int i = 0; i < 4; i++)
            Opart[ob + i * 16 + ll] = f2bf(oacc[i][r]);
        if (ll == 0) {
            size_t mi = ((size_t)(z * 8 + h) * 3600 + q) * 2;
            mlpart[mi]     = m[r];
            mlpart[mi + 1] = lsum[r];
        }
    }
}

// ---------------- merge KSPLIT partials -> ob ------------------------------
__global__ __launch_bounds__(256) void attn_merge_kernel(
    const u16* __restrict__ Opart, const float* __restrict__ mlpart,
    float* __restrict__ ob)
{
    int t = threadIdx.x;
    int h = blockIdx.y;
    int q = blockIdx.x * 64 + (t >> 2);
    if (q >= T_TOK) return;
    int dg = (t & 3) * 16;
    float mz[KSPLIT], lz[KSPLIT];
    #pragma unroll
    for (int zz = 0; zz < KSPLIT; zz++) {
        size_t mi = ((size_t)(zz * 8 + h) * 3600 + q) * 2;
        mz[zz] = mlpart[mi];
        lz[zz] = mlpart[mi + 1];
    }
    float M = -INFINITY;
    #pragma unroll
    for (int zz = 0; zz < KSPLIT; zz++) if (lz[zz] > 0.f) M = fmaxf(M, mz[zz]);
    float wz[KSPLIT], den = 0.f;
    #pragma unroll
    for (int zz = 0; zz < KSPLIT; zz++) {
        wz[zz] = (lz[zz] > 0.f) ? __expf(mz[zz] - M) : 0.f;
        den += wz[zz] * lz[zz];
    }
    float inv = (den > 0.f) ? 1.f / den : 0.f;
    float* op = ob + (size_t)q * D_ + h * HD + dg;
    #pragma unroll
    for (int e = 0; e < 16; e++) {
        float o = 0.f;
        #pragma unroll
        for (int zz = 0; zz < KSPLIT; zz++)
            o += bf2f(Opart[((size_t)(zz * 8 + h) * 3600 + q) * 64 + dg + e]) * wz[zz];
        op[e] = o * inv;
    }
}

// ---------------- fused residual add + LayerNorm ---------------------------
__global__ __launch_bounds__(256) void add_ln_kernel(
    float* __restrict__ x, const float* __restrict__ r,
    const float* __restrict__ g, const float* __restrict__ b)
{
    int row = blockIdx.x, t = threadIdx.x;
    size_t base = (size_t)row * D_;
    float v0 = x[base + t] + r[base + t];
    float v1 = x[base + t + 256] + r[base + t + 256];
    float s = v0 + v1, ss = v0 * v0 + v1 * v1;
    #pragma unroll
    for (int off = 32; off > 0; off >>= 1) {
        s  += __shfl_xor(s, off);
        ss += __shfl_xor(ss, off);
    }
    __shared__ float rs[4], rss[4];
    int w = t >> 6;
    if ((t & 63) == 0) { rs[w] = s; rss[w] = ss; }
    __syncthreads();
    s  = rs[0] + rs[1] + rs[2] + rs[3];
    ss = rss[0] + rss[1] + rss[2] + rss[3];
    float mean = s * (1.f / 512.f);
    float var = ss * (1.f / 512.f) - mean * mean;
    float rstd = rsqrtf(var + 1e-5f);
    x[base + t]       = (v0 - mean) * rstd * g[t]       + b[t];
    x[base + t + 256] = (v1 - mean) * rstd * g[t + 256] + b[t + 256];
}

// ---------------------------------------------------------------------------
extern "C" void kernel_launch(void* const* d_in, const int* in_sizes, int n_in,
                              void* d_out, int out_size, void* d_ws, size_t ws_size,
                              hipStream_t stream)
{
    const float* player_xs = (const float*)d_in[0];
    const float* player_ys = (const float*)d_in[1];
    const float* player_hs = (const float*)d_in[2];
    const float* ball_xs   = (const float*)d_in[3];
    const float* ball_ys   = (const float*)d_in[4];
    const float* ball_zs   = (const float*)d_in[5];
    const float* emb_table = (const float*)d_in[6];
    const float* ball_emb  = (const float*)d_in[7];
    const float* cls_emb   = (const float*)d_in[8];
    const float* pW0 = (const float*)d_in[9];   const float* pb0 = (const float*)d_in[10];
    const float* pW1 = (const float*)d_in[11];  const float* pb1 = (const float*)d_in[12];
    const float* pW2 = (const float*)d_in[13];  const float* pb2 = (const float*)d_in[14];
    const float* bW0 = (const float*)d_in[15];  const float* bb0 = (const float*)d_in[16];
    const float* bW1 = (const float*)d_in[17];  const float* bb1 = (const float*)d_in[18];
    const float* bW2 = (const float*)d_in[19];  const float* bb2 = (const float*)d_in[20];
    const float* Wqkv = (const float*)d_in[21]; const float* bqkv = (const float*)d_in[22];
    const float* Wo  = (const float*)d_in[23];  const float* bo  = (const float*)d_in[24];
    const float* W1f = (const float*)d_in[25];  const float* b1f = (const float*)d_in[26];
    const float* W2f = (const float*)d_in[27];  const float* b2f = (const float*)d_in[28];
    const float* g1  = (const float*)d_in[29];  const float* be1 = (const float*)d_in[30];
    const float* g2  = (const float*)d_in[31];  const float* be2 = (const float*)d_in[32];
    const float* cpW = (const float*)d_in[33];  const float* cpb = (const float*)d_in[34];
    const float* cbW = (const float*)d_in[35];  const float* cbb = (const float*)d_in[36];
    const float* csW = (const float*)d_in[37];  const float* csb = (const float*)d_in[38];
    const int* pidx = (const int*)d_in[39];

    // workspace (51.7 MB): x | big | ob | tmp2
    float* x    = (float*)d_ws;            // 1,843,200 f32
    float* big  = x + 1843200;             // 7,372,800 f32
    float* ob   = big + 7372800;           // 1,843,200 f32
    float* tmp2 = ob + 1843200;            // 1,843,200 f32
    // attention-phase aliases inside big:
    u16*   qkvb   = (u16*)big;             // [3600][1536] bf16 = 2,764,800 f32-slots
    u16*   Opart  = (u16*)(big + 2764800); // [4][8][3600][64] bf16 = 3,686,400 f32-slots
    float* mlpart = big + 6451200;         // [4][8][3600][2] f32 = 230,400 (ends 6,681,600)
    u16*   ff1b   = (u16*)big;             // [3600][2048] bf16 (FF phase)
    u16*   vt     = (u16*)tmp2;            // [512][3648] bf16
    // token-MLP temporaries (big is free before qkv GEMM)
    float* IN = big;                       // 3600*24
    float* h0 = big + 131072;              // 3600*128
    float* h1 = big + 131072 + 460800;     // 3600*256
    float* out = (float*)d_out;

    gather_kernel<<<15, 256, 0, stream>>>(
        player_xs, player_ys, player_hs, ball_xs, ball_ys, ball_zs,
        emb_table, ball_emb, cls_emb, pidx, IN, x);

    gemm_mfma<1,0,0><<<dim3(24, 1), 256, 0, stream>>>(IN,            pW0, pb0, h0,            3000, 128, 23, 24, 1.f);
    gemm_mfma<1,0,0><<<dim3(3,  1), 256, 0, stream>>>(IN + 3000*24,  bW0, bb0, h0 + 3000*128,  300, 128, 23, 24, 1.f);
    gemm_mfma<1,0,0><<<dim3(24, 2), 256, 0, stream>>>(h0,            pW1, pb1, h1,            3000, 256, 128, 128, 1.f);
    gemm_mfma<1,0,0><<<dim3(3,  2), 256, 0, stream>>>(h0 + 3000*128, bW1, bb1, h1 + 3000*256,  300, 256, 128, 128, 1.f);
    gemm_mfma<0,0,0><<<dim3(24, 4), 256, 0, stream>>>(h1,            pW2, pb2, x,             3000, 512, 256, 256, SQRT512);
    gemm_mfma<0,0,0><<<dim3(3,  4), 256, 0, stream>>>(h1 + 3000*256, bW2, bb2, x + 3000*512,   300, 512, 256, 256, SQRT512);

    for (int l = 0; l < 4; l++) {
        const float* Wqkv_l = Wqkv + (size_t)l * 1536 * 512;
        const float* bqkv_l = bqkv + (size_t)l * 1536;
        const float* Wo_l   = Wo   + (size_t)l * 512 * 512;
        const float* bo_l   = bo   + (size_t)l * 512;
        const float* W1f_l  = W1f  + (size_t)l * 2048 * 512;
        const float* b1f_l  = b1f  + (size_t)l * 2048;
        const float* W2f_l  = W2f  + (size_t)l * 512 * 2048;
        const float* b2f_l  = b2f  + (size_t)l * 512;

        gemm_mfma<0,1,0><<<dim3(29, 12), 256, 0, stream>>>(x, Wqkv_l, bqkv_l, qkvb, 3600, 1536, 512, 512, 1.f);
        vtrans_kernel<<<dim3(57, 8), 256, 0, stream>>>(qkvb, vt);
        attn_mfma_kernel<<<dim3(225, 8, KSPLIT), 64, 0, stream>>>(qkvb, vt, Opart, mlpart);
        attn_merge_kernel<<<dim3(57, 8), 256, 0, stream>>>(Opart, mlpart, ob);
        gemm_mfma<0,0,0><<<dim3(29, 4), 256, 0, stream>>>(ob, Wo_l, bo_l, tmp2, 3600, 512, 512, 512, 1.f);
        add_ln_kernel<<<3600, 256, 0, stream>>>(x, tmp2, g1 + (size_t)l * 512, be1 + (size_t)l * 512);
        gemm_mfma<1,1,0><<<dim3(29, 16), 256, 0, stream>>>(x, W1f_l, b1f_l, ff1b, 3600, 2048, 512, 512, 1.f);
        gemm_mfma<0,0,1><<<dim3(29, 4), 256, 0, stream>>>(ff1b, W2f_l, b2f_l, tmp2, 3600, 512, 2048, 2048, 1.f);
        add_ln_kernel<<<3600, 256, 0, stream>>>(x, tmp2, g2 + (size_t)l * 512, be2 + (size_t)l * 512);
    }

    gemm_mfma<0,0,0><<<dim3(29, 1),  256, 0, stream>>>(x, cpW, cpb, out + 0,       3600, 121,  512, 512, 1.f);
    gemm_mfma<0,0,0><<<dim3(29, 11), 256, 0, stream>>>(x, cbW, cbb, out + 435600,  3600, 1331, 512, 512, 1.f);
    gemm_mfma<0,0,0><<<dim3(29, 1),  256, 0, stream>>>(x, csW, csb, out + 5227200, 3600, 10,   512, 512, 1.f);
}

// Round 8
// 1363.718 us; speedup vs baseline: 5.4063x; 1.1058x over previous
//
#include <hip/hip_runtime.h>
#include <hip/hip_bf16.h>

typedef unsigned short u16;
typedef __attribute__((ext_vector_type(8))) short bf16x8;
typedef __attribute__((ext_vector_type(4))) float f32x4;

#define T_TOK 3600
#define D_    512
#define H_    8
#define HD    64
#define NKT   57    // ceil(3600/64)
#define VT_S  3648  // padded token stride for Vt
#define KSPLIT 4
#define SQRT512 22.627416997969522f

__device__ __forceinline__ u16 f2bf(float f) {
    unsigned int x = __float_as_uint(f);
    unsigned int lsb = (x >> 16) & 1;
    return (u16)((x + 0x7fffu + lsb) >> 16);
}
__device__ __forceinline__ float bf2f(u16 u) {
    return __uint_as_float(((unsigned int)u) << 16);
}
// timestep of token: players [0,3000) -> i/10, ball [3000,3300), cls [3300,3600)
__device__ __forceinline__ int step_of(int i) {
    return (i < 3000) ? (i / 10) : ((i < 3300) ? (i - 3000) : (i - 3300));
}

// ---------------- gather: build IN[3600][24] + fill cls rows of x ----------
__global__ __launch_bounds__(256) void gather_kernel(
    const float* __restrict__ pxs, const float* __restrict__ pys, const float* __restrict__ phs,
    const float* __restrict__ bxs, const float* __restrict__ bys, const float* __restrict__ bzs,
    const float* __restrict__ emb_table, const float* __restrict__ ball_emb,
    const float* __restrict__ cls_emb, const int* __restrict__ pidx,
    float* __restrict__ IN, float* __restrict__ x)
{
    int g = blockIdx.x * 256 + threadIdx.x;   // 15*256 = 3840
    if (g < 3300) {
        float* row = IN + g * 24;
        if (g < 3000) {
            int id = pidx[g];
            #pragma unroll
            for (int e = 0; e < 20; e++) row[e] = emb_table[id * 20 + e];
            row[20] = pxs[g]; row[21] = pys[g]; row[22] = phs[g];
        } else {
            int b = g - 3000;
            #pragma unroll
            for (int e = 0; e < 20; e++) row[e] = ball_emb[e];
            row[20] = bxs[b]; row[21] = bys[b]; row[22] = bzs[b];
        }
        row[23] = 0.f;
    }
    for (int i = g; i < 300 * 512; i += 3840) {
        x[3300 * 512 + i] = cls_emb[i & 511];
    }
}

// ---------------- fp32 -> bf16 convert (grid-stride, float4) ---------------
__global__ __launch_bounds__(256) void w2b_kernel(
    const float* __restrict__ src, u16* __restrict__ dst, int n4)
{
    int stride = gridDim.x * 256;
    for (int i = blockIdx.x * 256 + threadIdx.x; i < n4; i += stride) {
        float4 v = reinterpret_cast<const float4*>(src)[i];
        ushort4 o;
        o.x = f2bf(v.x); o.y = f2bf(v.y); o.z = f2bf(v.z); o.w = f2bf(v.w);
        reinterpret_cast<ushort4*>(dst)[i] = o;
    }
}

// ---------------- MFMA GEMM ------------------------------------------------
// C[M,N] = act(A[M,K] * W[N,K]^T + bias) * scale.  A/W fp32 or bf16; C fp32 or bf16.
__device__ __forceinline__ void stage_f32(
    const float* __restrict__ src, int nrows, int K, int lda,
    int r0, int kk, int srow, int scg, u16* dst)
{
    u16 tmp[16];
    int rr = r0 + srow;
    if (rr < nrows) {
        if (((lda & 3) == 0) && (kk + scg + 16 <= K)) {
            const float4* p = reinterpret_cast<const float4*>(src + (size_t)rr * lda + kk + scg);
            #pragma unroll
            for (int q = 0; q < 4; q++) {
                float4 v = p[q];
                tmp[q*4+0] = f2bf(v.x); tmp[q*4+1] = f2bf(v.y);
                tmp[q*4+2] = f2bf(v.z); tmp[q*4+3] = f2bf(v.w);
            }
        } else {
            #pragma unroll
            for (int e = 0; e < 16; e++) {
                int kc = kk + scg + e;
                tmp[e] = (kc < K) ? f2bf(src[(size_t)rr * lda + kc]) : (u16)0;
            }
        }
    } else {
        #pragma unroll
        for (int e = 0; e < 16; e++) tmp[e] = 0;
    }
    *reinterpret_cast<bf16x8*>(dst)     = *reinterpret_cast<const bf16x8*>(&tmp[0]);
    *reinterpret_cast<bf16x8*>(dst + 8) = *reinterpret_cast<const bf16x8*>(&tmp[8]);
}

__device__ __forceinline__ void stage_b16(
    const u16* __restrict__ src, int nrows, int lda,
    int r0, int kk, int srow, int scg, u16* dst)
{
    int rr = r0 + srow;
    bf16x8 a = {}, b = {};
    if (rr < nrows) {
        const bf16x8* p = reinterpret_cast<const bf16x8*>(src + (size_t)rr * lda + kk + scg);
        a = p[0]; b = p[1];
    }
    *reinterpret_cast<bf16x8*>(dst)     = a;
    *reinterpret_cast<bf16x8*>(dst + 8) = b;
}

template<int RELU, int BF16OUT, int ABF16, int BBF16, int QSCALE>
__global__ __launch_bounds__(256) void gemm_mfma(
    const void* __restrict__ Av, const void* __restrict__ Wv,
    const float* __restrict__ bias, void* __restrict__ Cv,
    int M, int N, int K, int lda, float scale)
{
    __shared__ u16 As[128][40];
    __shared__ u16 Bs[128][40];
    int t = threadIdx.x;
    int w = t >> 6, l = t & 63;
    int ll = l & 15, lg = l >> 4;
    int wr = w >> 1, wc = w & 1;
    int m0 = blockIdx.x * 128, n0 = blockIdx.y * 128;
    int srow = t >> 1;
    int scg  = (t & 1) * 16;

    f32x4 acc[4][4];
    #pragma unroll
    for (int i = 0; i < 4; i++)
        #pragma unroll
        for (int j = 0; j < 4; j++) acc[i][j] = (f32x4){0.f, 0.f, 0.f, 0.f};

    for (int kk = 0; kk < K; kk += 32) {
        if (ABF16) stage_b16((const u16*)Av, M, lda, m0, kk, srow, scg, &As[srow][scg]);
        else       stage_f32((const float*)Av, M, K, lda, m0, kk, srow, scg, &As[srow][scg]);
        if (BBF16) stage_b16((const u16*)Wv, N, K, n0, kk, srow, scg, &Bs[srow][scg]);
        else       stage_f32((const float*)Wv, N, K, K, n0, kk, srow, scg, &Bs[srow][scg]);
        __syncthreads();
        bf16x8 af[4], bf[4];
        #pragma unroll
        for (int i = 0; i < 4; i++)
            af[i] = *reinterpret_cast<const bf16x8*>(&As[wr*64 + i*16 + ll][lg*8]);
        #pragma unroll
        for (int j = 0; j < 4; j++)
            bf[j] = *reinterpret_cast<const bf16x8*>(&Bs[wc*64 + j*16 + ll][lg*8]);
        #pragma unroll
        for (int i = 0; i < 4; i++)
            #pragma unroll
            for (int j = 0; j < 4; j++)
                acc[i][j] = __builtin_amdgcn_mfma_f32_16x16x32_bf16(af[i], bf[j], acc[i][j], 0, 0, 0);
        __syncthreads();
    }

    float bv[4];
    #pragma unroll
    for (int j = 0; j < 4; j++) {
        int n = n0 + wc*64 + j*16 + ll;
        bv[j] = (n < N) ? bias[n] : 0.f;
    }
    #pragma unroll
    for (int i = 0; i < 4; i++) {
        #pragma unroll
        for (int r = 0; r < 4; r++) {
            int m = m0 + wr*64 + i*16 + lg*4 + r;
            if (m >= M) continue;
            #pragma unroll
            for (int j = 0; j < 4; j++) {
                int n = n0 + wc*64 + j*16 + ll;
                if (n >= N) continue;
                float v = acc[i][j][r] + bv[j];
                if (RELU) v = fmaxf(v, 0.f);
                v *= scale;
                if (QSCALE && n < 512) v *= 0.125f;   // fold 1/sqrt(hd) into Q
                if (BF16OUT) ((u16*)Cv)[(size_t)m * N + n] = f2bf(v);
                else         ((float*)Cv)[(size_t)m * N + n] = v;
            }
        }
    }
}

// ---------------- V transpose: vt[h*64+d][tok] = qkvb[tok][1024+h*64+d] ----
__global__ __launch_bounds__(256) void vtrans_kernel(
    const u16* __restrict__ qkvb, u16* __restrict__ vt)
{
    __shared__ u16 tile[64][72];
    int t = threadIdx.x;
    int tok0 = blockIdx.x * 64;
    int h = blockIdx.y;
    {
        int i = t >> 2, c16 = (t & 3) * 16;
        int tok = tok0 + i;
        bf16x8 a = {}, b = {};
        if (tok < T_TOK) {
            const bf16x8* p = reinterpret_cast<const bf16x8*>(qkvb + (size_t)tok * 1536 + 1024 + h * HD + c16);
            a = p[0]; b = p[1];
        }
        *reinterpret_cast<bf16x8*>(&tile[i][c16])     = a;
        *reinterpret_cast<bf16x8*>(&tile[i][c16 + 8]) = b;
    }
    __syncthreads();
    {
        int d = t >> 2, i0 = (t & 3) * 16;
        u16 tt[16];
        #pragma unroll
        for (int e = 0; e < 16; e++) tt[e] = tile[i0 + e][d];
        u16* dst = vt + (size_t)(h * HD + d) * VT_S + tok0 + i0;
        *reinterpret_cast<bf16x8*>(dst)     = *reinterpret_cast<const bf16x8*>(&tt[0]);
        *reinterpret_cast<bf16x8*>(dst + 8) = *reinterpret_cast<const bf16x8*>(&tt[8]);
    }
}

// ---------------- MFMA flash attention, 1 wave per 16 queries --------------
// grid (225, 8, KSPLIT); block 64 = 1 wave owning queries [bx*16, bx*16+16).
// Q pre-scaled by 0.125 in the qkv GEMM epilogue.
__global__ __launch_bounds__(64) void attn_mfma_kernel(
    const u16* __restrict__ qkvb, const u16* __restrict__ vt,
    u16* __restrict__ Opart, float* __restrict__ mlpart)
{
    __shared__ u16 plds[16][68];   // stride 68 u16 -> lane groups on disjoint banks
    int l = threadIdx.x;
    int lg = l >> 4, ll = l & 15;
    int h = blockIdx.y;
    int z = blockIdx.z;
    int q0 = blockIdx.x * 16;

    int qa = q0 + ll;
    const u16* qrow = qkvb + (size_t)qa * 1536 + h * HD + lg * 8;
    bf16x8 qf0 = *reinterpret_cast<const bf16x8*>(qrow);
    bf16x8 qf1 = *reinterpret_cast<const bf16x8*>(qrow + 32);

    int sq[4];
    #pragma unroll
    for (int r = 0; r < 4; r++) sq[r] = step_of(q0 + lg * 4 + r);
    int sqa = step_of(qa);
    int smax = sqa, smin = sqa;
    #pragma unroll
    for (int off = 1; off < 16; off <<= 1) {
        smax = max(smax, __shfl_xor(smax, off));
        smin = min(smin, __shfl_xor(smin, off));
    }

    f32x4 oacc[4];
    #pragma unroll
    for (int i = 0; i < 4; i++) oacc[i] = (f32x4){0.f, 0.f, 0.f, 0.f};
    float m[4], lsum[4];
    #pragma unroll
    for (int r = 0; r < 4; r++) { m[r] = -INFINITY; lsum[r] = 0.f; }

    #pragma unroll 1
    for (int kt = z; kt < NKT; kt += KSPLIT) {
        int kbase = kt * 64;
        int a = kbase, b = min(kbase + 63, T_TOK - 1);
        int mn = 0x7fffffff, mx = -1;
        if (a < 3000)                { mn = min(mn, a / 10);              mx = max(mx, min(b, 2999) / 10); }
        if (b >= 3000 && a < 3300)   { mn = min(mn, max(a, 3000) - 3000); mx = max(mx, min(b, 3299) - 3000); }
        if (b >= 3300)               { mn = min(mn, max(a, 3300) - 3300); mx = max(mx, b - 3300); }
        if (mn > smax) continue;
        bool needmask = (mx > smin) || (kbase + 64 > T_TOK);

        // ---- V preload (independent of QK; latency hides under QK+softmax) -
        bf16x8 vf0[4], vf1[4];
        #pragma unroll
        for (int i = 0; i < 4; i++) {
            const u16* vr = vt + (size_t)(h * HD + i * 16 + ll) * VT_S + kbase + lg * 8;
            vf0[i] = *reinterpret_cast<const bf16x8*>(vr);
            vf1[i] = *reinterpret_cast<const bf16x8*>(vr + 32);
        }

        // ---- QK^T ----
        f32x4 sfr[4];
        __builtin_amdgcn_s_setprio(1);
        #pragma unroll
        for (int f = 0; f < 4; f++) {
            int key = kbase + f * 16 + ll;
            int keyc = min(key, T_TOK - 1);
            const u16* krow = qkvb + (size_t)keyc * 1536 + 512 + h * HD + lg * 8;
            bf16x8 kf0 = *reinterpret_cast<const bf16x8*>(krow);
            bf16x8 kf1 = *reinterpret_cast<const bf16x8*>(krow + 32);
            f32x4 acc = (f32x4){0.f, 0.f, 0.f, 0.f};
            acc = __builtin_amdgcn_mfma_f32_16x16x32_bf16(qf0, kf0, acc, 0, 0, 0);
            acc = __builtin_amdgcn_mfma_f32_16x16x32_bf16(qf1, kf1, acc, 0, 0, 0);
            sfr[f] = acc;
        }
        __builtin_amdgcn_s_setprio(0);

        // ---- row max (fast path: no masking needed) ----
        float rmax[4];
        #pragma unroll
        for (int r = 0; r < 4; r++) rmax[r] = -INFINITY;
        if (!needmask) {
            #pragma unroll
            for (int f = 0; f < 4; f++)
                #pragma unroll
                for (int r = 0; r < 4; r++) rmax[r] = fmaxf(rmax[r], sfr[f][r]);
        } else {
            #pragma unroll
            for (int f = 0; f < 4; f++) {
                int key = kbase + f * 16 + ll;
                int sk = (key < T_TOK) ? step_of(key) : 0x7fffffff;
                #pragma unroll
                for (int r = 0; r < 4; r++) {
                    float v = sfr[f][r];
                    v = (sk <= sq[r]) ? v : -INFINITY;
                    sfr[f][r] = v;
                    rmax[r] = fmaxf(rmax[r], v);
                }
            }
        }
        #pragma unroll
        for (int r = 0; r < 4; r++) {
            float v = rmax[r];
            v = fmaxf(v, __shfl_xor(v, 1));
            v = fmaxf(v, __shfl_xor(v, 2));
            v = fmaxf(v, __shfl_xor(v, 4));
            v = fmaxf(v, __shfl_xor(v, 8));
            rmax[r] = v;
        }
        // ---- defer-max: rescale only when some row grew past THR=8 ----
        bool upd = false;
        #pragma unroll
        for (int r = 0; r < 4; r++) upd = upd || (rmax[r] > m[r] + 8.f);
        if (__any(upd)) {
            float csc[4];
            #pragma unroll
            for (int r = 0; r < 4; r++) {
                float mn2 = fmaxf(m[r], rmax[r]);
                float c = (m[r] == -INFINITY) ? 0.f : __expf(m[r] - mn2);
                csc[r] = c;
                m[r] = mn2;
                lsum[r] *= c;
            }
            #pragma unroll
            for (int i = 0; i < 4; i++)
                #pragma unroll
                for (int r = 0; r < 4; r++) oacc[i][r] *= csc[r];
        }
        // ---- P = exp(S - m) -> bf16 -> LDS (A-frag layout) ----
        if (!needmask) {
            #pragma unroll
            for (int f = 0; f < 4; f++) {
                #pragma unroll
                for (int r = 0; r < 4; r++) {
                    float p = __expf(sfr[f][r] - m[r]);
                    lsum[r] += p;
                    plds[lg * 4 + r][f * 16 + ll] = f2bf(p);
                }
            }
        } else {
            #pragma unroll
            for (int f = 0; f < 4; f++) {
                #pragma unroll
                for (int r = 0; r < 4; r++) {
                    float sv = sfr[f][r];
                    float p = (sv == -INFINITY) ? 0.f : __expf(sv - m[r]);
                    lsum[r] += p;
                    plds[lg * 4 + r][f * 16 + ll] = f2bf(p);
                }
            }
        }
        // ---- PV (same-wave LDS RAW: compiler inserts lgkmcnt wait) ----
        __builtin_amdgcn_s_setprio(1);
        {
            bf16x8 pf0 = *reinterpret_cast<const bf16x8*>(&plds[ll][lg * 8]);
            #pragma unroll
            for (int i = 0; i < 4; i++)
                oacc[i] = __builtin_amdgcn_mfma_f32_16x16x32_bf16(pf0, vf0[i], oacc[i], 0, 0, 0);
            bf16x8 pf1 = *reinterpret_cast<const bf16x8*>(&plds[ll][32 + lg * 8]);
            #pragma unroll
            for (int i = 0; i < 4; i++)
                oacc[i] = __builtin_amdgcn_mfma_f32_16x16x32_bf16(pf1, vf1[i], oacc[i], 0, 0, 0);
        }
        __builtin_amdgcn_s_setprio(0);
    }

    // row-sum lsum across 16 col-lanes
    #pragma unroll
    for (int r = 0; r < 4; r++) {
        float v = lsum[r];
        v += __shfl_xor(v, 1);
        v += __shfl_xor(v, 2);
        v += __shfl_xor(v, 4);
        v += __shfl_xor(v, 8);
        lsum[r] = v;
    }
    // write partials (unnormalized)
    #pragma unroll
    for (int r = 0; r < 4; r++) {
        int q = q0 + lg * 4 + r;
        size_t ob = ((size_t)(z * 8 + h) * 3600 + q) * 64;
        #pragma unroll
        for (int i = 0; i < 4; i++)
            Opart[ob + i * 16 + ll] = f2bf(oacc[i][r]);
        if (ll == 0) {
            size_t mi = ((size_t)(z * 8 + h) * 3600 + q) * 2;
            mlpart[mi]     = m[r];
            mlpart[mi + 1] = lsum[r];
        }
    }
}

// ---------------- merge KSPLIT partials -> obb (bf16) ----------------------
__global__ __launch_bounds__(256) void attn_merge_kernel(
    const u16* __restrict__ Opart, const float* __restrict__ mlpart,
    u16* __restrict__ obb)
{
    int t = threadIdx.x;
    int h = blockIdx.y;
    int q = blockIdx.x * 64 + (t >> 2);
    if (q >= T_TOK) return;
    int dg = (t & 3) * 16;
    float mz[KSPLIT], lz[KSPLIT];
    #pragma unroll
    for (int zz = 0; zz < KSPLIT; zz++) {
        size_t mi = ((size_t)(zz * 8 + h) * 3600 + q) * 2;
        mz[zz] = mlpart[mi];
        lz[zz] = mlpart[mi + 1];
    }
    float M = -INFINITY;
    #pragma unroll
    for (int zz = 0; zz < KSPLIT; zz++) if (lz[zz] > 0.f) M = fmaxf(M, mz[zz]);
    float wz[KSPLIT], den = 0.f;
    #pragma unroll
    for (int zz = 0; zz < KSPLIT; zz++) {
        wz[zz] = (lz[zz] > 0.f) ? __expf(mz[zz] - M) : 0.f;
        den += wz[zz] * lz[zz];
    }
    float inv = (den > 0.f) ? 1.f / den : 0.f;
    u16* op = obb + (size_t)q * D_ + h * HD + dg;
    #pragma unroll
    for (int e = 0; e < 16; e++) {
        float o = 0.f;
        #pragma unroll
        for (int zz = 0; zz < KSPLIT; zz++)
            o += bf2f(Opart[((size_t)(zz * 8 + h) * 3600 + q) * 64 + dg + e]) * wz[zz];
        op[e] = f2bf(o * inv);
    }
}

// ---------------- fused residual add + LayerNorm (emits fp32 x + bf16 xb) --
__global__ __launch_bounds__(256) void add_ln_kernel(
    float* __restrict__ x, const float* __restrict__ r,
    const float* __restrict__ g, const float* __restrict__ b,
    u16* __restrict__ xb)
{
    int row = blockIdx.x, t = threadIdx.x;
    size_t base = (size_t)row * D_;
    float v0 = x[base + t] + r[base + t];
    float v1 = x[base + t + 256] + r[base + t + 256];
    float s = v0 + v1, ss = v0 * v0 + v1 * v1;
    #pragma unroll
    for (int off = 32; off > 0; off >>= 1) {
        s  += __shfl_xor(s, off);
        ss += __shfl_xor(ss, off);
    }
    __shared__ float rs[4], rss[4];
    int w = t >> 6;
    if ((t & 63) == 0) { rs[w] = s; rss[w] = ss; }
    __syncthreads();
    s  = rs[0] + rs[1] + rs[2] + rs[3];
    ss = rss[0] + rss[1] + rss[2] + rss[3];
    float mean = s * (1.f / 512.f);
    float var = ss * (1.f / 512.f) - mean * mean;
    float rstd = rsqrtf(var + 1e-5f);
    float o0 = (v0 - mean) * rstd * g[t]       + b[t];
    float o1 = (v1 - mean) * rstd * g[t + 256] + b[t + 256];
    x[base + t]        = o0;
    x[base + t + 256]  = o1;
    xb[base + t]       = f2bf(o0);
    xb[base + t + 256] = f2bf(o1);
}

// ---------------------------------------------------------------------------
extern "C" void kernel_launch(void* const* d_in, const int* in_sizes, int n_in,
                              void* d_out, int out_size, void* d_ws, size_t ws_size,
                              hipStream_t stream)
{
    const float* player_xs = (const float*)d_in[0];
    const float* player_ys = (const float*)d_in[1];
    const float* player_hs = (const float*)d_in[2];
    const float* ball_xs   = (const float*)d_in[3];
    const float* ball_ys   = (const float*)d_in[4];
    const float* ball_zs   = (const float*)d_in[5];
    const float* emb_table = (const float*)d_in[6];
    const float* ball_emb  = (const float*)d_in[7];
    const float* cls_emb   = (const float*)d_in[8];
    const float* pW0 = (const float*)d_in[9];   const float* pb0 = (const float*)d_in[10];
    const float* pW1 = (const float*)d_in[11];  const float* pb1 = (const float*)d_in[12];
    const float* pW2 = (const float*)d_in[13];  const float* pb2 = (const float*)d_in[14];
    const float* bW0 = (const float*)d_in[15];  const float* bb0 = (const float*)d_in[16];
    const float* bW1 = (const float*)d_in[17];  const float* bb1 = (const float*)d_in[18];
    const float* bW2 = (const float*)d_in[19];  const float* bb2 = (const float*)d_in[20];
    const float* Wqkv = (const float*)d_in[21]; const float* bqkv = (const float*)d_in[22];
    const float* Wo  = (const float*)d_in[23];  const float* bo  = (const float*)d_in[24];
    const float* W1f = (const float*)d_in[25];  const float* b1f = (const float*)d_in[26];
    const float* W2f = (const float*)d_in[27];  const float* b2f = (const float*)d_in[28];
    const float* g1  = (const float*)d_in[29];  const float* be1 = (const float*)d_in[30];
    const float* g2  = (const float*)d_in[31];  const float* be2 = (const float*)d_in[32];
    const float* cpW = (const float*)d_in[33];  const float* cpb = (const float*)d_in[34];
    const float* cbW = (const float*)d_in[35];  const float* cbb = (const float*)d_in[36];
    const float* csW = (const float*)d_in[37];  const float* csb = (const float*)d_in[38];
    const int* pidx = (const int*)d_in[39];

    // workspace (51.6 MB): x | big | ob-region | tmp2
    float* x    = (float*)d_ws;            // 1,843,200 f32
    float* big  = x + 1843200;             // 7,372,800 f32
    float* obr  = big + 7372800;           // 1,843,200 f32 (obb bf16 | xb bf16)
    float* tmp2 = obr + 1843200;           // 1,843,200 f32
    // aliases inside big:
    u16*   qkvb   = (u16*)big;             // [3600][1536] bf16 = 2,764,800 slots
    u16*   Opart  = (u16*)(big + 2764800); // [4][8][3600][64] bf16 = 3,686,400 slots
    float* mlpart = big + 6451200;         // [4][8][3600][2] f32 = 230,400 (ends 6,681,600)
    u16*   wb     = (u16*)(big + 6681600); // bf16 weight scratch (<=1,382,400 u16)
    u16*   ff1b   = (u16*)big;             // [3600][2048] bf16 (FF phase)
    u16*   obb    = (u16*)obr;             // [3600][512] bf16
    u16*   xb     = (u16*)(obr + 921600);  // [3600][512] bf16
    u16*   vt     = (u16*)tmp2;            // [512][3648] bf16 (dead once Wo writes tmp2)
    // token-MLP temporaries (big free before layers)
    float* IN = big;                       // 3600*24
    float* h0 = big + 131072;              // 3600*128
    float* h1 = big + 131072 + 460800;     // 3600*256
    float* out = (float*)d_out;

    gather_kernel<<<15, 256, 0, stream>>>(
        player_xs, player_ys, player_hs, ball_xs, ball_ys, ball_zs,
        emb_table, ball_emb, cls_emb, pidx, IN, x);

    gemm_mfma<1,0,0,0,0><<<dim3(24, 1), 256, 0, stream>>>(IN,            pW0, pb0, h0,            3000, 128, 23, 24, 1.f);
    gemm_mfma<1,0,0,0,0><<<dim3(3,  1), 256, 0, stream>>>(IN + 3000*24,  bW0, bb0, h0 + 3000*128,  300, 128, 23, 24, 1.f);
    gemm_mfma<1,0,0,0,0><<<dim3(24, 2), 256, 0, stream>>>(h0,            pW1, pb1, h1,            3000, 256, 128, 128, 1.f);
    gemm_mfma<1,0,0,0,0><<<dim3(3,  2), 256, 0, stream>>>(h0 + 3000*128, bW1, bb1, h1 + 3000*256,  300, 256, 128, 128, 1.f);
    gemm_mfma<0,0,0,0,0><<<dim3(24, 4), 256, 0, stream>>>(h1,            pW2, pb2, x,             3000, 512, 256, 256, SQRT512);
    gemm_mfma<0,0,0,0,0><<<dim3(3,  4), 256, 0, stream>>>(h1 + 3000*256, bW2, bb2, x + 3000*512,   300, 512, 256, 256, SQRT512);

    // initial xb = bf16(x)
    w2b_kernel<<<1024, 256, 0, stream>>>(x, xb, 1843200 / 4);

    for (int l = 0; l < 4; l++) {
        const float* Wqkv_l = Wqkv + (size_t)l * 1536 * 512;
        const float* bqkv_l = bqkv + (size_t)l * 1536;
        const float* Wo_l   = Wo   + (size_t)l * 512 * 512;
        const float* bo_l   = bo   + (size_t)l * 512;
        const float* W1f_l  = W1f  + (size_t)l * 2048 * 512;
        const float* b1f_l  = b1f  + (size_t)l * 2048;
        const float* W2f_l  = W2f  + (size_t)l * 512 * 2048;
        const float* b2f_l  = b2f  + (size_t)l * 512;

        w2b_kernel<<<768, 256, 0, stream>>>(Wqkv_l, wb, 1536 * 512 / 4);
        gemm_mfma<0,1,1,1,1><<<dim3(29, 12), 256, 0, stream>>>(xb, wb, bqkv_l, qkvb, 3600, 1536, 512, 512, 1.f);
        vtrans_kernel<<<dim3(57, 8), 256, 0, stream>>>(qkvb, vt);
        attn_mfma_kernel<<<dim3(225, 8, KSPLIT), 64, 0, stream>>>(qkvb, vt, Opart, mlpart);
        attn_merge_kernel<<<dim3(57, 8), 256, 0, stream>>>(Opart, mlpart, obb);
        w2b_kernel<<<256, 256, 0, stream>>>(Wo_l, wb, 512 * 512 / 4);
        gemm_mfma<0,0,1,1,0><<<dim3(29, 4), 256, 0, stream>>>(obb, wb, bo_l, tmp2, 3600, 512, 512, 512, 1.f);
        add_ln_kernel<<<3600, 256, 0, stream>>>(x, tmp2, g1 + (size_t)l * 512, be1 + (size_t)l * 512, xb);
        w2b_kernel<<<1024, 256, 0, stream>>>(W1f_l, wb, 2048 * 512 / 4);
        gemm_mfma<1,1,1,1,0><<<dim3(29, 16), 256, 0, stream>>>(xb, wb, b1f_l, ff1b, 3600, 2048, 512, 512, 1.f);
        w2b_kernel<<<1024, 256, 0, stream>>>(W2f_l, wb, 512 * 2048 / 4);
        gemm_mfma<0,0,1,1,0><<<dim3(29, 4), 256, 0, stream>>>(ff1b, wb, b2f_l, tmp2, 3600, 512, 2048, 2048, 1.f);
        add_ln_kernel<<<3600, 256, 0, stream>>>(x, tmp2, g2 + (size_t)l * 512, be2 + (size_t)l * 512, xb);
    }

    w2b_kernel<<<64, 256, 0, stream>>>(cpW, wb, 121 * 512 / 4);
    gemm_mfma<0,0,1,1,0><<<dim3(29, 1),  256, 0, stream>>>(xb, wb, cpb, out + 0,       3600, 121,  512, 512, 1.f);
    w2b_kernel<<<512, 256, 0, stream>>>(cbW, wb, 1331 * 512 / 4);
    gemm_mfma<0,0,1,1,0><<<dim3(29, 11), 256, 0, stream>>>(xb, wb, cbb, out + 435600,  3600, 1331, 512, 512, 1.f);
    w2b_kernel<<<8, 256, 0, stream>>>(csW, wb, 10 * 512 / 4);
    gemm_mfma<0,0,1,1,0><<<dim3(29, 1),  256, 0, stream>>>(xb, wb, csb, out + 5227200, 3600, 10,   512, 512, 1.f);
}

// Round 9
// 1338.136 us; speedup vs baseline: 5.5097x; 1.0191x over previous
//
#include <hip/hip_runtime.h>
#include <hip/hip_bf16.h>

typedef unsigned short u16;
typedef __attribute__((ext_vector_type(8))) short bf16x8;
typedef __attribute__((ext_vector_type(4))) float f32x4;

#define T_TOK 3600
#define D_    512
#define H_    8
#define HD    64
#define NKT   57    // ceil(3600/64)
#define VT_S  3648  // padded token stride for Vt
#define KSPLIT 4
#define SQRT512 22.627416997969522f

__device__ __forceinline__ u16 f2bf(float f) {
    unsigned int x = __float_as_uint(f);
    unsigned int lsb = (x >> 16) & 1;
    return (u16)((x + 0x7fffu + lsb) >> 16);
}
__device__ __forceinline__ float bf2f(u16 u) {
    return __uint_as_float(((unsigned int)u) << 16);
}
// timestep of token: players [0,3000) -> i/10, ball [3000,3300), cls [3300,3600)
__device__ __forceinline__ int step_of(int i) {
    return (i < 3000) ? (i / 10) : ((i < 3300) ? (i - 3000) : (i - 3300));
}
// min/max step of key-tile [kbase, kbase+64)
__device__ __forceinline__ void tile_minmax(int kbase, int& mn, int& mx) {
    int a = kbase, b = min(kbase + 63, T_TOK - 1);
    mn = 0x7fffffff; mx = -1;
    if (a < 3000)              { mn = min(mn, a / 10);              mx = max(mx, min(b, 2999) / 10); }
    if (b >= 3000 && a < 3300) { mn = min(mn, max(a, 3000) - 3000); mx = max(mx, min(b, 3299) - 3000); }
    if (b >= 3300)             { mn = min(mn, max(a, 3300) - 3300); mx = max(mx, b - 3300); }
}

// ---------------- gather: build IN[3600][24] + fill cls rows of x ----------
__global__ __launch_bounds__(256) void gather_kernel(
    const float* __restrict__ pxs, const float* __restrict__ pys, const float* __restrict__ phs,
    const float* __restrict__ bxs, const float* __restrict__ bys, const float* __restrict__ bzs,
    const float* __restrict__ emb_table, const float* __restrict__ ball_emb,
    const float* __restrict__ cls_emb, const int* __restrict__ pidx,
    float* __restrict__ IN, float* __restrict__ x)
{
    int g = blockIdx.x * 256 + threadIdx.x;   // 15*256 = 3840
    if (g < 3300) {
        float* row = IN + g * 24;
        if (g < 3000) {
            int id = pidx[g];
            #pragma unroll
            for (int e = 0; e < 20; e++) row[e] = emb_table[id * 20 + e];
            row[20] = pxs[g]; row[21] = pys[g]; row[22] = phs[g];
        } else {
            int b = g - 3000;
            #pragma unroll
            for (int e = 0; e < 20; e++) row[e] = ball_emb[e];
            row[20] = bxs[b]; row[21] = bys[b]; row[22] = bzs[b];
        }
        row[23] = 0.f;
    }
    for (int i = g; i < 300 * 512; i += 3840) {
        x[3300 * 512 + i] = cls_emb[i & 511];
    }
}

// ---------------- fp32 -> bf16 convert (grid-stride, float4) ---------------
__global__ __launch_bounds__(256) void w2b_kernel(
    const float* __restrict__ src, u16* __restrict__ dst, int n4)
{
    int stride = gridDim.x * 256;
    for (int i = blockIdx.x * 256 + threadIdx.x; i < n4; i += stride) {
        float4 v = reinterpret_cast<const float4*>(src)[i];
        ushort4 o;
        o.x = f2bf(v.x); o.y = f2bf(v.y); o.z = f2bf(v.z); o.w = f2bf(v.w);
        reinterpret_cast<ushort4*>(dst)[i] = o;
    }
}

// ---------------- fused per-layer weight convert (Wqkv|Wo|W1f|W2f) --------
// float4 ranges: qkv 196608, wo 65536, w1f 262144, w2f 262144; total 786432.
__global__ __launch_bounds__(256) void w2b4_kernel(
    const float* __restrict__ s0, const float* __restrict__ s1,
    const float* __restrict__ s2, const float* __restrict__ s3,
    u16* __restrict__ dst)
{
    int stride = gridDim.x * 256;
    for (int i = blockIdx.x * 256 + threadIdx.x; i < 786432; i += stride) {
        const float4* src;
        int j = i;
        if (j < 196608)      { src = (const float4*)s0; }
        else if (j < 262144) { src = (const float4*)s1; j -= 196608; }
        else if (j < 524288) { src = (const float4*)s2; j -= 262144; }
        else                 { src = (const float4*)s3; j -= 524288; }
        float4 v = src[j];
        ushort4 o;
        o.x = f2bf(v.x); o.y = f2bf(v.y); o.z = f2bf(v.z); o.w = f2bf(v.w);
        reinterpret_cast<ushort4*>(dst)[i] = o;
    }
}

// ---------------- MFMA GEMM ------------------------------------------------
// C[M,N] = act(A[M,K] * W[N,K]^T + bias) * scale.  A/W fp32 or bf16; C fp32 or bf16.
__device__ __forceinline__ void stage_f32(
    const float* __restrict__ src, int nrows, int K, int lda,
    int r0, int kk, int srow, int scg, u16* dst)
{
    u16 tmp[16];
    int rr = r0 + srow;
    if (rr < nrows) {
        if (((lda & 3) == 0) && (kk + scg + 16 <= K)) {
            const float4* p = reinterpret_cast<const float4*>(src + (size_t)rr * lda + kk + scg);
            #pragma unroll
            for (int q = 0; q < 4; q++) {
                float4 v = p[q];
                tmp[q*4+0] = f2bf(v.x); tmp[q*4+1] = f2bf(v.y);
                tmp[q*4+2] = f2bf(v.z); tmp[q*4+3] = f2bf(v.w);
            }
        } else {
            #pragma unroll
            for (int e = 0; e < 16; e++) {
                int kc = kk + scg + e;
                tmp[e] = (kc < K) ? f2bf(src[(size_t)rr * lda + kc]) : (u16)0;
            }
        }
    } else {
        #pragma unroll
        for (int e = 0; e < 16; e++) tmp[e] = 0;
    }
    *reinterpret_cast<bf16x8*>(dst)     = *reinterpret_cast<const bf16x8*>(&tmp[0]);
    *reinterpret_cast<bf16x8*>(dst + 8) = *reinterpret_cast<const bf16x8*>(&tmp[8]);
}

__device__ __forceinline__ void stage_b16(
    const u16* __restrict__ src, int nrows, int lda,
    int r0, int kk, int srow, int scg, u16* dst)
{
    int rr = r0 + srow;
    bf16x8 a = {}, b = {};
    if (rr < nrows) {
        const bf16x8* p = reinterpret_cast<const bf16x8*>(src + (size_t)rr * lda + kk + scg);
        a = p[0]; b = p[1];
    }
    *reinterpret_cast<bf16x8*>(dst)     = a;
    *reinterpret_cast<bf16x8*>(dst + 8) = b;
}

template<int RELU, int BF16OUT, int ABF16, int BBF16, int QSCALE>
__global__ __launch_bounds__(256) void gemm_mfma(
    const void* __restrict__ Av, const void* __restrict__ Wv,
    const float* __restrict__ bias, void* __restrict__ Cv,
    int M, int N, int K, int lda, float scale)
{
    __shared__ u16 As[128][40];
    __shared__ u16 Bs[128][40];
    int t = threadIdx.x;
    int w = t >> 6, l = t & 63;
    int ll = l & 15, lg = l >> 4;
    int wr = w >> 1, wc = w & 1;
    int m0 = blockIdx.x * 128, n0 = blockIdx.y * 128;
    int srow = t >> 1;
    int scg  = (t & 1) * 16;

    f32x4 acc[4][4];
    #pragma unroll
    for (int i = 0; i < 4; i++)
        #pragma unroll
        for (int j = 0; j < 4; j++) acc[i][j] = (f32x4){0.f, 0.f, 0.f, 0.f};

    for (int kk = 0; kk < K; kk += 32) {
        if (ABF16) stage_b16((const u16*)Av, M, lda, m0, kk, srow, scg, &As[srow][scg]);
        else       stage_f32((const float*)Av, M, K, lda, m0, kk, srow, scg, &As[srow][scg]);
        if (BBF16) stage_b16((const u16*)Wv, N, K, n0, kk, srow, scg, &Bs[srow][scg]);
        else       stage_f32((const float*)Wv, N, K, K, n0, kk, srow, scg, &Bs[srow][scg]);
        __syncthreads();
        bf16x8 af[4], bf[4];
        #pragma unroll
        for (int i = 0; i < 4; i++)
            af[i] = *reinterpret_cast<const bf16x8*>(&As[wr*64 + i*16 + ll][lg*8]);
        #pragma unroll
        for (int j = 0; j < 4; j++)
            bf[j] = *reinterpret_cast<const bf16x8*>(&Bs[wc*64 + j*16 + ll][lg*8]);
        #pragma unroll
        for (int i = 0; i < 4; i++)
            #pragma unroll
            for (int j = 0; j < 4; j++)
                acc[i][j] = __builtin_amdgcn_mfma_f32_16x16x32_bf16(af[i], bf[j], acc[i][j], 0, 0, 0);
        __syncthreads();
    }

    float bv[4];
    #pragma unroll
    for (int j = 0; j < 4; j++) {
        int n = n0 + wc*64 + j*16 + ll;
        bv[j] = (n < N) ? bias[n] : 0.f;
    }
    #pragma unroll
    for (int i = 0; i < 4; i++) {
        #pragma unroll
        for (int r = 0; r < 4; r++) {
            int m = m0 + wr*64 + i*16 + lg*4 + r;
            if (m >= M) continue;
            #pragma unroll
            for (int j = 0; j < 4; j++) {
                int n = n0 + wc*64 + j*16 + ll;
                if (n >= N) continue;
                float v = acc[i][j][r] + bv[j];
                if (RELU) v = fmaxf(v, 0.f);
                v *= scale;
                if (QSCALE && n < 512) v *= 0.125f;   // fold 1/sqrt(hd) into Q
                if (BF16OUT) ((u16*)Cv)[(size_t)m * N + n] = f2bf(v);
                else         ((float*)Cv)[(size_t)m * N + n] = v;
            }
        }
    }
}

// ---------------- V transpose: vt[h*64+d][tok] = qkvb[tok][1024+h*64+d] ----
__global__ __launch_bounds__(256) void vtrans_kernel(
    const u16* __restrict__ qkvb, u16* __restrict__ vt)
{
    __shared__ u16 tile[64][72];
    int t = threadIdx.x;
    int tok0 = blockIdx.x * 64;
    int h = blockIdx.y;
    {
        int i = t >> 2, c16 = (t & 3) * 16;
        int tok = tok0 + i;
        bf16x8 a = {}, b = {};
        if (tok < T_TOK) {
            const bf16x8* p = reinterpret_cast<const bf16x8*>(qkvb + (size_t)tok * 1536 + 1024 + h * HD + c16);
            a = p[0]; b = p[1];
        }
        *reinterpret_cast<bf16x8*>(&tile[i][c16])     = a;
        *reinterpret_cast<bf16x8*>(&tile[i][c16 + 8]) = b;
    }
    __syncthreads();
    {
        int d = t >> 2, i0 = (t & 3) * 16;
        u16 tt[16];
        #pragma unroll
        for (int e = 0; e < 16; e++) tt[e] = tile[i0 + e][d];
        u16* dst = vt + (size_t)(h * HD + d) * VT_S + tok0 + i0;
        *reinterpret_cast<bf16x8*>(dst)     = *reinterpret_cast<const bf16x8*>(&tt[0]);
        *reinterpret_cast<bf16x8*>(dst + 8) = *reinterpret_cast<const bf16x8*>(&tt[8]);
    }
}

// ---------------- MFMA flash attention, 1 wave per 16 queries --------------
// grid (225, 8, KSPLIT); block 64 = 1 wave. LPT: heavy q-tiles launch first.
// K register double-buffer: next tile's K loads issued before current compute.
__global__ __launch_bounds__(64) void attn_mfma_kernel(
    const u16* __restrict__ qkvb, const u16* __restrict__ vt,
    u16* __restrict__ Opart, float* __restrict__ mlpart)
{
    __shared__ u16 plds[16][68];
    int l = threadIdx.x;
    int lg = l >> 4, ll = l & 15;
    int h = blockIdx.y;
    int z = blockIdx.z;
    int q0 = (224 - (int)blockIdx.x) * 16;   // LPT order

    int qa = q0 + ll;
    const u16* qrow = qkvb + (size_t)qa * 1536 + h * HD + lg * 8;
    bf16x8 qf0 = *reinterpret_cast<const bf16x8*>(qrow);
    bf16x8 qf1 = *reinterpret_cast<const bf16x8*>(qrow + 32);

    int sq[4];
    #pragma unroll
    for (int r = 0; r < 4; r++) sq[r] = step_of(q0 + lg * 4 + r);
    int sqa = step_of(qa);
    int smax = sqa, smin = sqa;
    #pragma unroll
    for (int off = 1; off < 16; off <<= 1) {
        smax = max(smax, __shfl_xor(smax, off));
        smin = min(smin, __shfl_xor(smin, off));
    }

    f32x4 oacc[4];
    #pragma unroll
    for (int i = 0; i < 4; i++) oacc[i] = (f32x4){0.f, 0.f, 0.f, 0.f};
    float m[4], lsum[4];
    #pragma unroll
    for (int r = 0; r < 4; r++) { m[r] = -INFINITY; lsum[r] = 0.f; }

    // scan to first visible tile
    int kt = z, mxc = -1;
    #pragma unroll 1
    for (; kt < NKT; kt += KSPLIT) {
        int mn, mx;
        tile_minmax(kt * 64, mn, mx);
        if (mn <= smax) { mxc = mx; break; }
    }
    // load first K tile
    bf16x8 kc0[4], kc1[4];
    if (kt < NKT) {
        int kbase = kt * 64;
        #pragma unroll
        for (int f = 0; f < 4; f++) {
            int keyc = min(kbase + f * 16 + ll, T_TOK - 1);
            const u16* kr = qkvb + (size_t)keyc * 1536 + 512 + h * HD + lg * 8;
            kc0[f] = *reinterpret_cast<const bf16x8*>(kr);
            kc1[f] = *reinterpret_cast<const bf16x8*>(kr + 32);
        }
    }

    #pragma unroll 1
    while (kt < NKT) {
        int kbase = kt * 64;
        bool needmask = (mxc > smin) || (kbase + 64 > T_TOK);

        // scan for next visible tile
        int ktn = kt + KSPLIT, mxn = -1;
        #pragma unroll 1
        for (; ktn < NKT; ktn += KSPLIT) {
            int mn, mx;
            tile_minmax(ktn * 64, mn, mx);
            if (mn <= smax) { mxn = mx; break; }
        }
        // prefetch next K tile (latency hidden under this tile's compute)
        bf16x8 kn0[4], kn1[4];
        {
            int kb2 = (ktn < NKT) ? ktn * 64 : kbase;
            #pragma unroll
            for (int f = 0; f < 4; f++) {
                int keyc = min(kb2 + f * 16 + ll, T_TOK - 1);
                const u16* kr = qkvb + (size_t)keyc * 1536 + 512 + h * HD + lg * 8;
                kn0[f] = *reinterpret_cast<const bf16x8*>(kr);
                kn1[f] = *reinterpret_cast<const bf16x8*>(kr + 32);
            }
        }
        // V preload (consumed after softmax; latency hidden)
        bf16x8 vf0[4], vf1[4];
        #pragma unroll
        for (int i = 0; i < 4; i++) {
            const u16* vr = vt + (size_t)(h * HD + i * 16 + ll) * VT_S + kbase + lg * 8;
            vf0[i] = *reinterpret_cast<const bf16x8*>(vr);
            vf1[i] = *reinterpret_cast<const bf16x8*>(vr + 32);
        }

        // ---- QK^T (uses pre-loaded kc) ----
        f32x4 sfr[4];
        __builtin_amdgcn_s_setprio(1);
        #pragma unroll
        for (int f = 0; f < 4; f++) {
            f32x4 acc = (f32x4){0.f, 0.f, 0.f, 0.f};
            acc = __builtin_amdgcn_mfma_f32_16x16x32_bf16(qf0, kc0[f], acc, 0, 0, 0);
            acc = __builtin_amdgcn_mfma_f32_16x16x32_bf16(qf1, kc1[f], acc, 0, 0, 0);
            sfr[f] = acc;
        }
        __builtin_amdgcn_s_setprio(0);

        // ---- row max (fast path: no masking needed) ----
        float rmax[4];
        #pragma unroll
        for (int r = 0; r < 4; r++) rmax[r] = -INFINITY;
        if (!needmask) {
            #pragma unroll
            for (int f = 0; f < 4; f++)
                #pragma unroll
                for (int r = 0; r < 4; r++) rmax[r] = fmaxf(rmax[r], sfr[f][r]);
        } else {
            #pragma unroll
            for (int f = 0; f < 4; f++) {
                int key = kbase + f * 16 + ll;
                int sk = (key < T_TOK) ? step_of(key) : 0x7fffffff;
                #pragma unroll
                for (int r = 0; r < 4; r++) {
                    float v = sfr[f][r];
                    v = (sk <= sq[r]) ? v : -INFINITY;
                    sfr[f][r] = v;
                    rmax[r] = fmaxf(rmax[r], v);
                }
            }
        }
        #pragma unroll
        for (int r = 0; r < 4; r++) {
            float v = rmax[r];
            v = fmaxf(v, __shfl_xor(v, 1));
            v = fmaxf(v, __shfl_xor(v, 2));
            v = fmaxf(v, __shfl_xor(v, 4));
            v = fmaxf(v, __shfl_xor(v, 8));
            rmax[r] = v;
        }
        // ---- defer-max: rescale only when some row grew past THR=8 ----
        bool upd = false;
        #pragma unroll
        for (int r = 0; r < 4; r++) upd = upd || (rmax[r] > m[r] + 8.f);
        if (__any(upd)) {
            float csc[4];
            #pragma unroll
            for (int r = 0; r < 4; r++) {
                float mn2 = fmaxf(m[r], rmax[r]);
                float c = (m[r] == -INFINITY) ? 0.f : __expf(m[r] - mn2);
                csc[r] = c;
                m[r] = mn2;
                lsum[r] *= c;
            }
            #pragma unroll
            for (int i = 0; i < 4; i++)
                #pragma unroll
                for (int r = 0; r < 4; r++) oacc[i][r] *= csc[r];
        }
        // ---- P = exp(S - m) -> bf16 -> LDS (A-frag layout) ----
        if (!needmask) {
            #pragma unroll
            for (int f = 0; f < 4; f++) {
                #pragma unroll
                for (int r = 0; r < 4; r++) {
                    float p = __expf(sfr[f][r] - m[r]);
                    lsum[r] += p;
                    plds[lg * 4 + r][f * 16 + ll] = f2bf(p);
                }
            }
        } else {
            #pragma unroll
            for (int f = 0; f < 4; f++) {
                #pragma unroll
                for (int r = 0; r < 4; r++) {
                    float sv = sfr[f][r];
                    float p = (sv == -INFINITY) ? 0.f : __expf(sv - m[r]);
                    lsum[r] += p;
                    plds[lg * 4 + r][f * 16 + ll] = f2bf(p);
                }
            }
        }
        // ---- PV (same-wave LDS RAW: compiler inserts lgkmcnt wait) ----
        __builtin_amdgcn_s_setprio(1);
        {
            bf16x8 pf0 = *reinterpret_cast<const bf16x8*>(&plds[ll][lg * 8]);
            #pragma unroll
            for (int i = 0; i < 4; i++)
                oacc[i] = __builtin_amdgcn_mfma_f32_16x16x32_bf16(pf0, vf0[i], oacc[i], 0, 0, 0);
            bf16x8 pf1 = *reinterpret_cast<const bf16x8*>(&plds[ll][32 + lg * 8]);
            #pragma unroll
            for (int i = 0; i < 4; i++)
                oacc[i] = __builtin_amdgcn_mfma_f32_16x16x32_bf16(pf1, vf1[i], oacc[i], 0, 0, 0);
        }
        __builtin_amdgcn_s_setprio(0);

        // advance: promote prefetched K
        kt = ktn; mxc = mxn;
        #pragma unroll
        for (int f = 0; f < 4; f++) { kc0[f] = kn0[f]; kc1[f] = kn1[f]; }
    }

    // row-sum lsum across 16 col-lanes
    #pragma unroll
    for (int r = 0; r < 4; r++) {
        float v = lsum[r];
        v += __shfl_xor(v, 1);
        v += __shfl_xor(v, 2);
        v += __shfl_xor(v, 4);
        v += __shfl_xor(v, 8);
        lsum[r] = v;
    }
    // write partials (unnormalized)
    #pragma unroll
    for (int r = 0; r < 4; r++) {
        int q = q0 + lg * 4 + r;
        size_t ob = ((size_t)(z * 8 + h) * 3600 + q) * 64;
        #pragma unroll
        for (int i = 0; i < 4; i++)
            Opart[ob + i * 16 + ll] = f2bf(oacc[i][r]);
        if (ll == 0) {
            size_t mi = ((size_t)(z * 8 + h) * 3600 + q) * 2;
            mlpart[mi]     = m[r];
            mlpart[mi + 1] = lsum[r];
        }
    }
}

// ---------------- merge KSPLIT partials -> obb (bf16) ----------------------
__global__ __launch_bounds__(256) void attn_merge_kernel(
    const u16* __restrict__ Opart, const float* __restrict__ mlpart,
    u16* __restrict__ obb)
{
    int t = threadIdx.x;
    int h = blockIdx.y;
    int q = blockIdx.x * 64 + (t >> 2);
    if (q >= T_TOK) return;
    int dg = (t & 3) * 16;
    float mz[KSPLIT], lz[KSPLIT];
    #pragma unroll
    for (int zz = 0; zz < KSPLIT; zz++) {
        size_t mi = ((size_t)(zz * 8 + h) * 3600 + q) * 2;
        mz[zz] = mlpart[mi];
        lz[zz] = mlpart[mi + 1];
    }
    float M = -INFINITY;
    #pragma unroll
    for (int zz = 0; zz < KSPLIT; zz++) if (lz[zz] > 0.f) M = fmaxf(M, mz[zz]);
    float wz[KSPLIT], den = 0.f;
    #pragma unroll
    for (int zz = 0; zz < KSPLIT; zz++) {
        wz[zz] = (lz[zz] > 0.f) ? __expf(mz[zz] - M) : 0.f;
        den += wz[zz] * lz[zz];
    }
    float inv = (den > 0.f) ? 1.f / den : 0.f;
    u16* op = obb + (size_t)q * D_ + h * HD + dg;
    #pragma unroll
    for (int e = 0; e < 16; e++) {
        float o = 0.f;
        #pragma unroll
        for (int zz = 0; zz < KSPLIT; zz++)
            o += bf2f(Opart[((size_t)(zz * 8 + h) * 3600 + q) * 64 + dg + e]) * wz[zz];
        op[e] = f2bf(o * inv);
    }
}

// ---------------- fused residual add + LayerNorm (emits fp32 x + bf16 xb) --
__global__ __launch_bounds__(256) void add_ln_kernel(
    float* __restrict__ x, const float* __restrict__ r,
    const float* __restrict__ g, const float* __restrict__ b,
    u16* __restrict__ xb)
{
    int row = blockIdx.x, t = threadIdx.x;
    size_t base = (size_t)row * D_;
    float v0 = x[base + t] + r[base + t];
    float v1 = x[base + t + 256] + r[base + t + 256];
    float s = v0 + v1, ss = v0 * v0 + v1 * v1;
    #pragma unroll
    for (int off = 32; off > 0; off >>= 1) {
        s  += __shfl_xor(s, off);
        ss += __shfl_xor(ss, off);
    }
    __shared__ float rs[4], rss[4];
    int w = t >> 6;
    if ((t & 63) == 0) { rs[w] = s; rss[w] = ss; }
    __syncthreads();
    s  = rs[0] + rs[1] + rs[2] + rs[3];
    ss = rss[0] + rss[1] + rss[2] + rss[3];
    float mean = s * (1.f / 512.f);
    float var = ss * (1.f / 512.f) - mean * mean;
    float rstd = rsqrtf(var + 1e-5f);
    float o0 = (v0 - mean) * rstd * g[t]       + b[t];
    float o1 = (v1 - mean) * rstd * g[t + 256] + b[t + 256];
    x[base + t]        = o0;
    x[base + t + 256]  = o1;
    xb[base + t]       = f2bf(o0);
    xb[base + t + 256] = f2bf(o1);
}

// ---------------------------------------------------------------------------
extern "C" void kernel_launch(void* const* d_in, const int* in_sizes, int n_in,
                              void* d_out, int out_size, void* d_ws, size_t ws_size,
                              hipStream_t stream)
{
    const float* player_xs = (const float*)d_in[0];
    const float* player_ys = (const float*)d_in[1];
    const float* player_hs = (const float*)d_in[2];
    const float* ball_xs   = (const float*)d_in[3];
    const float* ball_ys   = (const float*)d_in[4];
    const float* ball_zs   = (const float*)d_in[5];
    const float* emb_table = (const float*)d_in[6];
    const float* ball_emb  = (const float*)d_in[7];
    const float* cls_emb   = (const float*)d_in[8];
    const float* pW0 = (const float*)d_in[9];   const float* pb0 = (const float*)d_in[10];
    const float* pW1 = (const float*)d_in[11];  const float* pb1 = (const float*)d_in[12];
    const float* pW2 = (const float*)d_in[13];  const float* pb2 = (const float*)d_in[14];
    const float* bW0 = (const float*)d_in[15];  const float* bb0 = (const float*)d_in[16];
    const float* bW1 = (const float*)d_in[17];  const float* bb1 = (const float*)d_in[18];
    const float* bW2 = (const float*)d_in[19];  const float* bb2 = (const float*)d_in[20];
    const float* Wqkv = (const float*)d_in[21]; const float* bqkv = (const float*)d_in[22];
    const float* Wo  = (const float*)d_in[23];  const float* bo  = (const float*)d_in[24];
    const float* W1f = (const float*)d_in[25];  const float* b1f = (const float*)d_in[26];
    const float* W2f = (const float*)d_in[27];  const float* b2f = (const float*)d_in[28];
    const float* g1  = (const float*)d_in[29];  const float* be1 = (const float*)d_in[30];
    const float* g2  = (const float*)d_in[31];  const float* be2 = (const float*)d_in[32];
    const float* cpW = (const float*)d_in[33];  const float* cpb = (const float*)d_in[34];
    const float* cbW = (const float*)d_in[35];  const float* cbb = (const float*)d_in[36];
    const float* csW = (const float*)d_in[37];  const float* csb = (const float*)d_in[38];
    const int* pidx = (const int*)d_in[39];

    // workspace (51.6 MB): x | big | ob-region | tmp2
    float* x    = (float*)d_ws;            // 1,843,200 f32
    float* big  = x + 1843200;             // 7,372,800 f32
    float* obr  = big + 7372800;           // 1,843,200 f32 (obb bf16 | xb bf16)
    float* tmp2 = obr + 1843200;           // 1,843,200 f32
    // aliases inside big:
    u16*   qkvb   = (u16*)big;             // [3600][1536] bf16 = 2,764,800 slots
    u16*   Opart  = (u16*)(big + 2764800); // [4][8][3600][64] bf16 = 3,686,400 slots
    float* mlpart = big + 6451200;         // [4][8][3600][2] f32 = 230,400 (ends 6,681,600)
    u16*   wb     = (u16*)(big + 6681600); // bf16 head-weight scratch (<=1,382,400 u16)
    u16*   ff1b   = (u16*)big;             // [3600][2048] bf16 (FF phase)
    u16*   obb    = (u16*)obr;             // [3600][512] bf16
    u16*   xb     = (u16*)(obr + 921600);  // [3600][512] bf16
    u16*   vt     = (u16*)tmp2;            // [512][3648] bf16 (dead once Wo writes tmp2)
    // per-layer packed bf16 weights live in d_out (scratch until head GEMMs)
    float* out = (float*)d_out;
    u16* wpack  = (u16*)d_out;             // 3,145,728 u16 = 1,572,864 f32 < out_size
    u16* wqkv_b = wpack;                   // 1536*512
    u16* wo_b   = wpack + 786432;          // 512*512
    u16* w1f_b  = wpack + 1048576;         // 2048*512
    u16* w2f_b  = wpack + 2097152;         // 512*2048
    // token-MLP temporaries (big free before layers)
    float* IN = big;                       // 3600*24
    float* h0 = big + 131072;              // 3600*128
    float* h1 = big + 131072 + 460800;     // 3600*256

    gather_kernel<<<15, 256, 0, stream>>>(
        player_xs, player_ys, player_hs, ball_xs, ball_ys, ball_zs,
        emb_table, ball_emb, cls_emb, pidx, IN, x);

    gemm_mfma<1,0,0,0,0><<<dim3(24, 1), 256, 0, stream>>>(IN,            pW0, pb0, h0,            3000, 128, 23, 24, 1.f);
    gemm_mfma<1,0,0,0,0><<<dim3(3,  1), 256, 0, stream>>>(IN + 3000*24,  bW0, bb0, h0 + 3000*128,  300, 128, 23, 24, 1.f);
    gemm_mfma<1,0,0,0,0><<<dim3(24, 2), 256, 0, stream>>>(h0,            pW1, pb1, h1,            3000, 256, 128, 128, 1.f);
    gemm_mfma<1,0,0,0,0><<<dim3(3,  2), 256, 0, stream>>>(h0 + 3000*128, bW1, bb1, h1 + 3000*256,  300, 256, 128, 128, 1.f);
    gemm_mfma<0,0,0,0,0><<<dim3(24, 4), 256, 0, stream>>>(h1,            pW2, pb2, x,             3000, 512, 256, 256, SQRT512);
    gemm_mfma<0,0,0,0,0><<<dim3(3,  4), 256, 0, stream>>>(h1 + 3000*256, bW2, bb2, x + 3000*512,   300, 512, 256, 256, SQRT512);

    // initial xb = bf16(x)
    w2b_kernel<<<1024, 256, 0, stream>>>(x, xb, 1843200 / 4);

    for (int l = 0; l < 4; l++) {
        const float* Wqkv_l = Wqkv + (size_t)l * 1536 * 512;
        const float* bqkv_l = bqkv + (size_t)l * 1536;
        const float* Wo_l   = Wo   + (size_t)l * 512 * 512;
        const float* bo_l   = bo   + (size_t)l * 512;
        const float* W1f_l  = W1f  + (size_t)l * 2048 * 512;
        const float* b1f_l  = b1f  + (size_t)l * 2048;
        const float* W2f_l  = W2f  + (size_t)l * 512 * 2048;
        const float* b2f_l  = b2f  + (size_t)l * 512;

        w2b4_kernel<<<1024, 256, 0, stream>>>(Wqkv_l, Wo_l, W1f_l, W2f_l, wpack);
        gemm_mfma<0,1,1,1,1><<<dim3(29, 12), 256, 0, stream>>>(xb, wqkv_b, bqkv_l, qkvb, 3600, 1536, 512, 512, 1.f);
        vtrans_kernel<<<dim3(57, 8), 256, 0, stream>>>(qkvb, vt);
        attn_mfma_kernel<<<dim3(225, 8, KSPLIT), 64, 0, stream>>>(qkvb, vt, Opart, mlpart);
        attn_merge_kernel<<<dim3(57, 8), 256, 0, stream>>>(Opart, mlpart, obb);
        gemm_mfma<0,0,1,1,0><<<dim3(29, 4), 256, 0, stream>>>(obb, wo_b, bo_l, tmp2, 3600, 512, 512, 512, 1.f);
        add_ln_kernel<<<3600, 256, 0, stream>>>(x, tmp2, g1 + (size_t)l * 512, be1 + (size_t)l * 512, xb);
        gemm_mfma<1,1,1,1,0><<<dim3(29, 16), 256, 0, stream>>>(xb, w1f_b, b1f_l, ff1b, 3600, 2048, 512, 512, 1.f);
        gemm_mfma<0,0,1,1,0><<<dim3(29, 4), 256, 0, stream>>>(ff1b, w2f_b, b2f_l, tmp2, 3600, 512, 2048, 2048, 1.f);
        add_ln_kernel<<<3600, 256, 0, stream>>>(x, tmp2, g2 + (size_t)l * 512, be2 + (size_t)l * 512, xb);
    }

    w2b_kernel<<<64, 256, 0, stream>>>(cpW, wb, 121 * 512 / 4);
    gemm_mfma<0,0,1,1,0><<<dim3(29, 1),  256, 0, stream>>>(xb, wb, cpb, out + 0,       3600, 121,  512, 512, 1.f);
    w2b_kernel<<<512, 256, 0, stream>>>(cbW, wb, 1331 * 512 / 4);
    gemm_mfma<0,0,1,1,0><<<dim3(29, 11), 256, 0, stream>>>(xb, wb, cbb, out + 435600,  3600, 1331, 512, 512, 1.f);
    w2b_kernel<<<8, 256, 0, stream>>>(csW, wb, 10 * 512 / 4);
    gemm_mfma<0,0,1,1,0><<<dim3(29, 1),  256, 0, stream>>>(xb, wb, csb, out + 5227200, 3600, 10,   512, 512, 1.f);
}

// Round 10
// 1279.729 us; speedup vs baseline: 5.7612x; 1.0456x over previous
//
#include <hip/hip_runtime.h>
#include <hip/hip_bf16.h>

typedef unsigned short u16;
typedef __attribute__((ext_vector_type(8))) short bf16x8;
typedef __attribute__((ext_vector_type(4))) float f32x4;

#define T_TOK 3600
#define D_    512
#define H_    8
#define HD    64
#define NKT   57    // ceil(3600/64)
#define NQT   113   // ceil(3600/32)
#define VT_S  3648  // padded token stride for Vt
#define KSPLIT 4
#define SQRT512 22.627416997969522f

__device__ __forceinline__ u16 f2bf(float f) {
    unsigned int x = __float_as_uint(f);
    unsigned int lsb = (x >> 16) & 1;
    return (u16)((x + 0x7fffu + lsb) >> 16);
}
__device__ __forceinline__ float bf2f(u16 u) {
    return __uint_as_float(((unsigned int)u) << 16);
}
// timestep of token: players [0,3000) -> i/10, ball [3000,3300), cls [3300,3600)
__device__ __forceinline__ int step_of(int i) {
    return (i < 3000) ? (i / 10) : ((i < 3300) ? (i - 3000) : (i - 3300));
}
// min/max step of key-tile [kbase, kbase+64)
__device__ __forceinline__ void tile_minmax(int kbase, int& mn, int& mx) {
    int a = kbase, b = min(kbase + 63, T_TOK - 1);
    mn = 0x7fffffff; mx = -1;
    if (a < 3000)              { mn = min(mn, a / 10);              mx = max(mx, min(b, 2999) / 10); }
    if (b >= 3000 && a < 3300) { mn = min(mn, max(a, 3000) - 3000); mx = max(mx, min(b, 3299) - 3000); }
    if (b >= 3300)             { mn = min(mn, max(a, 3300) - 3300); mx = max(mx, b - 3300); }
}

// ---------------- gather: build IN[3600][24] + fill cls rows of x ----------
__global__ __launch_bounds__(256) void gather_kernel(
    const float* __restrict__ pxs, const float* __restrict__ pys, const float* __restrict__ phs,
    const float* __restrict__ bxs, const float* __restrict__ bys, const float* __restrict__ bzs,
    const float* __restrict__ emb_table, const float* __restrict__ ball_emb,
    const float* __restrict__ cls_emb, const int* __restrict__ pidx,
    float* __restrict__ IN, float* __restrict__ x)
{
    int g = blockIdx.x * 256 + threadIdx.x;   // 15*256 = 3840
    if (g < 3300) {
        float* row = IN + g * 24;
        if (g < 3000) {
            int id = pidx[g];
            #pragma unroll
            for (int e = 0; e < 20; e++) row[e] = emb_table[id * 20 + e];
            row[20] = pxs[g]; row[21] = pys[g]; row[22] = phs[g];
        } else {
            int b = g - 3000;
            #pragma unroll
            for (int e = 0; e < 20; e++) row[e] = ball_emb[e];
            row[20] = bxs[b]; row[21] = bys[b]; row[22] = bzs[b];
        }
        row[23] = 0.f;
    }
    for (int i = g; i < 300 * 512; i += 3840) {
        x[3300 * 512 + i] = cls_emb[i & 511];
    }
}

// ---------------- fp32 -> bf16 convert (grid-stride, float4) ---------------
__global__ __launch_bounds__(256) void w2b_kernel(
    const float* __restrict__ src, u16* __restrict__ dst, int n4)
{
    int stride = gridDim.x * 256;
    for (int i = blockIdx.x * 256 + threadIdx.x; i < n4; i += stride) {
        float4 v = reinterpret_cast<const float4*>(src)[i];
        ushort4 o;
        o.x = f2bf(v.x); o.y = f2bf(v.y); o.z = f2bf(v.z); o.w = f2bf(v.w);
        reinterpret_cast<ushort4*>(dst)[i] = o;
    }
}

// ---------------- fused per-layer weight convert (Wqkv|Wo|W1f|W2f) --------
__global__ __launch_bounds__(256) void w2b4_kernel(
    const float* __restrict__ s0, const float* __restrict__ s1,
    const float* __restrict__ s2, const float* __restrict__ s3,
    u16* __restrict__ dst)
{
    int stride = gridDim.x * 256;
    for (int i = blockIdx.x * 256 + threadIdx.x; i < 786432; i += stride) {
        const float4* src;
        int j = i;
        if (j < 196608)      { src = (const float4*)s0; }
        else if (j < 262144) { src = (const float4*)s1; j -= 196608; }
        else if (j < 524288) { src = (const float4*)s2; j -= 262144; }
        else                 { src = (const float4*)s3; j -= 524288; }
        float4 v = src[j];
        ushort4 o;
        o.x = f2bf(v.x); o.y = f2bf(v.y); o.z = f2bf(v.z); o.w = f2bf(v.w);
        reinterpret_cast<ushort4*>(dst)[i] = o;
    }
}

// ---------------- MFMA GEMM ------------------------------------------------
__device__ __forceinline__ void stage_f32(
    const float* __restrict__ src, int nrows, int K, int lda,
    int r0, int kk, int srow, int scg, u16* dst)
{
    u16 tmp[16];
    int rr = r0 + srow;
    if (rr < nrows) {
        if (((lda & 3) == 0) && (kk + scg + 16 <= K)) {
            const float4* p = reinterpret_cast<const float4*>(src + (size_t)rr * lda + kk + scg);
            #pragma unroll
            for (int q = 0; q < 4; q++) {
                float4 v = p[q];
                tmp[q*4+0] = f2bf(v.x); tmp[q*4+1] = f2bf(v.y);
                tmp[q*4+2] = f2bf(v.z); tmp[q*4+3] = f2bf(v.w);
            }
        } else {
            #pragma unroll
            for (int e = 0; e < 16; e++) {
                int kc = kk + scg + e;
                tmp[e] = (kc < K) ? f2bf(src[(size_t)rr * lda + kc]) : (u16)0;
            }
        }
    } else {
        #pragma unroll
        for (int e = 0; e < 16; e++) tmp[e] = 0;
    }
    *reinterpret_cast<bf16x8*>(dst)     = *reinterpret_cast<const bf16x8*>(&tmp[0]);
    *reinterpret_cast<bf16x8*>(dst + 8) = *reinterpret_cast<const bf16x8*>(&tmp[8]);
}

__device__ __forceinline__ void stage_b16(
    const u16* __restrict__ src, int nrows, int lda,
    int r0, int kk, int srow, int scg, u16* dst)
{
    int rr = r0 + srow;
    bf16x8 a = {}, b = {};
    if (rr < nrows) {
        const bf16x8* p = reinterpret_cast<const bf16x8*>(src + (size_t)rr * lda + kk + scg);
        a = p[0]; b = p[1];
    }
    *reinterpret_cast<bf16x8*>(dst)     = a;
    *reinterpret_cast<bf16x8*>(dst + 8) = b;
}

template<int RELU, int BF16OUT, int ABF16, int BBF16, int QSCALE>
__global__ __launch_bounds__(256) void gemm_mfma(
    const void* __restrict__ Av, const void* __restrict__ Wv,
    const float* __restrict__ bias, void* __restrict__ Cv,
    int M, int N, int K, int lda, float scale)
{
    __shared__ u16 As[128][40];
    __shared__ u16 Bs[128][40];
    int t = threadIdx.x;
    int w = t >> 6, l = t & 63;
    int ll = l & 15, lg = l >> 4;
    int wr = w >> 1, wc = w & 1;
    int m0 = blockIdx.x * 128, n0 = blockIdx.y * 128;
    int srow = t >> 1;
    int scg  = (t & 1) * 16;

    f32x4 acc[4][4];
    #pragma unroll
    for (int i = 0; i < 4; i++)
        #pragma unroll
        for (int j = 0; j < 4; j++) acc[i][j] = (f32x4){0.f, 0.f, 0.f, 0.f};

    for (int kk = 0; kk < K; kk += 32) {
        if (ABF16) stage_b16((const u16*)Av, M, lda, m0, kk, srow, scg, &As[srow][scg]);
        else       stage_f32((const float*)Av, M, K, lda, m0, kk, srow, scg, &As[srow][scg]);
        if (BBF16) stage_b16((const u16*)Wv, N, K, n0, kk, srow, scg, &Bs[srow][scg]);
        else       stage_f32((const float*)Wv, N, K, K, n0, kk, srow, scg, &Bs[srow][scg]);
        __syncthreads();
        bf16x8 af[4], bf[4];
        #pragma unroll
        for (int i = 0; i < 4; i++)
            af[i] = *reinterpret_cast<const bf16x8*>(&As[wr*64 + i*16 + ll][lg*8]);
        #pragma unroll
        for (int j = 0; j < 4; j++)
            bf[j] = *reinterpret_cast<const bf16x8*>(&Bs[wc*64 + j*16 + ll][lg*8]);
        #pragma unroll
        for (int i = 0; i < 4; i++)
            #pragma unroll
            for (int j = 0; j < 4; j++)
                acc[i][j] = __builtin_amdgcn_mfma_f32_16x16x32_bf16(af[i], bf[j], acc[i][j], 0, 0, 0);
        __syncthreads();
    }

    float bv[4];
    #pragma unroll
    for (int j = 0; j < 4; j++) {
        int n = n0 + wc*64 + j*16 + ll;
        bv[j] = (n < N) ? bias[n] : 0.f;
    }
    #pragma unroll
    for (int i = 0; i < 4; i++) {
        #pragma unroll
        for (int r = 0; r < 4; r++) {
            int m = m0 + wr*64 + i*16 + lg*4 + r;
            if (m >= M) continue;
            #pragma unroll
            for (int j = 0; j < 4; j++) {
                int n = n0 + wc*64 + j*16 + ll;
                if (n >= N) continue;
                float v = acc[i][j][r] + bv[j];
                if (RELU) v = fmaxf(v, 0.f);
                v *= scale;
                if (QSCALE && n < 512) v *= 0.125f;   // fold 1/sqrt(hd) into Q
                if (BF16OUT) ((u16*)Cv)[(size_t)m * N + n] = f2bf(v);
                else         ((float*)Cv)[(size_t)m * N + n] = v;
            }
        }
    }
}

// ---------------- V transpose: vt[h*64+d][tok] = qkvb[tok][1024+h*64+d] ----
__global__ __launch_bounds__(256) void vtrans_kernel(
    const u16* __restrict__ qkvb, u16* __restrict__ vt)
{
    __shared__ u16 tile[64][72];
    int t = threadIdx.x;
    int tok0 = blockIdx.x * 64;
    int h = blockIdx.y;
    {
        int i = t >> 2, c16 = (t & 3) * 16;
        int tok = tok0 + i;
        bf16x8 a = {}, b = {};
        if (tok < T_TOK) {
            const bf16x8* p = reinterpret_cast<const bf16x8*>(qkvb + (size_t)tok * 1536 + 1024 + h * HD + c16);
            a = p[0]; b = p[1];
        }
        *reinterpret_cast<bf16x8*>(&tile[i][c16])     = a;
        *reinterpret_cast<bf16x8*>(&tile[i][c16 + 8]) = b;
    }
    __syncthreads();
    {
        int d = t >> 2, i0 = (t & 3) * 16;
        u16 tt[16];
        #pragma unroll
        for (int e = 0; e < 16; e++) tt[e] = tile[i0 + e][d];
        u16* dst = vt + (size_t)(h * HD + d) * VT_S + tok0 + i0;
        *reinterpret_cast<bf16x8*>(dst)     = *reinterpret_cast<const bf16x8*>(&tt[0]);
        *reinterpret_cast<bf16x8*>(dst + 8) = *reinterpret_cast<const bf16x8*>(&tt[8]);
    }
}

// ---------------- MFMA flash attention, 1 wave per 32 queries --------------
// grid (113, 8, KSPLIT); block 64 = 1 wave owning 2x16-row MFMA blocks.
// Per-visit fixed costs (K/V loads, tile scan, loop control) amortized over
// 2x the scores vs the 16q version. LPT: heavy q-tiles launch first.
__global__ __launch_bounds__(64) void attn_mfma_kernel(
    const u16* __restrict__ qkvb, const u16* __restrict__ vt,
    u16* __restrict__ Opart, float* __restrict__ mlpart)
{
    __shared__ u16 plds[32][68];
    int l = threadIdx.x;
    int lg = l >> 4, ll = l & 15;
    int h = blockIdx.y;
    int z = blockIdx.z;
    int q0 = (NQT - 1 - (int)blockIdx.x) * 32;   // LPT order

    // Q frags for both 16-row blocks
    bf16x8 qf0[2], qf1[2];
    int sqa[2];
    #pragma unroll
    for (int b = 0; b < 2; b++) {
        int qa = min(q0 + b * 16 + ll, T_TOK - 1);
        const u16* qrow = qkvb + (size_t)qa * 1536 + h * HD + lg * 8;
        qf0[b] = *reinterpret_cast<const bf16x8*>(qrow);
        qf1[b] = *reinterpret_cast<const bf16x8*>(qrow + 32);
        sqa[b] = step_of(qa);
    }
    int sq[2][4];
    #pragma unroll
    for (int b = 0; b < 2; b++)
        #pragma unroll
        for (int r = 0; r < 4; r++)
            sq[b][r] = step_of(min(q0 + b * 16 + lg * 4 + r, T_TOK - 1));
    int smax = max(sqa[0], sqa[1]);
    int smin = min(sqa[0], sqa[1]);
    #pragma unroll
    for (int off = 1; off < 16; off <<= 1) {
        smax = max(smax, __shfl_xor(smax, off));
        smin = min(smin, __shfl_xor(smin, off));
    }

    f32x4 oacc[2][4];
    #pragma unroll
    for (int b = 0; b < 2; b++)
        #pragma unroll
        for (int i = 0; i < 4; i++) oacc[b][i] = (f32x4){0.f, 0.f, 0.f, 0.f};
    float m[2][4], lsum[2][4];
    #pragma unroll
    for (int b = 0; b < 2; b++)
        #pragma unroll
        for (int r = 0; r < 4; r++) { m[b][r] = -INFINITY; lsum[b][r] = 0.f; }

    #pragma unroll 1
    for (int kt = z; kt < NKT; kt += KSPLIT) {
        int kbase = kt * 64;
        int mn, mx;
        tile_minmax(kbase, mn, mx);
        if (mn > smax) continue;
        bool needmask = (mx > smin) || (kbase + 64 > T_TOK);

        // ---- K loads (8) ----
        bf16x8 kf0[4], kf1[4];
        #pragma unroll
        for (int f = 0; f < 4; f++) {
            int keyc = min(kbase + f * 16 + ll, T_TOK - 1);
            const u16* kr = qkvb + (size_t)keyc * 1536 + 512 + h * HD + lg * 8;
            kf0[f] = *reinterpret_cast<const bf16x8*>(kr);
            kf1[f] = *reinterpret_cast<const bf16x8*>(kr + 32);
        }
        // ---- V preload (8, shared by both q-blocks) ----
        bf16x8 vf0[4], vf1[4];
        #pragma unroll
        for (int i = 0; i < 4; i++) {
            const u16* vr = vt + (size_t)(h * HD + i * 16 + ll) * VT_S + kbase + lg * 8;
            vf0[i] = *reinterpret_cast<const bf16x8*>(vr);
            vf1[i] = *reinterpret_cast<const bf16x8*>(vr + 32);
        }

        // ---- QK^T: 16 MFMAs ----
        f32x4 sfr[2][4];
        __builtin_amdgcn_s_setprio(1);
        #pragma unroll
        for (int f = 0; f < 4; f++) {
            #pragma unroll
            for (int b = 0; b < 2; b++) {
                f32x4 acc = (f32x4){0.f, 0.f, 0.f, 0.f};
                acc = __builtin_amdgcn_mfma_f32_16x16x32_bf16(qf0[b], kf0[f], acc, 0, 0, 0);
                acc = __builtin_amdgcn_mfma_f32_16x16x32_bf16(qf1[b], kf1[f], acc, 0, 0, 0);
                sfr[b][f] = acc;
            }
        }
        __builtin_amdgcn_s_setprio(0);

        // ---- row max ----
        float rmax[2][4];
        #pragma unroll
        for (int b = 0; b < 2; b++)
            #pragma unroll
            for (int r = 0; r < 4; r++) rmax[b][r] = -INFINITY;
        if (!needmask) {
            #pragma unroll
            for (int f = 0; f < 4; f++)
                #pragma unroll
                for (int b = 0; b < 2; b++)
                    #pragma unroll
                    for (int r = 0; r < 4; r++) rmax[b][r] = fmaxf(rmax[b][r], sfr[b][f][r]);
        } else {
            #pragma unroll
            for (int f = 0; f < 4; f++) {
                int key = kbase + f * 16 + ll;
                int sk = (key < T_TOK) ? step_of(key) : 0x7fffffff;
                #pragma unroll
                for (int b = 0; b < 2; b++)
                    #pragma unroll
                    for (int r = 0; r < 4; r++) {
                        float v = sfr[b][f][r];
                        v = (sk <= sq[b][r]) ? v : -INFINITY;
                        sfr[b][f][r] = v;
                        rmax[b][r] = fmaxf(rmax[b][r], v);
                    }
            }
        }
        #pragma unroll
        for (int b = 0; b < 2; b++)
            #pragma unroll
            for (int r = 0; r < 4; r++) {
                float v = rmax[b][r];
                v = fmaxf(v, __shfl_xor(v, 1));
                v = fmaxf(v, __shfl_xor(v, 2));
                v = fmaxf(v, __shfl_xor(v, 4));
                v = fmaxf(v, __shfl_xor(v, 8));
                rmax[b][r] = v;
            }
        // ---- defer-max: rescale only when some row grew past THR=8 ----
        bool upd = false;
        #pragma unroll
        for (int b = 0; b < 2; b++)
            #pragma unroll
            for (int r = 0; r < 4; r++) upd = upd || (rmax[b][r] > m[b][r] + 8.f);
        if (__any(upd)) {
            #pragma unroll
            for (int b = 0; b < 2; b++) {
                float csc[4];
                #pragma unroll
                for (int r = 0; r < 4; r++) {
                    float mn2 = fmaxf(m[b][r], rmax[b][r]);
                    float c = (m[b][r] == -INFINITY) ? 0.f : __expf(m[b][r] - mn2);
                    csc[r] = c;
                    m[b][r] = mn2;
                    lsum[b][r] *= c;
                }
                #pragma unroll
                for (int i = 0; i < 4; i++)
                    #pragma unroll
                    for (int r = 0; r < 4; r++) oacc[b][i][r] *= csc[r];
            }
        }
        // ---- P = exp(S - m) -> bf16 -> LDS (A-frag layout) ----
        if (!needmask) {
            #pragma unroll
            for (int f = 0; f < 4; f++)
                #pragma unroll
                for (int b = 0; b < 2; b++)
                    #pragma unroll
                    for (int r = 0; r < 4; r++) {
                        float p = __expf(sfr[b][f][r] - m[b][r]);
                        lsum[b][r] += p;
                        plds[b * 16 + lg * 4 + r][f * 16 + ll] = f2bf(p);
                    }
        } else {
            #pragma unroll
            for (int f = 0; f < 4; f++)
                #pragma unroll
                for (int b = 0; b < 2; b++)
                    #pragma unroll
                    for (int r = 0; r < 4; r++) {
                        float sv = sfr[b][f][r];
                        float p = (sv == -INFINITY) ? 0.f : __expf(sv - m[b][r]);
                        lsum[b][r] += p;
                        plds[b * 16 + lg * 4 + r][f * 16 + ll] = f2bf(p);
                    }
        }
        // ---- PV: 16 MFMAs (same-wave LDS RAW) ----
        __builtin_amdgcn_s_setprio(1);
        #pragma unroll
        for (int b = 0; b < 2; b++) {
            bf16x8 pf0 = *reinterpret_cast<const bf16x8*>(&plds[b * 16 + ll][lg * 8]);
            #pragma unroll
            for (int i = 0; i < 4; i++)
                oacc[b][i] = __builtin_amdgcn_mfma_f32_16x16x32_bf16(pf0, vf0[i], oacc[b][i], 0, 0, 0);
            bf16x8 pf1 = *reinterpret_cast<const bf16x8*>(&plds[b * 16 + ll][32 + lg * 8]);
            #pragma unroll
            for (int i = 0; i < 4; i++)
                oacc[b][i] = __builtin_amdgcn_mfma_f32_16x16x32_bf16(pf1, vf1[i], oacc[b][i], 0, 0, 0);
        }
        __builtin_amdgcn_s_setprio(0);
    }

    // row-sum lsum across 16 col-lanes
    #pragma unroll
    for (int b = 0; b < 2; b++)
        #pragma unroll
        for (int r = 0; r < 4; r++) {
            float v = lsum[b][r];
            v += __shfl_xor(v, 1);
            v += __shfl_xor(v, 2);
            v += __shfl_xor(v, 4);
            v += __shfl_xor(v, 8);
            lsum[b][r] = v;
        }
    // write partials (unnormalized)
    #pragma unroll
    for (int b = 0; b < 2; b++)
        #pragma unroll
        for (int r = 0; r < 4; r++) {
            int q = q0 + b * 16 + lg * 4 + r;
            if (q >= T_TOK) continue;
            size_t ob = ((size_t)(z * 8 + h) * 3600 + q) * 64;
            #pragma unroll
            for (int i = 0; i < 4; i++)
                Opart[ob + i * 16 + ll] = f2bf(oacc[b][i][r]);
            if (ll == 0) {
                size_t mi = ((size_t)(z * 8 + h) * 3600 + q) * 2;
                mlpart[mi]     = m[b][r];
                mlpart[mi + 1] = lsum[b][r];
            }
        }
}

// ---------------- merge KSPLIT partials -> obb (bf16) ----------------------
__global__ __launch_bounds__(256) void attn_merge_kernel(
    const u16* __restrict__ Opart, const float* __restrict__ mlpart,
    u16* __restrict__ obb)
{
    int t = threadIdx.x;
    int h = blockIdx.y;
    int q = blockIdx.x * 64 + (t >> 2);
    if (q >= T_TOK) return;
    int dg = (t & 3) * 16;
    float mz[KSPLIT], lz[KSPLIT];
    #pragma unroll
    for (int zz = 0; zz < KSPLIT; zz++) {
        size_t mi = ((size_t)(zz * 8 + h) * 3600 + q) * 2;
        mz[zz] = mlpart[mi];
        lz[zz] = mlpart[mi + 1];
    }
    float M = -INFINITY;
    #pragma unroll
    for (int zz = 0; zz < KSPLIT; zz++) if (lz[zz] > 0.f) M = fmaxf(M, mz[zz]);
    float wz[KSPLIT], den = 0.f;
    #pragma unroll
    for (int zz = 0; zz < KSPLIT; zz++) {
        wz[zz] = (lz[zz] > 0.f) ? __expf(mz[zz] - M) : 0.f;
        den += wz[zz] * lz[zz];
    }
    float inv = (den > 0.f) ? 1.f / den : 0.f;
    u16* op = obb + (size_t)q * D_ + h * HD + dg;
    #pragma unroll
    for (int e = 0; e < 16; e++) {
        float o = 0.f;
        #pragma unroll
        for (int zz = 0; zz < KSPLIT; zz++)
            o += bf2f(Opart[((size_t)(zz * 8 + h) * 3600 + q) * 64 + dg + e]) * wz[zz];
        op[e] = f2bf(o * inv);
    }
}

// ---------------- fused residual add + LayerNorm (emits fp32 x + bf16 xb) --
__global__ __launch_bounds__(256) void add_ln_kernel(
    float* __restrict__ x, const float* __restrict__ r,
    const float* __restrict__ g, const float* __restrict__ b,
    u16* __restrict__ xb)
{
    int row = blockIdx.x, t = threadIdx.x;
    size_t base = (size_t)row * D_;
    float v0 = x[base + t] + r[base + t];
    float v1 = x[base + t + 256] + r[base + t + 256];
    float s = v0 + v1, ss = v0 * v0 + v1 * v1;
    #pragma unroll
    for (int off = 32; off > 0; off >>= 1) {
        s  += __shfl_xor(s, off);
        ss += __shfl_xor(ss, off);
    }
    __shared__ float rs[4], rss[4];
    int w = t >> 6;
    if ((t & 63) == 0) { rs[w] = s; rss[w] = ss; }
    __syncthreads();
    s  = rs[0] + rs[1] + rs[2] + rs[3];
    ss = rss[0] + rss[1] + rss[2] + rss[3];
    float mean = s * (1.f / 512.f);
    float var = ss * (1.f / 512.f) - mean * mean;
    float rstd = rsqrtf(var + 1e-5f);
    float o0 = (v0 - mean) * rstd * g[t]       + b[t];
    float o1 = (v1 - mean) * rstd * g[t + 256] + b[t + 256];
    x[base + t]        = o0;
    x[base + t + 256]  = o1;
    xb[base + t]       = f2bf(o0);
    xb[base + t + 256] = f2bf(o1);
}

// ---------------------------------------------------------------------------
extern "C" void kernel_launch(void* const* d_in, const int* in_sizes, int n_in,
                              void* d_out, int out_size, void* d_ws, size_t ws_size,
                              hipStream_t stream)
{
    const float* player_xs = (const float*)d_in[0];
    const float* player_ys = (const float*)d_in[1];
    const float* player_hs = (const float*)d_in[2];
    const float* ball_xs   = (const float*)d_in[3];
    const float* ball_ys   = (const float*)d_in[4];
    const float* ball_zs   = (const float*)d_in[5];
    const float* emb_table = (const float*)d_in[6];
    const float* ball_emb  = (const float*)d_in[7];
    const float* cls_emb   = (const float*)d_in[8];
    const float* pW0 = (const float*)d_in[9];   const float* pb0 = (const float*)d_in[10];
    const float* pW1 = (const float*)d_in[11];  const float* pb1 = (const float*)d_in[12];
    const float* pW2 = (const float*)d_in[13];  const float* pb2 = (const float*)d_in[14];
    const float* bW0 = (const float*)d_in[15];  const float* bb0 = (const float*)d_in[16];
    const float* bW1 = (const float*)d_in[17];  const float* bb1 = (const float*)d_in[18];
    const float* bW2 = (const float*)d_in[19];  const float* bb2 = (const float*)d_in[20];
    const float* Wqkv = (const float*)d_in[21]; const float* bqkv = (const float*)d_in[22];
    const float* Wo  = (const float*)d_in[23];  const float* bo  = (const float*)d_in[24];
    const float* W1f = (const float*)d_in[25];  const float* b1f = (const float*)d_in[26];
    const float* W2f = (const float*)d_in[27];  const float* b2f = (const float*)d_in[28];
    const float* g1  = (const float*)d_in[29];  const float* be1 = (const float*)d_in[30];
    const float* g2  = (const float*)d_in[31];  const float* be2 = (const float*)d_in[32];
    const float* cpW = (const float*)d_in[33];  const float* cpb = (const float*)d_in[34];
    const float* cbW = (const float*)d_in[35];  const float* cbb = (const float*)d_in[36];
    const float* csW = (const float*)d_in[37];  const float* csb = (const float*)d_in[38];
    const int* pidx = (const int*)d_in[39];

    // workspace (51.6 MB): x | big | ob-region | tmp2
    float* x    = (float*)d_ws;            // 1,843,200 f32
    float* big  = x + 1843200;             // 7,372,800 f32
    float* obr  = big + 7372800;           // 1,843,200 f32 (obb bf16 | xb bf16)
    float* tmp2 = obr + 1843200;           // 1,843,200 f32
    // aliases inside big:
    u16*   qkvb   = (u16*)big;             // [3600][1536] bf16 = 2,764,800 slots
    u16*   Opart  = (u16*)(big + 2764800); // [4][8][3600][64] bf16 = 3,686,400 slots
    float* mlpart = big + 6451200;         // [4][8][3600][2] f32 = 230,400 (ends 6,681,600)
    u16*   wb     = (u16*)(big + 6681600); // bf16 head-weight scratch (<=1,382,400 u16)
    u16*   ff1b   = (u16*)big;             // [3600][2048] bf16 (FF phase)
    u16*   obb    = (u16*)obr;             // [3600][512] bf16
    u16*   xb     = (u16*)(obr + 921600);  // [3600][512] bf16
    u16*   vt     = (u16*)tmp2;            // [512][3648] bf16 (dead once Wo writes tmp2)
    // per-layer packed bf16 weights live in d_out (scratch until head GEMMs)
    float* out = (float*)d_out;
    u16* wpack  = (u16*)d_out;             // 3,145,728 u16 < out_size floats
    u16* wqkv_b = wpack;                   // 1536*512
    u16* wo_b   = wpack + 786432;          // 512*512
    u16* w1f_b  = wpack + 1048576;         // 2048*512
    u16* w2f_b  = wpack + 2097152;         // 512*2048
    // token-MLP temporaries (big free before layers)
    float* IN = big;                       // 3600*24
    float* h0 = big + 131072;              // 3600*128
    float* h1 = big + 131072 + 460800;     // 3600*256

    gather_kernel<<<15, 256, 0, stream>>>(
        player_xs, player_ys, player_hs, ball_xs, ball_ys, ball_zs,
        emb_table, ball_emb, cls_emb, pidx, IN, x);

    gemm_mfma<1,0,0,0,0><<<dim3(24, 1), 256, 0, stream>>>(IN,            pW0, pb0, h0,            3000, 128, 23, 24, 1.f);
    gemm_mfma<1,0,0,0,0><<<dim3(3,  1), 256, 0, stream>>>(IN + 3000*24,  bW0, bb0, h0 + 3000*128,  300, 128, 23, 24, 1.f);
    gemm_mfma<1,0,0,0,0><<<dim3(24, 2), 256, 0, stream>>>(h0,            pW1, pb1, h1,            3000, 256, 128, 128, 1.f);
    gemm_mfma<1,0,0,0,0><<<dim3(3,  2), 256, 0, stream>>>(h0 + 3000*128, bW1, bb1, h1 + 3000*256,  300, 256, 128, 128, 1.f);
    gemm_mfma<0,0,0,0,0><<<dim3(24, 4), 256, 0, stream>>>(h1,            pW2, pb2, x,             3000, 512, 256, 256, SQRT512);
    gemm_mfma<0,0,0,0,0><<<dim3(3,  4), 256, 0, stream>>>(h1 + 3000*256, bW2, bb2, x + 3000*512,   300, 512, 256, 256, SQRT512);

    // initial xb = bf16(x)
    w2b_kernel<<<1024, 256, 0, stream>>>(x, xb, 1843200 / 4);

    for (int l = 0; l < 4; l++) {
        const float* Wqkv_l = Wqkv + (size_t)l * 1536 * 512;
        const float* bqkv_l = bqkv + (size_t)l * 1536;
        const float* Wo_l   = Wo   + (size_t)l * 512 * 512;
        const float* bo_l   = bo   + (size_t)l * 512;
        const float* W1f_l  = W1f  + (size_t)l * 2048 * 512;
        const float* b1f_l  = b1f  + (size_t)l * 2048;
        const float* W2f_l  = W2f  + (size_t)l * 512 * 2048;
        const float* b2f_l  = b2f  + (size_t)l * 512;

        w2b4_kernel<<<1024, 256, 0, stream>>>(Wqkv_l, Wo_l, W1f_l, W2f_l, wpack);
        gemm_mfma<0,1,1,1,1><<<dim3(29, 12), 256, 0, stream>>>(xb, wqkv_b, bqkv_l, qkvb, 3600, 1536, 512, 512, 1.f);
        vtrans_kernel<<<dim3(57, 8), 256, 0, stream>>>(qkvb, vt);
        attn_mfma_kernel<<<dim3(NQT, 8, KSPLIT), 64, 0, stream>>>(qkvb, vt, Opart, mlpart);
        attn_merge_kernel<<<dim3(57, 8), 256, 0, stream>>>(Opart, mlpart, obb);
        gemm_mfma<0,0,1,1,0><<<dim3(29, 4), 256, 0, stream>>>(obb, wo_b, bo_l, tmp2, 3600, 512, 512, 512, 1.f);
        add_ln_kernel<<<3600, 256, 0, stream>>>(x, tmp2, g1 + (size_t)l * 512, be1 + (size_t)l * 512, xb);
        gemm_mfma<1,1,1,1,0><<<dim3(29, 16), 256, 0, stream>>>(xb, w1f_b, b1f_l, ff1b, 3600, 2048, 512, 512, 1.f);
        gemm_mfma<0,0,1,1,0><<<dim3(29, 4), 256, 0, stream>>>(ff1b, w2f_b, b2f_l, tmp2, 3600, 512, 2048, 2048, 1.f);
        add_ln_kernel<<<3600, 256, 0, stream>>>(x, tmp2, g2 + (size_t)l * 512, be2 + (size_t)l * 512, xb);
    }

    w2b_kernel<<<64, 256, 0, stream>>>(cpW, wb, 121 * 512 / 4);
    gemm_mfma<0,0,1,1,0><<<dim3(29, 1),  256, 0, stream>>>(xb, wb, cpb, out + 0,       3600, 121,  512, 512, 1.f);
    w2b_kernel<<<512, 256, 0, stream>>>(cbW, wb, 1331 * 512 / 4);
    gemm_mfma<0,0,1,1,0><<<dim3(29, 11), 256, 0, stream>>>(xb, wb, cbb, out + 435600,  3600, 1331, 512, 512, 1.f);
    w2b_kernel<<<8, 256, 0, stream>>>(csW, wb, 10 * 512 / 4);
    gemm_mfma<0,0,1,1,0><<<dim3(29, 1),  256, 0, stream>>>(xb, wb, csb, out + 5227200, 3600, 10,   512, 512, 1.f);
}